// Round 3
// baseline (1951.339 us; speedup 1.0000x reference)
//
#include <hip/hip_runtime.h>
#include <hip/hip_bf16.h>
#include <math.h>

#define N_NODES 50000
#define N_EDGES 800000
#define ET (N_EDGES + N_NODES)   // edges + self loops
#define IN_F 256
#define G 128                    // 2*HID
#define NHID 64
#define NGRAPH 32

typedef __hip_bfloat16 bf16;

// ---------- dtype-agnostic loads (flags resolved at runtime, wave-uniform) ----------
__device__ __forceinline__ float bf2f(unsigned short u) {
    union { unsigned u; float f; } c; c.u = ((unsigned)u) << 16; return c.f;
}
__device__ __forceinline__ float ldf(const void* p, long i, int f32) {
    return f32 ? ((const float*)p)[i] : bf2f(((const unsigned short*)p)[i]);
}
__device__ __forceinline__ int ldi(const void* p, long i, int i64) {
    return i64 ? (int)((const long long*)p)[i] : ((const int*)p)[i];
}

__device__ __forceinline__ float selu_f(float x) {
    const float sc = 1.0507009873554805f, al = 1.6732632423543772f;
    return x > 0.f ? sc * x : sc * al * expm1f(x);
}

// order-preserving float<->uint encoding for atomicMax on floats
__device__ __forceinline__ unsigned fenc(float f) {
    unsigned u = __float_as_uint(f);
    return (u & 0x80000000u) ? ~u : (u | 0x80000000u);
}
__device__ __forceinline__ float fdec(unsigned u) {
    return (u & 0x80000000u) ? __uint_as_float(u & 0x7fffffffu) : __uint_as_float(~u);
}

// flags[0]=1 -> float inputs are f32 (else bf16); flags[1]=1 -> ints are int64.
// All reads stay within the SMALLER (bf16/int32) buffer size -> safe in either world.
__global__ void detect_kernel(const void* x, const void* ei, int* flags) {
    if (threadIdx.x != 0 || blockIdx.x != 0) return;
    // float detection: view as uint32. f32 world: each word is a float with a
    // sane exponent. bf16 world: high 16 bits are a bf16 whose exponent bits
    // land in the f32 exponent field as >=240 -> insane.
    const unsigned* xu = (const unsigned*)x;
    const long NW = (long)N_NODES * IN_F / 2;   // uint32 words, safe both worlds
    long stride = NW / 1024;
    int sane = 0;
    for (int k = 0; k < 1024; k++) {
        unsigned u = xu[(long)k * stride];
        unsigned e = (u >> 23) & 0xFF;
        if (u == 0u || (e >= 100 && e <= 140)) sane++;
    }
    flags[0] = (sane >= 512) ? 1 : 0;
    // int detection: odd uint32 words of edge_index. int64 world: high words,
    // all zero (node ids >=0 < 2^31). int32 world: actual ids, mostly nonzero.
    const unsigned* wu = (const unsigned*)ei;
    int nz = 0;
    for (int k = 0; k < 1024; k++) {
        long j = ((long)k * 1562) | 1;          // odd, < 1,600,000
        nz += (wu[j] != 0u);
    }
    flags[1] = (nz < 16) ? 1 : 0;
}

__global__ void zero_kernel(float* __restrict__ p, long n) {
    long i = (long)blockIdx.x * 256 + threadIdx.x;
    if (i < n) p[i] = 0.f;
}

// C[M x 128] = A[M x K] * W[K x 128]; blockDim=128, grid = M/RPB
template <int RPB>
__global__ void gemm_kernel(const void* __restrict__ A, const void* __restrict__ W,
                            float* __restrict__ C, int K, int a_internal,
                            const int* __restrict__ flags) {
    __shared__ float At[RPB * IN_F];  // max K = 256 -> 8 KB
    int tid = threadIdx.x;
    int f32 = flags[0];
    int af32 = a_internal ? 1 : f32;
    long row0 = (long)blockIdx.x * RPB;
    if (af32) {
        const float* Af = (const float*)A;
        for (int i = tid; i < RPB * K; i += 128) At[i] = Af[row0 * K + i];
    } else {
        const unsigned short* Ab = (const unsigned short*)A;
        for (int i = tid; i < RPB * K; i += 128) At[i] = bf2f(Ab[row0 * K + i]);
    }
    __syncthreads();
    float acc[RPB];
#pragma unroll
    for (int r = 0; r < RPB; r++) acc[r] = 0.f;
    if (f32) {
        const float* Wf = (const float*)W;
        for (int k = 0; k < K; k++) {
            float w = Wf[k * G + tid];
#pragma unroll
            for (int r = 0; r < RPB; r++) acc[r] += At[r * K + k] * w;
        }
    } else {
        const unsigned short* Wb = (const unsigned short*)W;
        for (int k = 0; k < K; k++) {
            float w = bf2f(Wb[k * G + tid]);
#pragma unroll
            for (int r = 0; r < RPB; r++) acc[r] += At[r * K + k] * w;
        }
    }
#pragma unroll
    for (int r = 0; r < RPB; r++) C[(row0 + r) * G + tid] = acc[r];
}

// per-node attention terms: es = h.as, ed = h.ad ; one wave per node
__global__ void ead_kernel(const float* __restrict__ h, const void* __restrict__ aS,
                           const void* __restrict__ aD, float* __restrict__ es,
                           float* __restrict__ ed, const int* __restrict__ flags) {
    int n = blockIdx.x;
    int l = threadIdx.x;  // 64
    int f32 = flags[0];
    const float* hp = h + (size_t)n * G;
    float h0 = hp[l], h1 = hp[l + 64];
    float s = h0 * ldf(aS, l, f32) + h1 * ldf(aS, l + 64, f32);
    float d = h0 * ldf(aD, l, f32) + h1 * ldf(aD, l + 64, f32);
    for (int off = 32; off; off >>= 1) {
        s += __shfl_down(s, off);
        d += __shfl_down(d, off);
    }
    if (l == 0) { es[n] = s; ed[n] = d; }
}

__device__ __forceinline__ void edge_sd(const void* __restrict__ ei, int e, int i64,
                                        int& s, int& d) {
    if (e < N_EDGES) {
        s = ldi(ei, e, i64);
        d = ldi(ei, (long)N_EDGES + e, i64);
        s = min(max(s, 0), N_NODES - 1);
        d = min(max(d, 0), N_NODES - 1);
    } else {
        s = d = e - N_EDGES;
    }
}

__global__ void edge_max_kernel(const void* __restrict__ ei, const float* __restrict__ es,
                                const float* __restrict__ ed, float* __restrict__ ebuf,
                                unsigned* __restrict__ menc, const int* __restrict__ flags) {
    int e = blockIdx.x * 256 + threadIdx.x;
    if (e >= ET) return;
    int s, d; edge_sd(ei, e, flags[1], s, d);
    float v = es[s] + ed[d];
    v = v >= 0.f ? v : 0.2f * v;  // LeakyReLU(0.2)
    ebuf[e] = v;
    atomicMax(&menc[d], fenc(v));
}

__global__ void edge_exp_kernel(const void* __restrict__ ei, float* __restrict__ ebuf,
                                const unsigned* __restrict__ menc, float* __restrict__ den,
                                const int* __restrict__ flags) {
    int e = blockIdx.x * 256 + threadIdx.x;
    if (e >= ET) return;
    int s, d; edge_sd(ei, e, flags[1], s, d);
    float ex = expf(fminf(ebuf[e] - fdec(menc[d]), 20.f));
    ebuf[e] = ex;
    atomicAdd(&den[d], ex);
}

__global__ void edge_alpha_kernel(const void* __restrict__ ei, float* __restrict__ ebuf,
                                  const float* __restrict__ den, const int* __restrict__ flags) {
    int e = blockIdx.x * 256 + threadIdx.x;
    if (e >= ET) return;
    int s, d; edge_sd(ei, e, flags[1], s, d);
    ebuf[e] = ebuf[e] / (den[d] + 1e-16f);
}

// agg[dst][f] += alpha[e] * h[src][f]; thread = (edge, feat)
__global__ void edge_scatter_kernel(const void* __restrict__ ei, const float* __restrict__ alpha,
                                    const float* __restrict__ h, float* __restrict__ agg,
                                    const int* __restrict__ flags) {
    unsigned gid = blockIdx.x * 256u + threadIdx.x;
    unsigned e = gid >> 7;
    int f = gid & (G - 1);
    if (e >= ET) return;
    int s, d; edge_sd(ei, (int)e, flags[1], s, d);
    atomicAdd(&agg[(size_t)d * G + f], alpha[e] * h[(size_t)s * G + f]);
}

__global__ void bias_selu_kernel(float* __restrict__ a, const void* __restrict__ b,
                                 const int* __restrict__ flags) {
    size_t i = (size_t)blockIdx.x * 256 + threadIdx.x;
    if (i >= (size_t)N_NODES * G) return;
    int f = (int)(i & (G - 1));
    a[i] = selu_f(a[i] + ldf(b, f, flags[0]));
}

// batch is sorted: run-length accumulate, flush on graph change. blockDim=128
__global__ void pool_kernel(const float* __restrict__ h, const void* __restrict__ batch,
                            float* __restrict__ gsum, const int* __restrict__ flags) {
    int t = threadIdx.x;
    int i64 = flags[1];
    int i0 = blockIdx.x * 512;
    int i1 = min(N_NODES, i0 + 512);
    int cur = -1;
    float acc = 0.f;
    for (int i = i0; i < i1; i++) {
        int g = min(max(ldi(batch, i, i64), 0), NGRAPH - 1);
        if (g != cur) {
            if (cur >= 0) atomicAdd(&gsum[cur * G + t], acc);
            cur = g; acc = 0.f;
        }
        acc += h[(size_t)i * G + t];
    }
    if (cur >= 0) atomicAdd(&gsum[cur * G + t], acc);
}

__global__ void count_kernel(const void* __restrict__ batch, float* __restrict__ gcnt,
                             const int* __restrict__ flags) {
    int i = blockIdx.x * 256 + threadIdx.x;
    if (i < N_NODES) {
        int g = min(max(ldi(batch, i, flags[1]), 0), NGRAPH - 1);
        atomicAdd(&gcnt[g], 1.0f);
    }
}

// pooled -> selu -> lin1+selu -> lin2 -> log_softmax; 32 blocks x 64 threads
// OUTPUT IS FLOAT32 (reference output dtype; harness doc: non-bf16 -> float*)
__global__ void head_kernel(const float* __restrict__ gsum, const float* __restrict__ gcnt,
                            const void* __restrict__ lw1, const void* __restrict__ lb1,
                            const void* __restrict__ lw2, const void* __restrict__ lb2,
                            float* __restrict__ out, const int* __restrict__ flags) {
    int g = blockIdx.x, t = threadIdx.x;  // 64
    int f32 = flags[0];
    __shared__ float z[G];
    __shared__ float z1[NHID];
    __shared__ float z2[2];
    float cnt = fmaxf(gcnt[g], 1.0f);
    z[t]      = selu_f(gsum[g * G + t] / cnt);
    z[t + 64] = selu_f(gsum[g * G + 64 + t] / cnt);
    __syncthreads();
    float a = ldf(lb1, t, f32);
    for (int k = 0; k < G; k++) a += z[k] * ldf(lw1, k * NHID + t, f32);
    z1[t] = selu_f(a);
    __syncthreads();
    if (t < 2) {
        float s = ldf(lb2, t, f32);
        for (int j = 0; j < NHID; j++) s += z1[j] * ldf(lw2, j * 2 + t, f32);
        z2[t] = s;
    }
    __syncthreads();
    if (t == 0) {
        float mx = fmaxf(z2[0], z2[1]);
        float l = mx + logf(expf(z2[0] - mx) + expf(z2[1] - mx));
        out[g * 2 + 0] = z2[0] - l;
        out[g * 2 + 1] = z2[1] - l;
    }
}

extern "C" void kernel_launch(void* const* d_in, const int* in_sizes, int n_in,
                              void* d_out, int out_size, void* d_ws, size_t ws_size,
                              hipStream_t stream) {
    const void* x    = d_in[0];
    const void* ei   = d_in[1];
    const void* batch= d_in[2];
    const void* W1   = d_in[3];
    const void* as1  = d_in[4];
    const void* ad1  = d_in[5];
    const void* b1   = d_in[6];
    const void* W2   = d_in[7];
    const void* as2  = d_in[8];
    const void* ad2  = d_in[9];
    const void* b2   = d_in[10];
    const void* lw1  = d_in[11];
    const void* lb1  = d_in[12];
    const void* lw2  = d_in[13];
    const void* lb2  = d_in[14];
    float* out = (float*)d_out;

    char* w = (char*)d_ws;
    size_t off = 0;
    auto alloc = [&](size_t bytes) -> char* {
        char* p = w + off;
        off = (off + bytes + 255) & ~(size_t)255;
        return p;
    };
    int*      flags = (int*)alloc(256);
    float*    hbuf = (float*)alloc((size_t)N_NODES * G * 4);
    float*    abuf = (float*)alloc((size_t)N_NODES * G * 4);
    float*    es   = (float*)alloc((size_t)N_NODES * 4);
    float*    edv  = (float*)alloc((size_t)N_NODES * 4);
    unsigned* menc = (unsigned*)alloc((size_t)N_NODES * 4);
    float*    den  = (float*)alloc((size_t)N_NODES * 4);
    float*    ebuf = (float*)alloc((size_t)ET * 4);
    float*    gsum = (float*)alloc((size_t)NGRAPH * G * 4);
    float*    gcnt = (float*)alloc((size_t)NGRAPH * 4);

    auto zero = [&](void* p, size_t nf) {
        zero_kernel<<<(unsigned)((nf + 255) / 256), 256, 0, stream>>>((float*)p, (long)nf);
    };
    unsigned eb = (ET + 255) / 256;
    unsigned sb = (unsigned)((size_t)ET * G / 256);
    unsigned nb = (unsigned)((size_t)N_NODES * G / 256);

    detect_kernel<<<1, 64, 0, stream>>>(x, ei, flags);

    // ---------------- Layer 1 ----------------
    gemm_kernel<8><<<N_NODES / 8, 128, 0, stream>>>(x, W1, hbuf, IN_F, 0, flags);
    ead_kernel<<<N_NODES, 64, 0, stream>>>(hbuf, as1, ad1, es, edv, flags);
    zero(menc, N_NODES);
    zero(den, N_NODES);
    zero(abuf, (size_t)N_NODES * G);
    edge_max_kernel<<<eb, 256, 0, stream>>>(ei, es, edv, ebuf, menc, flags);
    edge_exp_kernel<<<eb, 256, 0, stream>>>(ei, ebuf, menc, den, flags);
    edge_alpha_kernel<<<eb, 256, 0, stream>>>(ei, ebuf, den, flags);
    edge_scatter_kernel<<<sb, 256, 0, stream>>>(ei, ebuf, hbuf, abuf, flags);
    bias_selu_kernel<<<nb, 256, 0, stream>>>(abuf, b1, flags);

    // ---------------- Layer 2 ----------------
    gemm_kernel<8><<<N_NODES / 8, 128, 0, stream>>>(abuf, W2, hbuf, G, 1, flags);
    ead_kernel<<<N_NODES, 64, 0, stream>>>(hbuf, as2, ad2, es, edv, flags);
    zero(menc, N_NODES);
    zero(den, N_NODES);
    edge_max_kernel<<<eb, 256, 0, stream>>>(ei, es, edv, ebuf, menc, flags);
    edge_exp_kernel<<<eb, 256, 0, stream>>>(ei, ebuf, menc, den, flags);
    edge_alpha_kernel<<<eb, 256, 0, stream>>>(ei, ebuf, den, flags);
    zero(abuf, (size_t)N_NODES * G);
    edge_scatter_kernel<<<sb, 256, 0, stream>>>(ei, ebuf, hbuf, abuf, flags);
    bias_selu_kernel<<<nb, 256, 0, stream>>>(abuf, b2, flags);

    // ---------------- Pool + head ----------------
    zero(gsum, (size_t)NGRAPH * G);
    zero(gcnt, NGRAPH);
    pool_kernel<<<(N_NODES + 511) / 512, 128, 0, stream>>>(abuf, batch, gsum, flags);
    count_kernel<<<(N_NODES + 255) / 256, 256, 0, stream>>>(batch, gcnt, flags);
    head_kernel<<<NGRAPH, 64, 0, stream>>>(gsum, gcnt, lw1, lb1, lw2, lb2, out, flags);
}

// Round 4
// 1209.937 us; speedup vs baseline: 1.6128x; 1.6128x over previous
//
#include <hip/hip_runtime.h>
#include <hip/hip_bf16.h>
#include <math.h>

#define N_NODES 50000
#define N_EDGES 800000
#define ET (N_EDGES + N_NODES)   // edges + self loops
#define IN_F 256
#define G 128                    // 2*HID
#define NHID 64
#define NGRAPH 32
#define NCHUNK ((N_NODES + 255) / 256)   // 196
#define CHUNK 1024                        // edges per LDS softmax chunk

typedef __hip_bfloat16 bf16;

// ---------- dtype-agnostic loads (flags resolved at runtime, wave-uniform) ----------
__device__ __forceinline__ float bf2f(unsigned short u) {
    union { unsigned u; float f; } c; c.u = ((unsigned)u) << 16; return c.f;
}
__device__ __forceinline__ float ldf(const void* p, long i, int f32) {
    return f32 ? ((const float*)p)[i] : bf2f(((const unsigned short*)p)[i]);
}
__device__ __forceinline__ int ldi(const void* p, long i, int i64) {
    return i64 ? (int)((const long long*)p)[i] : ((const int*)p)[i];
}

__device__ __forceinline__ float selu_f(float x) {
    const float sc = 1.0507009873554805f, al = 1.6732632423543772f;
    return x > 0.f ? sc * x : sc * al * expm1f(x);
}

// flags[0]=1 -> float inputs are f32 (else bf16); flags[1]=1 -> ints are int64.
__global__ void detect_kernel(const void* x, const void* ei, int* flags) {
    if (threadIdx.x != 0 || blockIdx.x != 0) return;
    const unsigned* xu = (const unsigned*)x;
    const long NW = (long)N_NODES * IN_F / 2;
    long stride = NW / 1024;
    int sane = 0;
    for (int k = 0; k < 1024; k++) {
        unsigned u = xu[(long)k * stride];
        unsigned e = (u >> 23) & 0xFF;
        if (u == 0u || (e >= 100 && e <= 140)) sane++;
    }
    flags[0] = (sane >= 512) ? 1 : 0;
    const unsigned* wu = (const unsigned*)ei;
    int nz = 0;
    for (int k = 0; k < 1024; k++) {
        long j = ((long)k * 1562) | 1;
        nz += (wu[j] != 0u);
    }
    flags[1] = (nz < 16) ? 1 : 0;
}

__global__ void zero_float_kernel(float* __restrict__ p, long n) {
    long i = (long)blockIdx.x * 256 + threadIdx.x;
    if (i < n) p[i] = 0.f;
}
__global__ void zero_int_kernel(int* __restrict__ p, long n) {
    long i = (long)blockIdx.x * 256 + threadIdx.x;
    if (i < n) p[i] = 0;
}

__device__ __forceinline__ void edge_sd(const void* __restrict__ ei, int e, int i64,
                                        int& s, int& d) {
    if (e < N_EDGES) {
        s = ldi(ei, e, i64);
        d = ldi(ei, (long)N_EDGES + e, i64);
        s = min(max(s, 0), N_NODES - 1);
        d = min(max(d, 0), N_NODES - 1);
    } else {
        s = d = e - N_EDGES;
    }
}

// ---------------- CSR build (once; graph is layer-invariant) ----------------
__global__ void deg_kernel(const void* __restrict__ ei, int* __restrict__ deg,
                           const int* __restrict__ flags) {
    int e = blockIdx.x * 256 + threadIdx.x;
    if (e >= ET) return;
    int s, d; edge_sd(ei, e, flags[1], s, d);
    atomicAdd(&deg[d], 1);
}

__global__ void chunk_sum_kernel(const int* __restrict__ deg, int* __restrict__ csum) {
    __shared__ int sd[256];
    int t = threadIdx.x;
    int i = blockIdx.x * 256 + t;
    sd[t] = (i < N_NODES) ? deg[i] : 0;
    __syncthreads();
    for (int off = 128; off; off >>= 1) {
        if (t < off) sd[t] += sd[t + off];
        __syncthreads();
    }
    if (t == 0) csum[blockIdx.x] = sd[0];
}

__global__ void scan_csum_kernel(int* __restrict__ csum) {  // in-place exclusive
    if (threadIdx.x != 0 || blockIdx.x != 0) return;
    int acc = 0;
    for (int i = 0; i < NCHUNK; i++) { int v = csum[i]; csum[i] = acc; acc += v; }
}

__global__ void chunk_scan_kernel(const int* __restrict__ deg, const int* __restrict__ csum,
                                  int* __restrict__ rowptr, int* __restrict__ cursor) {
    __shared__ int sd[256];
    int t = threadIdx.x;
    int i = blockIdx.x * 256 + t;
    int v = (i < N_NODES) ? deg[i] : 0;
    sd[t] = v;
    for (int off = 1; off < 256; off <<= 1) {
        __syncthreads();
        int add = (t >= off) ? sd[t - off] : 0;
        __syncthreads();
        sd[t] += add;
    }
    __syncthreads();
    int excl = sd[t] - v + csum[blockIdx.x];
    if (i < N_NODES) { rowptr[i] = excl; cursor[i] = excl; }
    if (i == 0) rowptr[N_NODES] = ET;
}

__global__ void fill_kernel(const void* __restrict__ ei, int* __restrict__ cursor,
                            int* __restrict__ srcs, const int* __restrict__ flags) {
    int e = blockIdx.x * 256 + threadIdx.x;
    if (e >= ET) return;
    int s, d; edge_sd(ei, e, flags[1], s, d);
    int pos = atomicAdd(&cursor[d], 1);
    srcs[pos] = s;
}

// ---------------- per-layer kernels ----------------
// C[M x 128] = A[M x K] * W[K x 128]; blockDim=128, grid = M/RPB
template <int RPB>
__global__ void gemm_kernel(const void* __restrict__ A, const void* __restrict__ W,
                            float* __restrict__ C, int K, int a_internal,
                            const int* __restrict__ flags) {
    __shared__ float At[RPB * IN_F];
    int tid = threadIdx.x;
    int f32 = flags[0];
    int af32 = a_internal ? 1 : f32;
    long row0 = (long)blockIdx.x * RPB;
    if (af32) {
        const float* Af = (const float*)A;
        for (int i = tid; i < RPB * K; i += 128) At[i] = Af[row0 * K + i];
    } else {
        const unsigned short* Ab = (const unsigned short*)A;
        for (int i = tid; i < RPB * K; i += 128) At[i] = bf2f(Ab[row0 * K + i]);
    }
    __syncthreads();
    float acc[RPB];
#pragma unroll
    for (int r = 0; r < RPB; r++) acc[r] = 0.f;
    if (f32) {
        const float* Wf = (const float*)W;
        for (int k = 0; k < K; k++) {
            float w = Wf[k * G + tid];
#pragma unroll
            for (int r = 0; r < RPB; r++) acc[r] += At[r * K + k] * w;
        }
    } else {
        const unsigned short* Wb = (const unsigned short*)W;
        for (int k = 0; k < K; k++) {
            float w = bf2f(Wb[k * G + tid]);
#pragma unroll
            for (int r = 0; r < RPB; r++) acc[r] += At[r * K + k] * w;
        }
    }
#pragma unroll
    for (int r = 0; r < RPB; r++) C[(row0 + r) * G + tid] = acc[r];
}

// per-node attention terms: es = h.as, ed = h.ad ; one wave per node
__global__ void ead_kernel(const float* __restrict__ h, const void* __restrict__ aS,
                           const void* __restrict__ aD, float* __restrict__ es,
                           float* __restrict__ ed, const int* __restrict__ flags) {
    int n = blockIdx.x;
    int l = threadIdx.x;  // 64
    int f32 = flags[0];
    const float* hp = h + (size_t)n * G;
    float h0 = hp[l], h1 = hp[l + 64];
    float s = h0 * ldf(aS, l, f32) + h1 * ldf(aS, l + 64, f32);
    float d = h0 * ldf(aD, l, f32) + h1 * ldf(aD, l + 64, f32);
    for (int off = 32; off; off >>= 1) {
        s += __shfl_down(s, off);
        d += __shfl_down(d, off);
    }
    if (l == 0) { es[n] = s; ed[n] = d; }
}

// Fused GAT aggregate: one wave per dst node. Online softmax over incoming
// edge list (CSR), weighted gather of h[src], normalize, +bias, SELU.
// No float atomics; single coalesced 25.6 MB write.
__global__ __launch_bounds__(64) void gat_agg_kernel(
    const float* __restrict__ h, const int* __restrict__ rowptr,
    const int* __restrict__ srcs, const float* __restrict__ es,
    const float* __restrict__ edv, const void* __restrict__ bias,
    float* __restrict__ outbuf, const int* __restrict__ flags) {
    int d = blockIdx.x;
    int l = threadIdx.x;  // 64
    __shared__ float sp[CHUNK];
    __shared__ int ssrc[CHUNK];
    int start = rowptr[d], end = rowptr[d + 1];
    float edd = edv[d];
    float m = -INFINITY, den = 0.f;
    float acc0 = 0.f, acc1 = 0.f;
    for (int c0 = start; c0 < end; c0 += CHUNK) {
        int cn = min(end - c0, CHUNK);
        // phase A: logits -> LDS, chunk max
        float mc = -INFINITY;
        for (int i = l; i < cn; i += 64) {
            int s = srcs[c0 + i];
            ssrc[i] = s;
            float v = es[s] + edd;
            v = v >= 0.f ? v : 0.2f * v;  // LeakyReLU(0.2)
            sp[i] = v;
            mc = fmaxf(mc, v);
        }
        for (int off = 32; off; off >>= 1) mc = fmaxf(mc, __shfl_xor(mc, off));
        float mnew = fmaxf(m, mc);
        float scale = (den > 0.f) ? expf(m - mnew) : 0.f;
        __syncthreads();
        // phase B: exp -> LDS, chunk sum
        float lsum = 0.f;
        for (int i = l; i < cn; i += 64) {
            float p = expf(sp[i] - mnew);
            sp[i] = p;
            lsum += p;
        }
        for (int off = 32; off; off >>= 1) lsum += __shfl_xor(lsum, off);
        den = den * scale + lsum;
        acc0 *= scale; acc1 *= scale;
        __syncthreads();
        // phase C: weighted gather (sp/ssrc broadcast; h loads coalesced 256B)
        for (int i = 0; i < cn; i++) {
            float p = sp[i];
            const float* hp = h + (size_t)ssrc[i] * G;
            acc0 += p * hp[l];
            acc1 += p * hp[l + 64];
        }
        __syncthreads();
        m = mnew;
    }
    float inv = 1.f / (den + 1e-16f);
    int f32 = flags[0];
    float o0 = acc0 * inv + ldf(bias, l, f32);
    float o1 = acc1 * inv + ldf(bias, l + 64, f32);
    outbuf[(size_t)d * G + l]      = selu_f(o0);
    outbuf[(size_t)d * G + l + 64] = selu_f(o1);
}

// ---------------- pool + head ----------------
__global__ void pool_kernel(const float* __restrict__ h, const void* __restrict__ batch,
                            float* __restrict__ gsum, const int* __restrict__ flags) {
    int t = threadIdx.x;  // 128
    int i64 = flags[1];
    int i0 = blockIdx.x * 512;
    int i1 = min(N_NODES, i0 + 512);
    int cur = -1;
    float acc = 0.f;
    for (int i = i0; i < i1; i++) {
        int g = min(max(ldi(batch, i, i64), 0), NGRAPH - 1);
        if (g != cur) {
            if (cur >= 0) atomicAdd(&gsum[cur * G + t], acc);
            cur = g; acc = 0.f;
        }
        acc += h[(size_t)i * G + t];
    }
    if (cur >= 0) atomicAdd(&gsum[cur * G + t], acc);
}

__global__ void count_kernel(const void* __restrict__ batch, float* __restrict__ gcnt,
                             const int* __restrict__ flags) {
    int i = blockIdx.x * 256 + threadIdx.x;
    if (i < N_NODES) {
        int g = min(max(ldi(batch, i, flags[1]), 0), NGRAPH - 1);
        atomicAdd(&gcnt[g], 1.0f);
    }
}

// pooled -> selu -> lin1+selu -> lin2 -> log_softmax; OUTPUT FLOAT32
__global__ void head_kernel(const float* __restrict__ gsum, const float* __restrict__ gcnt,
                            const void* __restrict__ lw1, const void* __restrict__ lb1,
                            const void* __restrict__ lw2, const void* __restrict__ lb2,
                            float* __restrict__ out, const int* __restrict__ flags) {
    int g = blockIdx.x, t = threadIdx.x;  // 64
    int f32 = flags[0];
    __shared__ float z[G];
    __shared__ float z1[NHID];
    __shared__ float z2[2];
    float cnt = fmaxf(gcnt[g], 1.0f);
    z[t]      = selu_f(gsum[g * G + t] / cnt);
    z[t + 64] = selu_f(gsum[g * G + 64 + t] / cnt);
    __syncthreads();
    float a = ldf(lb1, t, f32);
    for (int k = 0; k < G; k++) a += z[k] * ldf(lw1, k * NHID + t, f32);
    z1[t] = selu_f(a);
    __syncthreads();
    if (t < 2) {
        float s = ldf(lb2, t, f32);
        for (int j = 0; j < NHID; j++) s += z1[j] * ldf(lw2, j * 2 + t, f32);
        z2[t] = s;
    }
    __syncthreads();
    if (t == 0) {
        float mx = fmaxf(z2[0], z2[1]);
        float l = mx + logf(expf(z2[0] - mx) + expf(z2[1] - mx));
        out[g * 2 + 0] = z2[0] - l;
        out[g * 2 + 1] = z2[1] - l;
    }
}

extern "C" void kernel_launch(void* const* d_in, const int* in_sizes, int n_in,
                              void* d_out, int out_size, void* d_ws, size_t ws_size,
                              hipStream_t stream) {
    const void* x    = d_in[0];
    const void* ei   = d_in[1];
    const void* batch= d_in[2];
    const void* W1   = d_in[3];
    const void* as1  = d_in[4];
    const void* ad1  = d_in[5];
    const void* b1   = d_in[6];
    const void* W2   = d_in[7];
    const void* as2  = d_in[8];
    const void* ad2  = d_in[9];
    const void* b2   = d_in[10];
    const void* lw1  = d_in[11];
    const void* lb1  = d_in[12];
    const void* lw2  = d_in[13];
    const void* lb2  = d_in[14];
    float* out = (float*)d_out;

    char* w = (char*)d_ws;
    size_t off = 0;
    auto alloc = [&](size_t bytes) -> char* {
        char* p = w + off;
        off = (off + bytes + 255) & ~(size_t)255;
        return p;
    };
    int*   flags  = (int*)alloc(256);
    float* hbuf   = (float*)alloc((size_t)N_NODES * G * 4);
    float* abuf   = (float*)alloc((size_t)N_NODES * G * 4);
    float* es     = (float*)alloc((size_t)N_NODES * 4);
    float* edv    = (float*)alloc((size_t)N_NODES * 4);
    int*   deg    = (int*)alloc((size_t)N_NODES * 4);
    int*   rowptr = (int*)alloc((size_t)(N_NODES + 1) * 4);
    int*   cursor = (int*)alloc((size_t)N_NODES * 4);
    int*   csum   = (int*)alloc((size_t)NCHUNK * 4);
    int*   srcs   = (int*)alloc((size_t)ET * 4);
    float* gsum   = (float*)alloc((size_t)NGRAPH * G * 4);
    float* gcnt   = (float*)alloc((size_t)NGRAPH * 4);

    unsigned eb = (ET + 255) / 256;

    detect_kernel<<<1, 64, 0, stream>>>(x, ei, flags);

    // ---------------- CSR build (once) ----------------
    zero_int_kernel<<<(N_NODES + 255) / 256, 256, 0, stream>>>(deg, N_NODES);
    deg_kernel<<<eb, 256, 0, stream>>>(ei, deg, flags);
    chunk_sum_kernel<<<NCHUNK, 256, 0, stream>>>(deg, csum);
    scan_csum_kernel<<<1, 64, 0, stream>>>(csum);
    chunk_scan_kernel<<<NCHUNK, 256, 0, stream>>>(deg, csum, rowptr, cursor);
    fill_kernel<<<eb, 256, 0, stream>>>(ei, cursor, srcs, flags);

    // ---------------- Layer 1 ----------------
    gemm_kernel<8><<<N_NODES / 8, 128, 0, stream>>>(x, W1, hbuf, IN_F, 0, flags);
    ead_kernel<<<N_NODES, 64, 0, stream>>>(hbuf, as1, ad1, es, edv, flags);
    gat_agg_kernel<<<N_NODES, 64, 0, stream>>>(hbuf, rowptr, srcs, es, edv, b1, abuf, flags);

    // ---------------- Layer 2 ----------------
    gemm_kernel<8><<<N_NODES / 8, 128, 0, stream>>>(abuf, W2, hbuf, G, 1, flags);
    ead_kernel<<<N_NODES, 64, 0, stream>>>(hbuf, as2, ad2, es, edv, flags);
    gat_agg_kernel<<<N_NODES, 64, 0, stream>>>(hbuf, rowptr, srcs, es, edv, b2, abuf, flags);

    // ---------------- Pool + head ----------------
    zero_float_kernel<<<(NGRAPH * G + 255) / 256, 256, 0, stream>>>(gsum, NGRAPH * G);
    zero_float_kernel<<<1, 256, 0, stream>>>(gcnt, NGRAPH);
    pool_kernel<<<(N_NODES + 511) / 512, 128, 0, stream>>>(abuf, batch, gsum, flags);
    count_kernel<<<(N_NODES + 255) / 256, 256, 0, stream>>>(batch, gcnt, flags);
    head_kernel<<<NGRAPH, 64, 0, stream>>>(gsum, gcnt, lw1, lb1, lw2, lb2, out, flags);
}

// Round 5
// 686.543 us; speedup vs baseline: 2.8423x; 1.7624x over previous
//
#include <hip/hip_runtime.h>
#include <hip/hip_bf16.h>
#include <math.h>

#define N_NODES 50000
#define N_EDGES 800000
#define ET (N_EDGES + N_NODES)   // edges + self loops
#define IN_F 256
#define G 128                    // 2*HID
#define NHID 64
#define NGRAPH 32
#define NCHUNK ((N_NODES + 255) / 256)   // 196
#define CHUNK 1024                        // edges per LDS softmax chunk

typedef __hip_bfloat16 bf16;

// ---------- dtype-agnostic loads (flags resolved at runtime, wave-uniform) ----------
__device__ __forceinline__ float bf2f(unsigned short u) {
    union { unsigned u; float f; } c; c.u = ((unsigned)u) << 16; return c.f;
}
__device__ __forceinline__ float ldf(const void* p, long i, int f32) {
    return f32 ? ((const float*)p)[i] : bf2f(((const unsigned short*)p)[i]);
}
__device__ __forceinline__ int ldi(const void* p, long i, int i64) {
    return i64 ? (int)((const long long*)p)[i] : ((const int*)p)[i];
}

__device__ __forceinline__ float selu_f(float x) {
    const float sc = 1.0507009873554805f, al = 1.6732632423543772f;
    return x > 0.f ? sc * x : sc * al * expm1f(x);
}

// flags[0]=1 -> float inputs are f32 (else bf16); flags[1]=1 -> ints are int64.
// Parallelized across one wave (was single-thread: ~2048 serialized HBM loads).
__global__ void detect_kernel(const void* x, const void* ei, int* flags) {
    int l = threadIdx.x;  // 64
    const unsigned* xu = (const unsigned*)x;
    const long NW = (long)N_NODES * IN_F / 2;
    long stride = NW / 1024;
    int sane = 0;
    for (int k = l; k < 1024; k += 64) {
        unsigned u = xu[(long)k * stride];
        unsigned e = (u >> 23) & 0xFF;
        if (u == 0u || (e >= 100 && e <= 140)) sane++;
    }
    const unsigned* wu = (const unsigned*)ei;
    int nz = 0;
    for (int k = l; k < 1024; k += 64) {
        long j = ((long)k * 1562) | 1;
        nz += (wu[j] != 0u);
    }
    for (int off = 32; off; off >>= 1) {
        sane += __shfl_xor(sane, off);
        nz   += __shfl_xor(nz, off);
    }
    if (l == 0) {
        flags[0] = (sane >= 512) ? 1 : 0;
        flags[1] = (nz < 16) ? 1 : 0;
    }
}

__global__ void zero_float_kernel(float* __restrict__ p, long n) {
    long i = (long)blockIdx.x * 256 + threadIdx.x;
    if (i < n) p[i] = 0.f;
}
__global__ void zero_int_kernel(int* __restrict__ p, long n) {
    long i = (long)blockIdx.x * 256 + threadIdx.x;
    if (i < n) p[i] = 0;
}

__device__ __forceinline__ void edge_sd(const void* __restrict__ ei, int e, int i64,
                                        int& s, int& d) {
    if (e < N_EDGES) {
        s = ldi(ei, e, i64);
        d = ldi(ei, (long)N_EDGES + e, i64);
        s = min(max(s, 0), N_NODES - 1);
        d = min(max(d, 0), N_NODES - 1);
    } else {
        s = d = e - N_EDGES;
    }
}

// ---------------- CSR build (once; graph is layer-invariant) ----------------
__global__ void deg_kernel(const void* __restrict__ ei, int* __restrict__ deg,
                           const int* __restrict__ flags) {
    int e = blockIdx.x * 256 + threadIdx.x;
    if (e >= ET) return;
    int s, d; edge_sd(ei, e, flags[1], s, d);
    atomicAdd(&deg[d], 1);
}

__global__ void chunk_sum_kernel(const int* __restrict__ deg, int* __restrict__ csum) {
    __shared__ int sd[256];
    int t = threadIdx.x;
    int i = blockIdx.x * 256 + t;
    sd[t] = (i < N_NODES) ? deg[i] : 0;
    __syncthreads();
    for (int off = 128; off; off >>= 1) {
        if (t < off) sd[t] += sd[t + off];
        __syncthreads();
    }
    if (t == 0) csum[blockIdx.x] = sd[0];
}

__global__ void scan_csum_kernel(int* __restrict__ csum) {  // in-place exclusive
    if (threadIdx.x != 0 || blockIdx.x != 0) return;
    int acc = 0;
    for (int i = 0; i < NCHUNK; i++) { int v = csum[i]; csum[i] = acc; acc += v; }
}

__global__ void chunk_scan_kernel(const int* __restrict__ deg, const int* __restrict__ csum,
                                  int* __restrict__ rowptr, int* __restrict__ cursor) {
    __shared__ int sd[256];
    int t = threadIdx.x;
    int i = blockIdx.x * 256 + t;
    int v = (i < N_NODES) ? deg[i] : 0;
    sd[t] = v;
    for (int off = 1; off < 256; off <<= 1) {
        __syncthreads();
        int add = (t >= off) ? sd[t - off] : 0;
        __syncthreads();
        sd[t] += add;
    }
    __syncthreads();
    int excl = sd[t] - v + csum[blockIdx.x];
    if (i < N_NODES) { rowptr[i] = excl; cursor[i] = excl; }
    if (i == 0) rowptr[N_NODES] = ET;
}

__global__ void fill_kernel(const void* __restrict__ ei, int* __restrict__ cursor,
                            int* __restrict__ srcs, const int* __restrict__ flags) {
    int e = blockIdx.x * 256 + threadIdx.x;
    if (e >= ET) return;
    int s, d; edge_sd(ei, e, flags[1], s, d);
    int pos = atomicAdd(&cursor[d], 1);
    srcs[pos] = s;
}

// ---------------- per-layer kernels ----------------
// C[M x 128] = A[M x K] * W[K x 128]; blockDim=128, grid = M/RPB
template <int RPB>
__global__ void gemm_kernel(const void* __restrict__ A, const void* __restrict__ W,
                            float* __restrict__ C, int K, int a_internal,
                            const int* __restrict__ flags) {
    __shared__ float At[RPB * IN_F];
    int tid = threadIdx.x;
    int f32 = flags[0];
    int af32 = a_internal ? 1 : f32;
    long row0 = (long)blockIdx.x * RPB;
    if (af32) {
        const float* Af = (const float*)A;
        for (int i = tid; i < RPB * K; i += 128) At[i] = Af[row0 * K + i];
    } else {
        const unsigned short* Ab = (const unsigned short*)A;
        for (int i = tid; i < RPB * K; i += 128) At[i] = bf2f(Ab[row0 * K + i]);
    }
    __syncthreads();
    float acc[RPB];
#pragma unroll
    for (int r = 0; r < RPB; r++) acc[r] = 0.f;
    if (f32) {
        const float* Wf = (const float*)W;
        for (int k = 0; k < K; k++) {
            float w = Wf[k * G + tid];
#pragma unroll
            for (int r = 0; r < RPB; r++) acc[r] += At[r * K + k] * w;
        }
    } else {
        const unsigned short* Wb = (const unsigned short*)W;
        for (int k = 0; k < K; k++) {
            float w = bf2f(Wb[k * G + tid]);
#pragma unroll
            for (int r = 0; r < RPB; r++) acc[r] += At[r * K + k] * w;
        }
    }
#pragma unroll
    for (int r = 0; r < RPB; r++) C[(row0 + r) * G + tid] = acc[r];
}

// per-node attention terms: es = h.as, ed = h.ad ; one wave per node
__global__ void ead_kernel(const float* __restrict__ h, const void* __restrict__ aS,
                           const void* __restrict__ aD, float* __restrict__ es,
                           float* __restrict__ ed, const int* __restrict__ flags) {
    int n = blockIdx.x;
    int l = threadIdx.x;  // 64
    int f32 = flags[0];
    const float* hp = h + (size_t)n * G;
    float h0 = hp[l], h1 = hp[l + 64];
    float s = h0 * ldf(aS, l, f32) + h1 * ldf(aS, l + 64, f32);
    float d = h0 * ldf(aD, l, f32) + h1 * ldf(aD, l + 64, f32);
    for (int off = 32; off; off >>= 1) {
        s += __shfl_down(s, off);
        d += __shfl_down(d, off);
    }
    if (l == 0) { es[n] = s; ed[n] = d; }
}

// Fused GAT aggregate: one wave per dst node. Online softmax over incoming
// edge list (CSR), weighted gather of h[src], normalize, +bias, SELU.
__global__ __launch_bounds__(64) void gat_agg_kernel(
    const float* __restrict__ h, const int* __restrict__ rowptr,
    const int* __restrict__ srcs, const float* __restrict__ es,
    const float* __restrict__ edv, const void* __restrict__ bias,
    float* __restrict__ outbuf, const int* __restrict__ flags) {
    int d = blockIdx.x;
    int l = threadIdx.x;  // 64
    __shared__ float sp[CHUNK];
    __shared__ int ssrc[CHUNK];
    int start = rowptr[d], end = rowptr[d + 1];
    float edd = edv[d];
    float m = -INFINITY, den = 0.f;
    float acc0 = 0.f, acc1 = 0.f;
    for (int c0 = start; c0 < end; c0 += CHUNK) {
        int cn = min(end - c0, CHUNK);
        float mc = -INFINITY;
        for (int i = l; i < cn; i += 64) {
            int s = srcs[c0 + i];
            ssrc[i] = s;
            float v = es[s] + edd;
            v = v >= 0.f ? v : 0.2f * v;  // LeakyReLU(0.2)
            sp[i] = v;
            mc = fmaxf(mc, v);
        }
        for (int off = 32; off; off >>= 1) mc = fmaxf(mc, __shfl_xor(mc, off));
        float mnew = fmaxf(m, mc);
        float scale = (den > 0.f) ? expf(m - mnew) : 0.f;
        __syncthreads();
        float lsum = 0.f;
        for (int i = l; i < cn; i += 64) {
            float p = expf(sp[i] - mnew);
            sp[i] = p;
            lsum += p;
        }
        for (int off = 32; off; off >>= 1) lsum += __shfl_xor(lsum, off);
        den = den * scale + lsum;
        acc0 *= scale; acc1 *= scale;
        __syncthreads();
        for (int i = 0; i < cn; i++) {
            float p = sp[i];
            const float* hp = h + (size_t)ssrc[i] * G;
            acc0 += p * hp[l];
            acc1 += p * hp[l + 64];
        }
        __syncthreads();
        m = mnew;
    }
    float inv = 1.f / (den + 1e-16f);
    int f32 = flags[0];
    float o0 = acc0 * inv + ldf(bias, l, f32);
    float o1 = acc1 * inv + ldf(bias, l + 64, f32);
    outbuf[(size_t)d * G + l]      = selu_f(o0);
    outbuf[(size_t)d * G + l + 64] = selu_f(o1);
}

// ---------------- pool + head ----------------
__global__ void pool_kernel(const float* __restrict__ h, const void* __restrict__ batch,
                            float* __restrict__ gsum, const int* __restrict__ flags) {
    int t = threadIdx.x;  // 128
    int i64 = flags[1];
    int i0 = blockIdx.x * 512;
    int i1 = min(N_NODES, i0 + 512);
    int cur = -1;
    float acc = 0.f;
    for (int i = i0; i < i1; i++) {
        int g = min(max(ldi(batch, i, i64), 0), NGRAPH - 1);
        if (g != cur) {
            if (cur >= 0) atomicAdd(&gsum[cur * G + t], acc);
            cur = g; acc = 0.f;
        }
        acc += h[(size_t)i * G + t];
    }
    if (cur >= 0) atomicAdd(&gsum[cur * G + t], acc);
}

// LDS histogram first: 32 LDS atomics/thread-group, then <=32 global atomics
// per block (was: 50000 device-scope atomics on 32 addresses -> 328 us).
__global__ void count_kernel(const void* __restrict__ batch, float* __restrict__ gcnt,
                             const int* __restrict__ flags) {
    __shared__ int hist[NGRAPH];
    int t = threadIdx.x;
    if (t < NGRAPH) hist[t] = 0;
    __syncthreads();
    int i = blockIdx.x * 256 + t;
    if (i < N_NODES) {
        int g = min(max(ldi(batch, i, flags[1]), 0), NGRAPH - 1);
        atomicAdd(&hist[g], 1);
    }
    __syncthreads();
    if (t < NGRAPH && hist[t] != 0) atomicAdd(&gcnt[t], (float)hist[t]);
}

// pooled -> selu -> lin1+selu -> lin2 -> log_softmax; OUTPUT FLOAT32
__global__ void head_kernel(const float* __restrict__ gsum, const float* __restrict__ gcnt,
                            const void* __restrict__ lw1, const void* __restrict__ lb1,
                            const void* __restrict__ lw2, const void* __restrict__ lb2,
                            float* __restrict__ out, const int* __restrict__ flags) {
    int g = blockIdx.x, t = threadIdx.x;  // 64
    int f32 = flags[0];
    __shared__ float z[G];
    __shared__ float z1[NHID];
    __shared__ float z2[2];
    float cnt = fmaxf(gcnt[g], 1.0f);
    z[t]      = selu_f(gsum[g * G + t] / cnt);
    z[t + 64] = selu_f(gsum[g * G + 64 + t] / cnt);
    __syncthreads();
    float a = ldf(lb1, t, f32);
    for (int k = 0; k < G; k++) a += z[k] * ldf(lw1, k * NHID + t, f32);
    z1[t] = selu_f(a);
    __syncthreads();
    if (t < 2) {
        float s = ldf(lb2, t, f32);
        for (int j = 0; j < NHID; j++) s += z1[j] * ldf(lw2, j * 2 + t, f32);
        z2[t] = s;
    }
    __syncthreads();
    if (t == 0) {
        float mx = fmaxf(z2[0], z2[1]);
        float l = mx + logf(expf(z2[0] - mx) + expf(z2[1] - mx));
        out[g * 2 + 0] = z2[0] - l;
        out[g * 2 + 1] = z2[1] - l;
    }
}

extern "C" void kernel_launch(void* const* d_in, const int* in_sizes, int n_in,
                              void* d_out, int out_size, void* d_ws, size_t ws_size,
                              hipStream_t stream) {
    const void* x    = d_in[0];
    const void* ei   = d_in[1];
    const void* batch= d_in[2];
    const void* W1   = d_in[3];
    const void* as1  = d_in[4];
    const void* ad1  = d_in[5];
    const void* b1   = d_in[6];
    const void* W2   = d_in[7];
    const void* as2  = d_in[8];
    const void* ad2  = d_in[9];
    const void* b2   = d_in[10];
    const void* lw1  = d_in[11];
    const void* lb1  = d_in[12];
    const void* lw2  = d_in[13];
    const void* lb2  = d_in[14];
    float* out = (float*)d_out;

    char* w = (char*)d_ws;
    size_t off = 0;
    auto alloc = [&](size_t bytes) -> char* {
        char* p = w + off;
        off = (off + bytes + 255) & ~(size_t)255;
        return p;
    };
    int*   flags  = (int*)alloc(256);
    float* hbuf   = (float*)alloc((size_t)N_NODES * G * 4);
    float* abuf   = (float*)alloc((size_t)N_NODES * G * 4);
    float* es     = (float*)alloc((size_t)N_NODES * 4);
    float* edv    = (float*)alloc((size_t)N_NODES * 4);
    int*   deg    = (int*)alloc((size_t)N_NODES * 4);
    int*   rowptr = (int*)alloc((size_t)(N_NODES + 1) * 4);
    int*   cursor = (int*)alloc((size_t)N_NODES * 4);
    int*   csum   = (int*)alloc((size_t)NCHUNK * 4);
    int*   srcs   = (int*)alloc((size_t)ET * 4);
    float* gsum   = (float*)alloc((size_t)NGRAPH * G * 4);
    float* gcnt   = (float*)alloc((size_t)NGRAPH * 4);

    unsigned eb = (ET + 255) / 256;

    detect_kernel<<<1, 64, 0, stream>>>(x, ei, flags);

    // ---------------- CSR build (once) ----------------
    zero_int_kernel<<<(N_NODES + 255) / 256, 256, 0, stream>>>(deg, N_NODES);
    deg_kernel<<<eb, 256, 0, stream>>>(ei, deg, flags);
    chunk_sum_kernel<<<NCHUNK, 256, 0, stream>>>(deg, csum);
    scan_csum_kernel<<<1, 64, 0, stream>>>(csum);
    chunk_scan_kernel<<<NCHUNK, 256, 0, stream>>>(deg, csum, rowptr, cursor);
    fill_kernel<<<eb, 256, 0, stream>>>(ei, cursor, srcs, flags);

    // ---------------- Layer 1 ----------------
    gemm_kernel<8><<<N_NODES / 8, 128, 0, stream>>>(x, W1, hbuf, IN_F, 0, flags);
    ead_kernel<<<N_NODES, 64, 0, stream>>>(hbuf, as1, ad1, es, edv, flags);
    gat_agg_kernel<<<N_NODES, 64, 0, stream>>>(hbuf, rowptr, srcs, es, edv, b1, abuf, flags);

    // ---------------- Layer 2 ----------------
    gemm_kernel<8><<<N_NODES / 8, 128, 0, stream>>>(abuf, W2, hbuf, G, 1, flags);
    ead_kernel<<<N_NODES, 64, 0, stream>>>(hbuf, as2, ad2, es, edv, flags);
    gat_agg_kernel<<<N_NODES, 64, 0, stream>>>(hbuf, rowptr, srcs, es, edv, b2, abuf, flags);

    // ---------------- Pool + head ----------------
    zero_float_kernel<<<(NGRAPH * G + 255) / 256, 256, 0, stream>>>(gsum, NGRAPH * G);
    zero_float_kernel<<<1, 256, 0, stream>>>(gcnt, NGRAPH);
    pool_kernel<<<(N_NODES + 511) / 512, 128, 0, stream>>>(abuf, batch, gsum, flags);
    count_kernel<<<(N_NODES + 255) / 256, 256, 0, stream>>>(batch, gcnt, flags);
    head_kernel<<<NGRAPH, 64, 0, stream>>>(gsum, gcnt, lw1, lb1, lw2, lb2, out, flags);
}

// Round 6
// 548.933 us; speedup vs baseline: 3.5548x; 1.2507x over previous
//
#include <hip/hip_runtime.h>
#include <hip/hip_bf16.h>
#include <math.h>

#define N_NODES 50000
#define N_EDGES 800000
#define ET (N_EDGES + N_NODES)   // edges + self loops
#define IN_F 256
#define G 128                    // 2*HID
#define NHID 64
#define NGRAPH 32
#define NCHUNK ((N_NODES + 255) / 256)   // 196
#define CHUNK 1024                        // edges per LDS softmax chunk
#define POOL_NODES 64                     // nodes per pool block (was 512: 2% occupancy)

typedef __hip_bfloat16 bf16;

// ---------- dtype-agnostic loads (flags resolved at runtime, wave-uniform) ----------
__device__ __forceinline__ float bf2f(unsigned short u) {
    union { unsigned u; float f; } c; c.u = ((unsigned)u) << 16; return c.f;
}
__device__ __forceinline__ float ldf(const void* p, long i, int f32) {
    return f32 ? ((const float*)p)[i] : bf2f(((const unsigned short*)p)[i]);
}
__device__ __forceinline__ int ldi(const void* p, long i, int i64) {
    return i64 ? (int)((const long long*)p)[i] : ((const int*)p)[i];
}

__device__ __forceinline__ float selu_f(float x) {
    const float sc = 1.0507009873554805f, al = 1.6732632423543772f;
    return x > 0.f ? sc * x : sc * al * expm1f(x);
}

// flags[0]=1 -> float inputs are f32 (else bf16); flags[1]=1 -> ints are int64.
__global__ void detect_kernel(const void* x, const void* ei, int* flags) {
    int l = threadIdx.x;  // 64
    const unsigned* xu = (const unsigned*)x;
    const long NW = (long)N_NODES * IN_F / 2;
    long stride = NW / 1024;
    int sane = 0;
    for (int k = l; k < 1024; k += 64) {
        unsigned u = xu[(long)k * stride];
        unsigned e = (u >> 23) & 0xFF;
        if (u == 0u || (e >= 100 && e <= 140)) sane++;
    }
    const unsigned* wu = (const unsigned*)ei;
    int nz = 0;
    for (int k = l; k < 1024; k += 64) {
        long j = ((long)k * 1562) | 1;
        nz += (wu[j] != 0u);
    }
    for (int off = 32; off; off >>= 1) {
        sane += __shfl_xor(sane, off);
        nz   += __shfl_xor(nz, off);
    }
    if (l == 0) {
        flags[0] = (sane >= 512) ? 1 : 0;
        flags[1] = (nz < 16) ? 1 : 0;
    }
}

__global__ void zero_float_kernel(float* __restrict__ p, long n) {
    long i = (long)blockIdx.x * 256 + threadIdx.x;
    if (i < n) p[i] = 0.f;
}
__global__ void zero_int_kernel(int* __restrict__ p, long n) {
    long i = (long)blockIdx.x * 256 + threadIdx.x;
    if (i < n) p[i] = 0;
}

__device__ __forceinline__ void edge_sd(const void* __restrict__ ei, int e, int i64,
                                        int& s, int& d) {
    if (e < N_EDGES) {
        s = ldi(ei, e, i64);
        d = ldi(ei, (long)N_EDGES + e, i64);
        s = min(max(s, 0), N_NODES - 1);
        d = min(max(d, 0), N_NODES - 1);
    } else {
        s = d = e - N_EDGES;
    }
}

// ---------------- CSR build (once; graph is layer-invariant) ----------------
__global__ void deg_kernel(const void* __restrict__ ei, int* __restrict__ deg,
                           const int* __restrict__ flags) {
    int e = blockIdx.x * 256 + threadIdx.x;
    if (e >= ET) return;
    int s, d; edge_sd(ei, e, flags[1], s, d);
    atomicAdd(&deg[d], 1);
}

__global__ void chunk_sum_kernel(const int* __restrict__ deg, int* __restrict__ csum) {
    __shared__ int sd[256];
    int t = threadIdx.x;
    int i = blockIdx.x * 256 + t;
    sd[t] = (i < N_NODES) ? deg[i] : 0;
    __syncthreads();
    for (int off = 128; off; off >>= 1) {
        if (t < off) sd[t] += sd[t + off];
        __syncthreads();
    }
    if (t == 0) csum[blockIdx.x] = sd[0];
}

__global__ void scan_csum_kernel(int* __restrict__ csum) {  // in-place exclusive
    if (threadIdx.x != 0 || blockIdx.x != 0) return;
    int acc = 0;
    for (int i = 0; i < NCHUNK; i++) { int v = csum[i]; csum[i] = acc; acc += v; }
}

__global__ void chunk_scan_kernel(const int* __restrict__ deg, const int* __restrict__ csum,
                                  int* __restrict__ rowptr, int* __restrict__ cursor) {
    __shared__ int sd[256];
    int t = threadIdx.x;
    int i = blockIdx.x * 256 + t;
    int v = (i < N_NODES) ? deg[i] : 0;
    sd[t] = v;
    for (int off = 1; off < 256; off <<= 1) {
        __syncthreads();
        int add = (t >= off) ? sd[t - off] : 0;
        __syncthreads();
        sd[t] += add;
    }
    __syncthreads();
    int excl = sd[t] - v + csum[blockIdx.x];
    if (i < N_NODES) { rowptr[i] = excl; cursor[i] = excl; }
    if (i == 0) rowptr[N_NODES] = ET;
}

__global__ void fill_kernel(const void* __restrict__ ei, int* __restrict__ cursor,
                            int* __restrict__ srcs, const int* __restrict__ flags) {
    int e = blockIdx.x * 256 + threadIdx.x;
    if (e >= ET) return;
    int s, d; edge_sd(ei, e, flags[1], s, d);
    int pos = atomicAdd(&cursor[d], 1);
    srcs[pos] = s;
}

// ---------------- per-layer kernels ----------------
// C[M x 128] = A[M x K] * W[K x 128]; blockDim=128, grid = M/RPB
template <int RPB>
__global__ void gemm_kernel(const void* __restrict__ A, const void* __restrict__ W,
                            float* __restrict__ C, int K, int a_internal,
                            const int* __restrict__ flags) {
    __shared__ float At[RPB * IN_F];
    int tid = threadIdx.x;
    int f32 = flags[0];
    int af32 = a_internal ? 1 : f32;
    long row0 = (long)blockIdx.x * RPB;
    if (af32) {
        const float* Af = (const float*)A;
        for (int i = tid; i < RPB * K; i += 128) At[i] = Af[row0 * K + i];
    } else {
        const unsigned short* Ab = (const unsigned short*)A;
        for (int i = tid; i < RPB * K; i += 128) At[i] = bf2f(Ab[row0 * K + i]);
    }
    __syncthreads();
    float acc[RPB];
#pragma unroll
    for (int r = 0; r < RPB; r++) acc[r] = 0.f;
    if (f32) {
        const float* Wf = (const float*)W;
        for (int k = 0; k < K; k++) {
            float w = Wf[k * G + tid];
#pragma unroll
            for (int r = 0; r < RPB; r++) acc[r] += At[r * K + k] * w;
        }
    } else {
        const unsigned short* Wb = (const unsigned short*)W;
        for (int k = 0; k < K; k++) {
            float w = bf2f(Wb[k * G + tid]);
#pragma unroll
            for (int r = 0; r < RPB; r++) acc[r] += At[r * K + k] * w;
        }
    }
#pragma unroll
    for (int r = 0; r < RPB; r++) C[(row0 + r) * G + tid] = acc[r];
}

// per-node attention terms: es = h.as, ed = h.ad ; one wave per node
__global__ void ead_kernel(const float* __restrict__ h, const void* __restrict__ aS,
                           const void* __restrict__ aD, float* __restrict__ es,
                           float* __restrict__ ed, const int* __restrict__ flags) {
    int n = blockIdx.x;
    int l = threadIdx.x;  // 64
    int f32 = flags[0];
    const float* hp = h + (size_t)n * G;
    float h0 = hp[l], h1 = hp[l + 64];
    float s = h0 * ldf(aS, l, f32) + h1 * ldf(aS, l + 64, f32);
    float d = h0 * ldf(aD, l, f32) + h1 * ldf(aD, l + 64, f32);
    for (int off = 32; off; off >>= 1) {
        s += __shfl_down(s, off);
        d += __shfl_down(d, off);
    }
    if (l == 0) { es[n] = s; ed[n] = d; }
}

// Fused GAT aggregate: one wave per dst node. Online softmax over incoming
// edge list (CSR), weighted gather of h[src], normalize, +bias, SELU.
__global__ __launch_bounds__(64) void gat_agg_kernel(
    const float* __restrict__ h, const int* __restrict__ rowptr,
    const int* __restrict__ srcs, const float* __restrict__ es,
    const float* __restrict__ edv, const void* __restrict__ bias,
    float* __restrict__ outbuf, const int* __restrict__ flags) {
    int d = blockIdx.x;
    int l = threadIdx.x;  // 64
    __shared__ float sp[CHUNK];
    __shared__ int ssrc[CHUNK];
    int start = rowptr[d], end = rowptr[d + 1];
    float edd = edv[d];
    float m = -INFINITY, den = 0.f;
    float acc0 = 0.f, acc1 = 0.f;
    for (int c0 = start; c0 < end; c0 += CHUNK) {
        int cn = min(end - c0, CHUNK);
        float mc = -INFINITY;
        for (int i = l; i < cn; i += 64) {
            int s = srcs[c0 + i];
            ssrc[i] = s;
            float v = es[s] + edd;
            v = v >= 0.f ? v : 0.2f * v;  // LeakyReLU(0.2)
            sp[i] = v;
            mc = fmaxf(mc, v);
        }
        for (int off = 32; off; off >>= 1) mc = fmaxf(mc, __shfl_xor(mc, off));
        float mnew = fmaxf(m, mc);
        float scale = (den > 0.f) ? expf(m - mnew) : 0.f;
        __syncthreads();
        float lsum = 0.f;
        for (int i = l; i < cn; i += 64) {
            float p = expf(sp[i] - mnew);
            sp[i] = p;
            lsum += p;
        }
        for (int off = 32; off; off >>= 1) lsum += __shfl_xor(lsum, off);
        den = den * scale + lsum;
        acc0 *= scale; acc1 *= scale;
        __syncthreads();
        for (int i = 0; i < cn; i++) {
            float p = sp[i];
            const float* hp = h + (size_t)ssrc[i] * G;
            acc0 += p * hp[l];
            acc1 += p * hp[l + 64];
        }
        __syncthreads();
        m = mnew;
    }
    float inv = 1.f / (den + 1e-16f);
    int f32 = flags[0];
    float o0 = acc0 * inv + ldf(bias, l, f32);
    float o1 = acc1 * inv + ldf(bias, l + 64, f32);
    outbuf[(size_t)d * G + l]      = selu_f(o0);
    outbuf[(size_t)d * G + l + 64] = selu_f(o1);
}

// ---------------- pool + head ----------------
// 64 nodes/block -> 782 blocks (was 512/block -> 98 blocks, 2% occupancy,
// latency-bound at 83 GB/s). Run-length flush keeps atomics ~25/address.
__global__ void pool_kernel(const float* __restrict__ h, const void* __restrict__ batch,
                            float* __restrict__ gsum, const int* __restrict__ flags) {
    int t = threadIdx.x;  // 128
    int i64 = flags[1];
    int i0 = blockIdx.x * POOL_NODES;
    int i1 = min(N_NODES, i0 + POOL_NODES);
    int cur = -1;
    float acc = 0.f;
    for (int i = i0; i < i1; i++) {
        int g = min(max(ldi(batch, i, i64), 0), NGRAPH - 1);
        if (g != cur) {
            if (cur >= 0) atomicAdd(&gsum[cur * G + t], acc);
            cur = g; acc = 0.f;
        }
        acc += h[(size_t)i * G + t];
    }
    if (cur >= 0) atomicAdd(&gsum[cur * G + t], acc);
}

// LDS histogram, then <=32 global atomics per block.
__global__ void count_kernel(const void* __restrict__ batch, float* __restrict__ gcnt,
                             const int* __restrict__ flags) {
    __shared__ int hist[NGRAPH];
    int t = threadIdx.x;
    if (t < NGRAPH) hist[t] = 0;
    __syncthreads();
    int i = blockIdx.x * 256 + t;
    if (i < N_NODES) {
        int g = min(max(ldi(batch, i, flags[1]), 0), NGRAPH - 1);
        atomicAdd(&hist[g], 1);
    }
    __syncthreads();
    if (t < NGRAPH && hist[t] != 0) atomicAdd(&gcnt[t], (float)hist[t]);
}

// pooled -> selu -> lin1+selu -> lin2 -> log_softmax; OUTPUT FLOAT32
__global__ void head_kernel(const float* __restrict__ gsum, const float* __restrict__ gcnt,
                            const void* __restrict__ lw1, const void* __restrict__ lb1,
                            const void* __restrict__ lw2, const void* __restrict__ lb2,
                            float* __restrict__ out, const int* __restrict__ flags) {
    int g = blockIdx.x, t = threadIdx.x;  // 64
    int f32 = flags[0];
    __shared__ float z[G];
    __shared__ float z1[NHID];
    __shared__ float z2[2];
    float cnt = fmaxf(gcnt[g], 1.0f);
    z[t]      = selu_f(gsum[g * G + t] / cnt);
    z[t + 64] = selu_f(gsum[g * G + 64 + t] / cnt);
    __syncthreads();
    float a = ldf(lb1, t, f32);
    for (int k = 0; k < G; k++) a += z[k] * ldf(lw1, k * NHID + t, f32);
    z1[t] = selu_f(a);
    __syncthreads();
    if (t < 2) {
        float s = ldf(lb2, t, f32);
        for (int j = 0; j < NHID; j++) s += z1[j] * ldf(lw2, j * 2 + t, f32);
        z2[t] = s;
    }
    __syncthreads();
    if (t == 0) {
        float mx = fmaxf(z2[0], z2[1]);
        float l = mx + logf(expf(z2[0] - mx) + expf(z2[1] - mx));
        out[g * 2 + 0] = z2[0] - l;
        out[g * 2 + 1] = z2[1] - l;
    }
}

extern "C" void kernel_launch(void* const* d_in, const int* in_sizes, int n_in,
                              void* d_out, int out_size, void* d_ws, size_t ws_size,
                              hipStream_t stream) {
    const void* x    = d_in[0];
    const void* ei   = d_in[1];
    const void* batch= d_in[2];
    const void* W1   = d_in[3];
    const void* as1  = d_in[4];
    const void* ad1  = d_in[5];
    const void* b1   = d_in[6];
    const void* W2   = d_in[7];
    const void* as2  = d_in[8];
    const void* ad2  = d_in[9];
    const void* b2   = d_in[10];
    const void* lw1  = d_in[11];
    const void* lb1  = d_in[12];
    const void* lw2  = d_in[13];
    const void* lb2  = d_in[14];
    float* out = (float*)d_out;

    char* w = (char*)d_ws;
    size_t off = 0;
    auto alloc = [&](size_t bytes) -> char* {
        char* p = w + off;
        off = (off + bytes + 255) & ~(size_t)255;
        return p;
    };
    int*   flags  = (int*)alloc(256);
    float* hbuf   = (float*)alloc((size_t)N_NODES * G * 4);
    float* abuf   = (float*)alloc((size_t)N_NODES * G * 4);
    float* es     = (float*)alloc((size_t)N_NODES * 4);
    float* edv    = (float*)alloc((size_t)N_NODES * 4);
    int*   deg    = (int*)alloc((size_t)N_NODES * 4);
    int*   rowptr = (int*)alloc((size_t)(N_NODES + 1) * 4);
    int*   cursor = (int*)alloc((size_t)N_NODES * 4);
    int*   csum   = (int*)alloc((size_t)NCHUNK * 4);
    int*   srcs   = (int*)alloc((size_t)ET * 4);
    float* gsum   = (float*)alloc((size_t)NGRAPH * G * 4);
    float* gcnt   = (float*)alloc((size_t)NGRAPH * 4);

    unsigned eb = (ET + 255) / 256;

    detect_kernel<<<1, 64, 0, stream>>>(x, ei, flags);

    // ---------------- CSR build (once) ----------------
    zero_int_kernel<<<(N_NODES + 255) / 256, 256, 0, stream>>>(deg, N_NODES);
    deg_kernel<<<eb, 256, 0, stream>>>(ei, deg, flags);
    chunk_sum_kernel<<<NCHUNK, 256, 0, stream>>>(deg, csum);
    scan_csum_kernel<<<1, 64, 0, stream>>>(csum);
    chunk_scan_kernel<<<NCHUNK, 256, 0, stream>>>(deg, csum, rowptr, cursor);
    fill_kernel<<<eb, 256, 0, stream>>>(ei, cursor, srcs, flags);

    // ---------------- Layer 1 ----------------
    gemm_kernel<8><<<N_NODES / 8, 128, 0, stream>>>(x, W1, hbuf, IN_F, 0, flags);
    ead_kernel<<<N_NODES, 64, 0, stream>>>(hbuf, as1, ad1, es, edv, flags);
    gat_agg_kernel<<<N_NODES, 64, 0, stream>>>(hbuf, rowptr, srcs, es, edv, b1, abuf, flags);

    // ---------------- Layer 2 ----------------
    gemm_kernel<8><<<N_NODES / 8, 128, 0, stream>>>(abuf, W2, hbuf, G, 1, flags);
    ead_kernel<<<N_NODES, 64, 0, stream>>>(hbuf, as2, ad2, es, edv, flags);
    gat_agg_kernel<<<N_NODES, 64, 0, stream>>>(hbuf, rowptr, srcs, es, edv, b2, abuf, flags);

    // ---------------- Pool + head ----------------
    zero_float_kernel<<<(NGRAPH * G + 255) / 256, 256, 0, stream>>>(gsum, NGRAPH * G);
    zero_float_kernel<<<1, 256, 0, stream>>>(gcnt, NGRAPH);
    pool_kernel<<<(N_NODES + POOL_NODES - 1) / POOL_NODES, 128, 0, stream>>>(abuf, batch, gsum, flags);
    count_kernel<<<(N_NODES + 255) / 256, 256, 0, stream>>>(batch, gcnt, flags);
    head_kernel<<<NGRAPH, 64, 0, stream>>>(gsum, gcnt, lw1, lb1, lw2, lb2, out, flags);
}

// Round 7
// 520.693 us; speedup vs baseline: 3.7476x; 1.0542x over previous
//
#include <hip/hip_runtime.h>
#include <hip/hip_bf16.h>
#include <math.h>

#define N_NODES 50000
#define N_EDGES 800000
#define ET (N_EDGES + N_NODES)   // edges + self loops
#define IN_F 256
#define G 128                    // 2*HID
#define NHID 64
#define NGRAPH 32
#define NCHUNK ((N_NODES + 255) / 256)   // 196
#define CHUNK 1024                        // edges per LDS softmax chunk
#define POOL_NODES 64

typedef __hip_bfloat16 bf16;
typedef unsigned short ushort;
typedef __attribute__((ext_vector_type(8))) short short8;
typedef __attribute__((ext_vector_type(4))) float f32x4;

// ---------- dtype-agnostic loads (flags resolved at runtime, wave-uniform) ----------
__device__ __forceinline__ float bf2f(ushort u) {
    union { unsigned u; float f; } c; c.u = ((unsigned)u) << 16; return c.f;
}
// round-to-nearest-even f32 -> bf16 (finite inputs)
__device__ __forceinline__ ushort f2bf(float f) {
    unsigned u = __float_as_uint(f);
    u += 0x7FFFu + ((u >> 16) & 1u);
    return (ushort)(u >> 16);
}
__device__ __forceinline__ float ldf(const void* p, long i, int f32) {
    return f32 ? ((const float*)p)[i] : bf2f(((const ushort*)p)[i]);
}
__device__ __forceinline__ int ldi(const void* p, long i, int i64) {
    return i64 ? (int)((const long long*)p)[i] : ((const int*)p)[i];
}

__device__ __forceinline__ float selu_f(float x) {
    const float sc = 1.0507009873554805f, al = 1.6732632423543772f;
    return x > 0.f ? sc * x : sc * al * expm1f(x);
}

// flags[0]=1 -> float inputs are f32 (else bf16); flags[1]=1 -> ints are int64.
__global__ void detect_kernel(const void* x, const void* ei, int* flags) {
    int l = threadIdx.x;  // 64
    const unsigned* xu = (const unsigned*)x;
    const long NW = (long)N_NODES * IN_F / 2;
    long stride = NW / 1024;
    int sane = 0;
    for (int k = l; k < 1024; k += 64) {
        unsigned u = xu[(long)k * stride];
        unsigned e = (u >> 23) & 0xFF;
        if (u == 0u || (e >= 100 && e <= 140)) sane++;
    }
    const unsigned* wu = (const unsigned*)ei;
    int nz = 0;
    for (int k = l; k < 1024; k += 64) {
        long j = ((long)k * 1562) | 1;
        nz += (wu[j] != 0u);
    }
    for (int off = 32; off; off >>= 1) {
        sane += __shfl_xor(sane, off);
        nz   += __shfl_xor(nz, off);
    }
    if (l == 0) {
        flags[0] = (sane >= 512) ? 1 : 0;
        flags[1] = (nz < 16) ? 1 : 0;
    }
}

__global__ void zero_float_kernel(float* __restrict__ p, long n) {
    long i = (long)blockIdx.x * 256 + threadIdx.x;
    if (i < n) p[i] = 0.f;
}
__global__ void zero_int_kernel(int* __restrict__ p, long n) {
    long i = (long)blockIdx.x * 256 + threadIdx.x;
    if (i < n) p[i] = 0;
}

__device__ __forceinline__ void edge_sd(const void* __restrict__ ei, int e, int i64,
                                        int& s, int& d) {
    if (e < N_EDGES) {
        s = ldi(ei, e, i64);
        d = ldi(ei, (long)N_EDGES + e, i64);
        s = min(max(s, 0), N_NODES - 1);
        d = min(max(d, 0), N_NODES - 1);
    } else {
        s = d = e - N_EDGES;
    }
}

// ---------------- CSR build (once; graph is layer-invariant) ----------------
__global__ void deg_kernel(const void* __restrict__ ei, int* __restrict__ deg,
                           const int* __restrict__ flags) {
    int e = blockIdx.x * 256 + threadIdx.x;
    if (e >= ET) return;
    int s, d; edge_sd(ei, e, flags[1], s, d);
    atomicAdd(&deg[d], 1);
}

__global__ void chunk_sum_kernel(const int* __restrict__ deg, int* __restrict__ csum) {
    __shared__ int sd[256];
    int t = threadIdx.x;
    int i = blockIdx.x * 256 + t;
    sd[t] = (i < N_NODES) ? deg[i] : 0;
    __syncthreads();
    for (int off = 128; off; off >>= 1) {
        if (t < off) sd[t] += sd[t + off];
        __syncthreads();
    }
    if (t == 0) csum[blockIdx.x] = sd[0];
}

__global__ void scan_csum_kernel(int* __restrict__ csum) {  // in-place exclusive
    if (threadIdx.x != 0 || blockIdx.x != 0) return;
    int acc = 0;
    for (int i = 0; i < NCHUNK; i++) { int v = csum[i]; csum[i] = acc; acc += v; }
}

__global__ void chunk_scan_kernel(const int* __restrict__ deg, const int* __restrict__ csum,
                                  int* __restrict__ rowptr, int* __restrict__ cursor) {
    __shared__ int sd[256];
    int t = threadIdx.x;
    int i = blockIdx.x * 256 + t;
    int v = (i < N_NODES) ? deg[i] : 0;
    sd[t] = v;
    for (int off = 1; off < 256; off <<= 1) {
        __syncthreads();
        int add = (t >= off) ? sd[t - off] : 0;
        __syncthreads();
        sd[t] += add;
    }
    __syncthreads();
    int excl = sd[t] - v + csum[blockIdx.x];
    if (i < N_NODES) { rowptr[i] = excl; cursor[i] = excl; }
    if (i == 0) rowptr[N_NODES] = ET;
}

__global__ void fill_kernel(const void* __restrict__ ei, int* __restrict__ cursor,
                            int* __restrict__ srcs, const int* __restrict__ flags) {
    int e = blockIdx.x * 256 + threadIdx.x;
    if (e >= ET) return;
    int s, d; edge_sd(ei, e, flags[1], s, d);
    int pos = atomicAdd(&cursor[d], 1);
    srcs[pos] = s;
}

// ---------------- GEMM: MFMA split-bf16 (hi+lo), f32-accurate ----------------
// Transpose W[K][128] -> Wt_hi/Wt_lo[n][k] bf16 (once per layer; L2-resident).
__global__ void wt_kernel(const void* __restrict__ W, ushort* __restrict__ wt_hi,
                          ushort* __restrict__ wt_lo, int K, const int* __restrict__ flags) {
    int i = blockIdx.x * 256 + threadIdx.x;
    if (i >= K * G) return;
    int k = i >> 7, n = i & (G - 1);
    float w = ldf(W, i, flags[0]);
    ushort h = f2bf(w);
    wt_hi[(size_t)n * K + k] = h;
    wt_lo[(size_t)n * K + k] = f2bf(w - bf2f(h));
}

// C[M x 128] = A[M x K] @ W; block = 256 thr = 4 waves, wave owns 16 rows x 128 cols.
// Per 32-k step: A-frag from global (2x float4) split hi/lo in-reg; B-frags from
// Wt (16B contiguous). D = Ahi*Bhi + Ahi*Blo + Alo*Bhi (err ~2^-16 << f32 need).
// Layouts (HW-verified, guide m89/m91/m120): A: m=lane&15,k=quad*8+j;
// B: n=lane&15,k=quad*8+j; C/D: col=lane&15,row=quad*4+reg.
__global__ __launch_bounds__(256) void gemm_mfma_kernel(
    const void* __restrict__ A, const ushort* __restrict__ wt_hi,
    const ushort* __restrict__ wt_lo, float* __restrict__ C, int K,
    int a_internal, const int* __restrict__ flags) {
    int wave = threadIdx.x >> 6, lane = threadIdx.x & 63;
    int quad = lane >> 4, n16 = lane & 15;
    int rb = blockIdx.x * 64 + wave * 16;
    int rowa = min(rb + n16, N_NODES - 1);       // A-frag row (clamped tail)
    int af32 = a_internal ? 1 : flags[0];
    f32x4 acc[8];
#pragma unroll
    for (int t = 0; t < 8; t++) acc[t] = (f32x4){0.f, 0.f, 0.f, 0.f};

    for (int k0 = 0; k0 < K; k0 += 32) {
        float av[8];
        if (af32) {
            const float* ap = (const float*)A + (size_t)rowa * K + k0 + quad * 8;
            f32x4 a0 = *(const f32x4*)ap;
            f32x4 a1 = *(const f32x4*)(ap + 4);
#pragma unroll
            for (int j = 0; j < 4; j++) { av[j] = a0[j]; av[j + 4] = a1[j]; }
        } else {
            const ushort* ap = (const ushort*)A + (size_t)rowa * K + k0 + quad * 8;
#pragma unroll
            for (int j = 0; j < 8; j++) av[j] = bf2f(ap[j]);
        }
        short8 ahi, alo;
#pragma unroll
        for (int j = 0; j < 8; j++) {
            ushort h = f2bf(av[j]);
            ahi[j] = (short)h;
            alo[j] = (short)f2bf(av[j] - bf2f(h));
        }
#pragma unroll
        for (int nt = 0; nt < 8; nt++) {
            size_t boff = (size_t)(nt * 16 + n16) * K + k0 + quad * 8;
            short8 bhi = *(const short8*)(wt_hi + boff);
            short8 blo = *(const short8*)(wt_lo + boff);
            acc[nt] = __builtin_amdgcn_mfma_f32_16x16x32_bf16(ahi, bhi, acc[nt], 0, 0, 0);
            acc[nt] = __builtin_amdgcn_mfma_f32_16x16x32_bf16(ahi, blo, acc[nt], 0, 0, 0);
            acc[nt] = __builtin_amdgcn_mfma_f32_16x16x32_bf16(alo, bhi, acc[nt], 0, 0, 0);
        }
    }
#pragma unroll
    for (int nt = 0; nt < 8; nt++) {
#pragma unroll
        for (int r = 0; r < 4; r++) {
            int ro = rb + quad * 4 + r;
            if (ro < N_NODES) C[(size_t)ro * G + nt * 16 + n16] = acc[nt][r];
        }
    }
}

// per-node attention terms: es = h.as, ed = h.ad ; one wave per node
__global__ void ead_kernel(const float* __restrict__ h, const void* __restrict__ aS,
                           const void* __restrict__ aD, float* __restrict__ es,
                           float* __restrict__ ed, const int* __restrict__ flags) {
    int n = blockIdx.x;
    int l = threadIdx.x;  // 64
    int f32 = flags[0];
    const float* hp = h + (size_t)n * G;
    float h0 = hp[l], h1 = hp[l + 64];
    float s = h0 * ldf(aS, l, f32) + h1 * ldf(aS, l + 64, f32);
    float d = h0 * ldf(aD, l, f32) + h1 * ldf(aD, l + 64, f32);
    for (int off = 32; off; off >>= 1) {
        s += __shfl_down(s, off);
        d += __shfl_down(d, off);
    }
    if (l == 0) { es[n] = s; ed[n] = d; }
}

// Fused GAT aggregate: one wave per dst node. Online softmax over incoming
// edge list (CSR), weighted gather of h[src], normalize, +bias, SELU.
__global__ __launch_bounds__(64) void gat_agg_kernel(
    const float* __restrict__ h, const int* __restrict__ rowptr,
    const int* __restrict__ srcs, const float* __restrict__ es,
    const float* __restrict__ edv, const void* __restrict__ bias,
    float* __restrict__ outbuf, const int* __restrict__ flags) {
    int d = blockIdx.x;
    int l = threadIdx.x;  // 64
    __shared__ float sp[CHUNK];
    __shared__ int ssrc[CHUNK];
    int start = rowptr[d], end = rowptr[d + 1];
    float edd = edv[d];
    float m = -INFINITY, den = 0.f;
    float acc0 = 0.f, acc1 = 0.f;
    for (int c0 = start; c0 < end; c0 += CHUNK) {
        int cn = min(end - c0, CHUNK);
        float mc = -INFINITY;
        for (int i = l; i < cn; i += 64) {
            int s = srcs[c0 + i];
            ssrc[i] = s;
            float v = es[s] + edd;
            v = v >= 0.f ? v : 0.2f * v;  // LeakyReLU(0.2)
            sp[i] = v;
            mc = fmaxf(mc, v);
        }
        for (int off = 32; off; off >>= 1) mc = fmaxf(mc, __shfl_xor(mc, off));
        float mnew = fmaxf(m, mc);
        float scale = (den > 0.f) ? expf(m - mnew) : 0.f;
        __syncthreads();
        float lsum = 0.f;
        for (int i = l; i < cn; i += 64) {
            float p = expf(sp[i] - mnew);
            sp[i] = p;
            lsum += p;
        }
        for (int off = 32; off; off >>= 1) lsum += __shfl_xor(lsum, off);
        den = den * scale + lsum;
        acc0 *= scale; acc1 *= scale;
        __syncthreads();
        for (int i = 0; i < cn; i++) {
            float p = sp[i];
            const float* hp = h + (size_t)ssrc[i] * G;
            acc0 += p * hp[l];
            acc1 += p * hp[l + 64];
        }
        __syncthreads();
        m = mnew;
    }
    float inv = 1.f / (den + 1e-16f);
    int f32 = flags[0];
    float o0 = acc0 * inv + ldf(bias, l, f32);
    float o1 = acc1 * inv + ldf(bias, l + 64, f32);
    outbuf[(size_t)d * G + l]      = selu_f(o0);
    outbuf[(size_t)d * G + l + 64] = selu_f(o1);
}

// ---------------- pool + head ----------------
__global__ void pool_kernel(const float* __restrict__ h, const void* __restrict__ batch,
                            float* __restrict__ gsum, const int* __restrict__ flags) {
    int t = threadIdx.x;  // 128
    int i64 = flags[1];
    int i0 = blockIdx.x * POOL_NODES;
    int i1 = min(N_NODES, i0 + POOL_NODES);
    int cur = -1;
    float acc = 0.f;
    for (int i = i0; i < i1; i++) {
        int g = min(max(ldi(batch, i, i64), 0), NGRAPH - 1);
        if (g != cur) {
            if (cur >= 0) atomicAdd(&gsum[cur * G + t], acc);
            cur = g; acc = 0.f;
        }
        acc += h[(size_t)i * G + t];
    }
    if (cur >= 0) atomicAdd(&gsum[cur * G + t], acc);
}

__global__ void count_kernel(const void* __restrict__ batch, float* __restrict__ gcnt,
                             const int* __restrict__ flags) {
    __shared__ int hist[NGRAPH];
    int t = threadIdx.x;
    if (t < NGRAPH) hist[t] = 0;
    __syncthreads();
    int i = blockIdx.x * 256 + t;
    if (i < N_NODES) {
        int g = min(max(ldi(batch, i, flags[1]), 0), NGRAPH - 1);
        atomicAdd(&hist[g], 1);
    }
    __syncthreads();
    if (t < NGRAPH && hist[t] != 0) atomicAdd(&gcnt[t], (float)hist[t]);
}

// pooled -> selu -> lin1+selu -> lin2 -> log_softmax; OUTPUT FLOAT32
__global__ void head_kernel(const float* __restrict__ gsum, const float* __restrict__ gcnt,
                            const void* __restrict__ lw1, const void* __restrict__ lb1,
                            const void* __restrict__ lw2, const void* __restrict__ lb2,
                            float* __restrict__ out, const int* __restrict__ flags) {
    int g = blockIdx.x, t = threadIdx.x;  // 64
    int f32 = flags[0];
    __shared__ float z[G];
    __shared__ float z1[NHID];
    __shared__ float z2[2];
    float cnt = fmaxf(gcnt[g], 1.0f);
    z[t]      = selu_f(gsum[g * G + t] / cnt);
    z[t + 64] = selu_f(gsum[g * G + 64 + t] / cnt);
    __syncthreads();
    float a = ldf(lb1, t, f32);
    for (int k = 0; k < G; k++) a += z[k] * ldf(lw1, k * NHID + t, f32);
    z1[t] = selu_f(a);
    __syncthreads();
    if (t < 2) {
        float s = ldf(lb2, t, f32);
        for (int j = 0; j < NHID; j++) s += z1[j] * ldf(lw2, j * 2 + t, f32);
        z2[t] = s;
    }
    __syncthreads();
    if (t == 0) {
        float mx = fmaxf(z2[0], z2[1]);
        float l = mx + logf(expf(z2[0] - mx) + expf(z2[1] - mx));
        out[g * 2 + 0] = z2[0] - l;
        out[g * 2 + 1] = z2[1] - l;
    }
}

extern "C" void kernel_launch(void* const* d_in, const int* in_sizes, int n_in,
                              void* d_out, int out_size, void* d_ws, size_t ws_size,
                              hipStream_t stream) {
    const void* x    = d_in[0];
    const void* ei   = d_in[1];
    const void* batch= d_in[2];
    const void* W1   = d_in[3];
    const void* as1  = d_in[4];
    const void* ad1  = d_in[5];
    const void* b1   = d_in[6];
    const void* W2   = d_in[7];
    const void* as2  = d_in[8];
    const void* ad2  = d_in[9];
    const void* b2   = d_in[10];
    const void* lw1  = d_in[11];
    const void* lb1  = d_in[12];
    const void* lw2  = d_in[13];
    const void* lb2  = d_in[14];
    float* out = (float*)d_out;

    char* w = (char*)d_ws;
    size_t off = 0;
    auto alloc = [&](size_t bytes) -> char* {
        char* p = w + off;
        off = (off + bytes + 255) & ~(size_t)255;
        return p;
    };
    int*    flags  = (int*)alloc(256);
    float*  hbuf   = (float*)alloc((size_t)N_NODES * G * 4);
    float*  abuf   = (float*)alloc((size_t)N_NODES * G * 4);
    float*  es     = (float*)alloc((size_t)N_NODES * 4);
    float*  edv    = (float*)alloc((size_t)N_NODES * 4);
    int*    deg    = (int*)alloc((size_t)N_NODES * 4);
    int*    rowptr = (int*)alloc((size_t)(N_NODES + 1) * 4);
    int*    cursor = (int*)alloc((size_t)N_NODES * 4);
    int*    csum   = (int*)alloc((size_t)NCHUNK * 4);
    int*    srcs   = (int*)alloc((size_t)ET * 4);
    float*  gsum   = (float*)alloc((size_t)NGRAPH * G * 4);
    float*  gcnt   = (float*)alloc((size_t)NGRAPH * 4);
    ushort* wt1_hi = (ushort*)alloc((size_t)IN_F * G * 2);
    ushort* wt1_lo = (ushort*)alloc((size_t)IN_F * G * 2);
    ushort* wt2_hi = (ushort*)alloc((size_t)G * G * 2);
    ushort* wt2_lo = (ushort*)alloc((size_t)G * G * 2);

    unsigned eb = (ET + 255) / 256;
    unsigned gemm_grid = (N_NODES + 63) / 64;

    detect_kernel<<<1, 64, 0, stream>>>(x, ei, flags);

    // ---------------- CSR build (once) ----------------
    zero_int_kernel<<<(N_NODES + 255) / 256, 256, 0, stream>>>(deg, N_NODES);
    deg_kernel<<<eb, 256, 0, stream>>>(ei, deg, flags);
    chunk_sum_kernel<<<NCHUNK, 256, 0, stream>>>(deg, csum);
    scan_csum_kernel<<<1, 64, 0, stream>>>(csum);
    chunk_scan_kernel<<<NCHUNK, 256, 0, stream>>>(deg, csum, rowptr, cursor);
    fill_kernel<<<eb, 256, 0, stream>>>(ei, cursor, srcs, flags);

    // ---------------- W split/transpose (once per layer) ----------------
    wt_kernel<<<(IN_F * G + 255) / 256, 256, 0, stream>>>(W1, wt1_hi, wt1_lo, IN_F, flags);
    wt_kernel<<<(G * G + 255) / 256, 256, 0, stream>>>(W2, wt2_hi, wt2_lo, G, flags);

    // ---------------- Layer 1 ----------------
    gemm_mfma_kernel<<<gemm_grid, 256, 0, stream>>>(x, wt1_hi, wt1_lo, hbuf, IN_F, 0, flags);
    ead_kernel<<<N_NODES, 64, 0, stream>>>(hbuf, as1, ad1, es, edv, flags);
    gat_agg_kernel<<<N_NODES, 64, 0, stream>>>(hbuf, rowptr, srcs, es, edv, b1, abuf, flags);

    // ---------------- Layer 2 ----------------
    gemm_mfma_kernel<<<gemm_grid, 256, 0, stream>>>(abuf, wt2_hi, wt2_lo, hbuf, G, 1, flags);
    ead_kernel<<<N_NODES, 64, 0, stream>>>(hbuf, as2, ad2, es, edv, flags);
    gat_agg_kernel<<<N_NODES, 64, 0, stream>>>(hbuf, rowptr, srcs, es, edv, b2, abuf, flags);

    // ---------------- Pool + head ----------------
    zero_float_kernel<<<(NGRAPH * G + 255) / 256, 256, 0, stream>>>(gsum, NGRAPH * G);
    zero_float_kernel<<<1, 256, 0, stream>>>(gcnt, NGRAPH);
    pool_kernel<<<(N_NODES + POOL_NODES - 1) / POOL_NODES, 128, 0, stream>>>(abuf, batch, gsum, flags);
    count_kernel<<<(N_NODES + 255) / 256, 256, 0, stream>>>(batch, gcnt, flags);
    head_kernel<<<NGRAPH, 64, 0, stream>>>(gsum, gcnt, lw1, lb1, lw2, lb2, out, flags);
}

// Round 8
// 502.788 us; speedup vs baseline: 3.8810x; 1.0356x over previous
//
#include <hip/hip_runtime.h>
#include <hip/hip_bf16.h>
#include <math.h>

#define N_NODES 50000
#define N_EDGES 800000
#define ET (N_EDGES + N_NODES)   // edges + self loops
#define IN_F 256
#define G 128                    // 2*HID
#define NHID 64
#define NGRAPH 32
#define NCHUNK ((N_NODES + 255) / 256)   // 196
#define CHUNK 1024                        // edges per LDS softmax chunk
#define POOL_NODES 64

typedef __hip_bfloat16 bf16;
typedef unsigned short ushort;
typedef __attribute__((ext_vector_type(8))) short short8;
typedef __attribute__((ext_vector_type(4))) float f32x4;

// ---------- dtype-agnostic loads (flags resolved at runtime, wave-uniform) ----------
__device__ __forceinline__ float bf2f(ushort u) {
    union { unsigned u; float f; } c; c.u = ((unsigned)u) << 16; return c.f;
}
// round-to-nearest-even f32 -> bf16 (finite inputs)
__device__ __forceinline__ ushort f2bf(float f) {
    unsigned u = __float_as_uint(f);
    u += 0x7FFFu + ((u >> 16) & 1u);
    return (ushort)(u >> 16);
}
__device__ __forceinline__ float ldf(const void* p, long i, int f32) {
    return f32 ? ((const float*)p)[i] : bf2f(((const ushort*)p)[i]);
}
__device__ __forceinline__ int ldi(const void* p, long i, int i64) {
    return i64 ? (int)((const long long*)p)[i] : ((const int*)p)[i];
}

__device__ __forceinline__ float selu_f(float x) {
    const float sc = 1.0507009873554805f, al = 1.6732632423543772f;
    return x > 0.f ? sc * x : sc * al * expm1f(x);
}

// flags[0]=1 -> float inputs are f32 (else bf16); flags[1]=1 -> ints are int64.
__global__ void detect_kernel(const void* x, const void* ei, int* flags) {
    int l = threadIdx.x;  // 64
    const unsigned* xu = (const unsigned*)x;
    const long NW = (long)N_NODES * IN_F / 2;
    long stride = NW / 1024;
    int sane = 0;
    for (int k = l; k < 1024; k += 64) {
        unsigned u = xu[(long)k * stride];
        unsigned e = (u >> 23) & 0xFF;
        if (u == 0u || (e >= 100 && e <= 140)) sane++;
    }
    const unsigned* wu = (const unsigned*)ei;
    int nz = 0;
    for (int k = l; k < 1024; k += 64) {
        long j = ((long)k * 1562) | 1;
        nz += (wu[j] != 0u);
    }
    for (int off = 32; off; off >>= 1) {
        sane += __shfl_xor(sane, off);
        nz   += __shfl_xor(nz, off);
    }
    if (l == 0) {
        flags[0] = (sane >= 512) ? 1 : 0;
        flags[1] = (nz < 16) ? 1 : 0;
    }
}

__global__ void zero_float_kernel(float* __restrict__ p, long n) {
    long i = (long)blockIdx.x * 256 + threadIdx.x;
    if (i < n) p[i] = 0.f;
}
__global__ void zero_int_kernel(int* __restrict__ p, long n) {
    long i = (long)blockIdx.x * 256 + threadIdx.x;
    if (i < n) p[i] = 0;
}

__device__ __forceinline__ void edge_sd(const void* __restrict__ ei, int e, int i64,
                                        int& s, int& d) {
    if (e < N_EDGES) {
        s = ldi(ei, e, i64);
        d = ldi(ei, (long)N_EDGES + e, i64);
        s = min(max(s, 0), N_NODES - 1);
        d = min(max(d, 0), N_NODES - 1);
    } else {
        s = d = e - N_EDGES;
    }
}

// ---------------- CSR build (once; graph is layer-invariant) ----------------
__global__ void deg_kernel(const void* __restrict__ ei, int* __restrict__ deg,
                           const int* __restrict__ flags) {
    int e = blockIdx.x * 256 + threadIdx.x;
    if (e >= ET) return;
    int s, d; edge_sd(ei, e, flags[1], s, d);
    atomicAdd(&deg[d], 1);
}

__global__ void chunk_sum_kernel(const int* __restrict__ deg, int* __restrict__ csum) {
    __shared__ int sd[256];
    int t = threadIdx.x;
    int i = blockIdx.x * 256 + t;
    sd[t] = (i < N_NODES) ? deg[i] : 0;
    __syncthreads();
    for (int off = 128; off; off >>= 1) {
        if (t < off) sd[t] += sd[t + off];
        __syncthreads();
    }
    if (t == 0) csum[blockIdx.x] = sd[0];
}

__global__ void scan_csum_kernel(int* __restrict__ csum) {  // in-place exclusive
    if (threadIdx.x != 0 || blockIdx.x != 0) return;
    int acc = 0;
    for (int i = 0; i < NCHUNK; i++) { int v = csum[i]; csum[i] = acc; acc += v; }
}

__global__ void chunk_scan_kernel(const int* __restrict__ deg, const int* __restrict__ csum,
                                  int* __restrict__ rowptr, int* __restrict__ cursor) {
    __shared__ int sd[256];
    int t = threadIdx.x;
    int i = blockIdx.x * 256 + t;
    int v = (i < N_NODES) ? deg[i] : 0;
    sd[t] = v;
    for (int off = 1; off < 256; off <<= 1) {
        __syncthreads();
        int add = (t >= off) ? sd[t - off] : 0;
        __syncthreads();
        sd[t] += add;
    }
    __syncthreads();
    int excl = sd[t] - v + csum[blockIdx.x];
    if (i < N_NODES) { rowptr[i] = excl; cursor[i] = excl; }
    if (i == 0) rowptr[N_NODES] = ET;
}

__global__ void fill_kernel(const void* __restrict__ ei, int* __restrict__ cursor,
                            int* __restrict__ srcs, const int* __restrict__ flags) {
    int e = blockIdx.x * 256 + threadIdx.x;
    if (e >= ET) return;
    int s, d; edge_sd(ei, e, flags[1], s, d);
    int pos = atomicAdd(&cursor[d], 1);
    srcs[pos] = s;
}

// ---------------- GEMM: MFMA split-bf16 (hi+lo), f32-accurate ----------------
// Transpose W[K][128] -> Wt_hi/Wt_lo[n][k] bf16 (once per layer; L2-resident).
__global__ void wt_kernel(const void* __restrict__ W, ushort* __restrict__ wt_hi,
                          ushort* __restrict__ wt_lo, int K, const int* __restrict__ flags) {
    int i = blockIdx.x * 256 + threadIdx.x;
    if (i >= K * G) return;
    int k = i >> 7, n = i & (G - 1);
    float w = ldf(W, i, flags[0]);
    ushort h = f2bf(w);
    wt_hi[(size_t)n * K + k] = h;
    wt_lo[(size_t)n * K + k] = f2bf(w - bf2f(h));
}

// C[M x 128] = A[M x K] @ W; block = 256 thr = 4 waves, wave owns 16 rows x 128 cols.
// K is compile-time: full unroll, all 16 B-frag loads of a k-step batched into
// register arrays BEFORE the MFMAs (round-7 failure: VGPR_Count=40 serialized
// every load at ~200cyc L2 latency -> MfmaUtil 5%). launch_bounds(256,3) gives
// ~170-reg budget at 3 blocks/CU (grid 782 = 3.05/CU).
// Epilogue fuses ead: es/ed row-dots via xor-shuffle over the 16-lane n16 group.
// Layouts (HW-verified): A: m=lane&15,k=quad*8+j; B: n=lane&15,k=quad*8+j;
// C/D: col=lane&15,row=quad*4+reg.
template <int K>
__global__ __launch_bounds__(256, 3) void gemm_mfma_kernel(
    const void* __restrict__ A, const ushort* __restrict__ wt_hi,
    const ushort* __restrict__ wt_lo, float* __restrict__ C,
    int a_internal, const int* __restrict__ flags,
    const void* __restrict__ aS, const void* __restrict__ aD,
    float* __restrict__ es, float* __restrict__ edv) {
    int wave = threadIdx.x >> 6, lane = threadIdx.x & 63;
    int quad = lane >> 4, n16 = lane & 15;
    int rb = blockIdx.x * 64 + wave * 16;
    int rowa = min(rb + n16, N_NODES - 1);       // A-frag row (clamped tail)
    int af32 = a_internal ? 1 : flags[0];
    f32x4 acc[8];
#pragma unroll
    for (int t = 0; t < 8; t++) acc[t] = (f32x4){0.f, 0.f, 0.f, 0.f};

#pragma unroll
    for (int k0 = 0; k0 < K; k0 += 32) {
        // batch all B loads first (16 outstanding vmem ops)
        short8 bh[8], bl[8];
#pragma unroll
        for (int nt = 0; nt < 8; nt++) {
            size_t boff = (size_t)(nt * 16 + n16) * K + k0 + quad * 8;
            bh[nt] = *(const short8*)(wt_hi + boff);
            bl[nt] = *(const short8*)(wt_lo + boff);
        }
        float av[8];
        if (af32) {
            const float* ap = (const float*)A + (size_t)rowa * K + k0 + quad * 8;
            f32x4 a0 = *(const f32x4*)ap;
            f32x4 a1 = *(const f32x4*)(ap + 4);
#pragma unroll
            for (int j = 0; j < 4; j++) { av[j] = a0[j]; av[j + 4] = a1[j]; }
        } else {
            const ushort* ap = (const ushort*)A + (size_t)rowa * K + k0 + quad * 8;
#pragma unroll
            for (int j = 0; j < 8; j++) av[j] = bf2f(ap[j]);
        }
        short8 ahi, alo;
#pragma unroll
        for (int j = 0; j < 8; j++) {
            ushort h = f2bf(av[j]);
            ahi[j] = (short)h;
            alo[j] = (short)f2bf(av[j] - bf2f(h));
        }
#pragma unroll
        for (int nt = 0; nt < 8; nt++) {
            acc[nt] = __builtin_amdgcn_mfma_f32_16x16x32_bf16(ahi, bh[nt], acc[nt], 0, 0, 0);
            acc[nt] = __builtin_amdgcn_mfma_f32_16x16x32_bf16(ahi, bl[nt], acc[nt], 0, 0, 0);
            acc[nt] = __builtin_amdgcn_mfma_f32_16x16x32_bf16(alo, bh[nt], acc[nt], 0, 0, 0);
        }
    }

    // epilogue: C store + fused ead (es = h.as, ed = h.ad per row)
    int f32 = flags[0];
    float asv[8], adv[8];
#pragma unroll
    for (int nt = 0; nt < 8; nt++) {
        asv[nt] = ldf(aS, nt * 16 + n16, f32);
        adv[nt] = ldf(aD, nt * 16 + n16, f32);
    }
#pragma unroll
    for (int r = 0; r < 4; r++) {
        int ro = rb + quad * 4 + r;
        float s = 0.f, dv = 0.f;
#pragma unroll
        for (int nt = 0; nt < 8; nt++) {
            float v = acc[nt][r];
            if (ro < N_NODES) C[(size_t)ro * G + nt * 16 + n16] = v;
            s += v * asv[nt];
            dv += v * adv[nt];
        }
#pragma unroll
        for (int off = 8; off; off >>= 1) {   // reduce across n16 group (same quad)
            s += __shfl_xor(s, off);
            dv += __shfl_xor(dv, off);
        }
        if (n16 == 0 && ro < N_NODES) { es[ro] = s; edv[ro] = dv; }
    }
}

// Fused GAT aggregate: one wave per dst node. Online softmax over incoming
// edge list (CSR), weighted gather of h[src], normalize, +bias, SELU.
__global__ __launch_bounds__(64) void gat_agg_kernel(
    const float* __restrict__ h, const int* __restrict__ rowptr,
    const int* __restrict__ srcs, const float* __restrict__ es,
    const float* __restrict__ edv, const void* __restrict__ bias,
    float* __restrict__ outbuf, const int* __restrict__ flags) {
    int d = blockIdx.x;
    int l = threadIdx.x;  // 64
    __shared__ float sp[CHUNK];
    __shared__ int ssrc[CHUNK];
    int start = rowptr[d], end = rowptr[d + 1];
    float edd = edv[d];
    float m = -INFINITY, den = 0.f;
    float acc0 = 0.f, acc1 = 0.f;
    for (int c0 = start; c0 < end; c0 += CHUNK) {
        int cn = min(end - c0, CHUNK);
        float mc = -INFINITY;
        for (int i = l; i < cn; i += 64) {
            int s = srcs[c0 + i];
            ssrc[i] = s;
            float v = es[s] + edd;
            v = v >= 0.f ? v : 0.2f * v;  // LeakyReLU(0.2)
            sp[i] = v;
            mc = fmaxf(mc, v);
        }
        for (int off = 32; off; off >>= 1) mc = fmaxf(mc, __shfl_xor(mc, off));
        float mnew = fmaxf(m, mc);
        float scale = (den > 0.f) ? expf(m - mnew) : 0.f;
        __syncthreads();
        float lsum = 0.f;
        for (int i = l; i < cn; i += 64) {
            float p = expf(sp[i] - mnew);
            sp[i] = p;
            lsum += p;
        }
        for (int off = 32; off; off >>= 1) lsum += __shfl_xor(lsum, off);
        den = den * scale + lsum;
        acc0 *= scale; acc1 *= scale;
        __syncthreads();
        for (int i = 0; i < cn; i++) {
            float p = sp[i];
            const float* hp = h + (size_t)ssrc[i] * G;
            acc0 += p * hp[l];
            acc1 += p * hp[l + 64];
        }
        __syncthreads();
        m = mnew;
    }
    float inv = 1.f / (den + 1e-16f);
    int f32 = flags[0];
    float o0 = acc0 * inv + ldf(bias, l, f32);
    float o1 = acc1 * inv + ldf(bias, l + 64, f32);
    outbuf[(size_t)d * G + l]      = selu_f(o0);
    outbuf[(size_t)d * G + l + 64] = selu_f(o1);
}

// ---------------- pool + head ----------------
__global__ void pool_kernel(const float* __restrict__ h, const void* __restrict__ batch,
                            float* __restrict__ gsum, const int* __restrict__ flags) {
    int t = threadIdx.x;  // 128
    int i64 = flags[1];
    int i0 = blockIdx.x * POOL_NODES;
    int i1 = min(N_NODES, i0 + POOL_NODES);
    int cur = -1;
    float acc = 0.f;
    for (int i = i0; i < i1; i++) {
        int g = min(max(ldi(batch, i, i64), 0), NGRAPH - 1);
        if (g != cur) {
            if (cur >= 0) atomicAdd(&gsum[cur * G + t], acc);
            cur = g; acc = 0.f;
        }
        acc += h[(size_t)i * G + t];
    }
    if (cur >= 0) atomicAdd(&gsum[cur * G + t], acc);
}

__global__ void count_kernel(const void* __restrict__ batch, float* __restrict__ gcnt,
                             const int* __restrict__ flags) {
    __shared__ int hist[NGRAPH];
    int t = threadIdx.x;
    if (t < NGRAPH) hist[t] = 0;
    __syncthreads();
    int i = blockIdx.x * 256 + t;
    if (i < N_NODES) {
        int g = min(max(ldi(batch, i, flags[1]), 0), NGRAPH - 1);
        atomicAdd(&hist[g], 1);
    }
    __syncthreads();
    if (t < NGRAPH && hist[t] != 0) atomicAdd(&gcnt[t], (float)hist[t]);
}

// pooled -> selu -> lin1+selu -> lin2 -> log_softmax; OUTPUT FLOAT32
__global__ void head_kernel(const float* __restrict__ gsum, const float* __restrict__ gcnt,
                            const void* __restrict__ lw1, const void* __restrict__ lb1,
                            const void* __restrict__ lw2, const void* __restrict__ lb2,
                            float* __restrict__ out, const int* __restrict__ flags) {
    int g = blockIdx.x, t = threadIdx.x;  // 64
    int f32 = flags[0];
    __shared__ float z[G];
    __shared__ float z1[NHID];
    __shared__ float z2[2];
    float cnt = fmaxf(gcnt[g], 1.0f);
    z[t]      = selu_f(gsum[g * G + t] / cnt);
    z[t + 64] = selu_f(gsum[g * G + 64 + t] / cnt);
    __syncthreads();
    float a = ldf(lb1, t, f32);
    for (int k = 0; k < G; k++) a += z[k] * ldf(lw1, k * NHID + t, f32);
    z1[t] = selu_f(a);
    __syncthreads();
    if (t < 2) {
        float s = ldf(lb2, t, f32);
        for (int j = 0; j < NHID; j++) s += z1[j] * ldf(lw2, j * 2 + t, f32);
        z2[t] = s;
    }
    __syncthreads();
    if (t == 0) {
        float mx = fmaxf(z2[0], z2[1]);
        float l = mx + logf(expf(z2[0] - mx) + expf(z2[1] - mx));
        out[g * 2 + 0] = z2[0] - l;
        out[g * 2 + 1] = z2[1] - l;
    }
}

extern "C" void kernel_launch(void* const* d_in, const int* in_sizes, int n_in,
                              void* d_out, int out_size, void* d_ws, size_t ws_size,
                              hipStream_t stream) {
    const void* x    = d_in[0];
    const void* ei   = d_in[1];
    const void* batch= d_in[2];
    const void* W1   = d_in[3];
    const void* as1  = d_in[4];
    const void* ad1  = d_in[5];
    const void* b1   = d_in[6];
    const void* W2   = d_in[7];
    const void* as2  = d_in[8];
    const void* ad2  = d_in[9];
    const void* b2   = d_in[10];
    const void* lw1  = d_in[11];
    const void* lb1  = d_in[12];
    const void* lw2  = d_in[13];
    const void* lb2  = d_in[14];
    float* out = (float*)d_out;

    char* w = (char*)d_ws;
    size_t off = 0;
    auto alloc = [&](size_t bytes) -> char* {
        char* p = w + off;
        off = (off + bytes + 255) & ~(size_t)255;
        return p;
    };
    int*    flags  = (int*)alloc(256);
    float*  hbuf   = (float*)alloc((size_t)N_NODES * G * 4);
    float*  abuf   = (float*)alloc((size_t)N_NODES * G * 4);
    float*  es     = (float*)alloc((size_t)N_NODES * 4);
    float*  edv    = (float*)alloc((size_t)N_NODES * 4);
    int*    deg    = (int*)alloc((size_t)N_NODES * 4);
    int*    rowptr = (int*)alloc((size_t)(N_NODES + 1) * 4);
    int*    cursor = (int*)alloc((size_t)N_NODES * 4);
    int*    csum   = (int*)alloc((size_t)NCHUNK * 4);
    int*    srcs   = (int*)alloc((size_t)ET * 4);
    float*  gsum   = (float*)alloc((size_t)NGRAPH * G * 4);
    float*  gcnt   = (float*)alloc((size_t)NGRAPH * 4);
    ushort* wt1_hi = (ushort*)alloc((size_t)IN_F * G * 2);
    ushort* wt1_lo = (ushort*)alloc((size_t)IN_F * G * 2);
    ushort* wt2_hi = (ushort*)alloc((size_t)G * G * 2);
    ushort* wt2_lo = (ushort*)alloc((size_t)G * G * 2);

    unsigned eb = (ET + 255) / 256;
    unsigned gemm_grid = (N_NODES + 63) / 64;

    detect_kernel<<<1, 64, 0, stream>>>(x, ei, flags);

    // ---------------- CSR build (once) ----------------
    zero_int_kernel<<<(N_NODES + 255) / 256, 256, 0, stream>>>(deg, N_NODES);
    deg_kernel<<<eb, 256, 0, stream>>>(ei, deg, flags);
    chunk_sum_kernel<<<NCHUNK, 256, 0, stream>>>(deg, csum);
    scan_csum_kernel<<<1, 64, 0, stream>>>(csum);
    chunk_scan_kernel<<<NCHUNK, 256, 0, stream>>>(deg, csum, rowptr, cursor);
    fill_kernel<<<eb, 256, 0, stream>>>(ei, cursor, srcs, flags);

    // ---------------- W split/transpose (once per layer) ----------------
    wt_kernel<<<(IN_F * G + 255) / 256, 256, 0, stream>>>(W1, wt1_hi, wt1_lo, IN_F, flags);
    wt_kernel<<<(G * G + 255) / 256, 256, 0, stream>>>(W2, wt2_hi, wt2_lo, G, flags);

    // ---------------- Layer 1 (gemm + fused ead) ----------------
    gemm_mfma_kernel<IN_F><<<gemm_grid, 256, 0, stream>>>(x, wt1_hi, wt1_lo, hbuf,
                                                          0, flags, as1, ad1, es, edv);
    gat_agg_kernel<<<N_NODES, 64, 0, stream>>>(hbuf, rowptr, srcs, es, edv, b1, abuf, flags);

    // ---------------- Layer 2 (gemm + fused ead) ----------------
    gemm_mfma_kernel<G><<<gemm_grid, 256, 0, stream>>>(abuf, wt2_hi, wt2_lo, hbuf,
                                                       1, flags, as2, ad2, es, edv);
    gat_agg_kernel<<<N_NODES, 64, 0, stream>>>(hbuf, rowptr, srcs, es, edv, b2, abuf, flags);

    // ---------------- Pool + head ----------------
    zero_float_kernel<<<(NGRAPH * G + 255) / 256, 256, 0, stream>>>(gsum, NGRAPH * G);
    zero_float_kernel<<<1, 256, 0, stream>>>(gcnt, NGRAPH);
    pool_kernel<<<(N_NODES + POOL_NODES - 1) / POOL_NODES, 128, 0, stream>>>(abuf, batch, gsum, flags);
    count_kernel<<<(N_NODES + 255) / 256, 256, 0, stream>>>(batch, gcnt, flags);
    head_kernel<<<NGRAPH, 64, 0, stream>>>(gsum, gcnt, lw1, lb1, lw2, lb2, out, flags);
}

// Round 9
// 501.955 us; speedup vs baseline: 3.8875x; 1.0017x over previous
//
#include <hip/hip_runtime.h>
#include <hip/hip_bf16.h>
#include <math.h>

#define N_NODES 50000
#define N_EDGES 800000
#define ET (N_EDGES + N_NODES)   // edges + self loops
#define IN_F 256
#define G 128                    // 2*HID
#define NHID 64
#define NGRAPH 32
#define NCHUNK ((N_NODES + 255) / 256)   // 196
#define CHUNK 1024                        // edges per LDS softmax chunk
#define POOL_NODES 64

typedef __hip_bfloat16 bf16;
typedef unsigned short ushort;
typedef __attribute__((ext_vector_type(8))) short short8;
typedef __attribute__((ext_vector_type(4))) float f32x4;

// ---------- dtype-agnostic loads (flags resolved at runtime, wave-uniform) ----------
__device__ __forceinline__ float bf2f(ushort u) {
    union { unsigned u; float f; } c; c.u = ((unsigned)u) << 16; return c.f;
}
// round-to-nearest-even f32 -> bf16 (finite inputs)
__device__ __forceinline__ ushort f2bf(float f) {
    unsigned u = __float_as_uint(f);
    u += 0x7FFFu + ((u >> 16) & 1u);
    return (ushort)(u >> 16);
}
__device__ __forceinline__ float ldf(const void* p, long i, int f32) {
    return f32 ? ((const float*)p)[i] : bf2f(((const ushort*)p)[i]);
}
__device__ __forceinline__ int ldi(const void* p, long i, int i64) {
    return i64 ? (int)((const long long*)p)[i] : ((const int*)p)[i];
}

__device__ __forceinline__ float selu_f(float x) {
    const float sc = 1.0507009873554805f, al = 1.6732632423543772f;
    return x > 0.f ? sc * x : sc * al * expm1f(x);
}

// flags[0]=1 -> float inputs are f32 (else bf16); flags[1]=1 -> ints are int64.
__global__ void detect_kernel(const void* x, const void* ei, int* flags) {
    int l = threadIdx.x;  // 64
    const unsigned* xu = (const unsigned*)x;
    const long NW = (long)N_NODES * IN_F / 2;
    long stride = NW / 1024;
    int sane = 0;
    for (int k = l; k < 1024; k += 64) {
        unsigned u = xu[(long)k * stride];
        unsigned e = (u >> 23) & 0xFF;
        if (u == 0u || (e >= 100 && e <= 140)) sane++;
    }
    const unsigned* wu = (const unsigned*)ei;
    int nz = 0;
    for (int k = l; k < 1024; k += 64) {
        long j = ((long)k * 1562) | 1;
        nz += (wu[j] != 0u);
    }
    for (int off = 32; off; off >>= 1) {
        sane += __shfl_xor(sane, off);
        nz   += __shfl_xor(nz, off);
    }
    if (l == 0) {
        flags[0] = (sane >= 512) ? 1 : 0;
        flags[1] = (nz < 16) ? 1 : 0;
    }
}

__global__ void zero_float_kernel(float* __restrict__ p, long n) {
    long i = (long)blockIdx.x * 256 + threadIdx.x;
    if (i < n) p[i] = 0.f;
}
__global__ void zero_int_kernel(int* __restrict__ p, long n) {
    long i = (long)blockIdx.x * 256 + threadIdx.x;
    if (i < n) p[i] = 0;
}

__device__ __forceinline__ void edge_sd(const void* __restrict__ ei, int e, int i64,
                                        int& s, int& d) {
    if (e < N_EDGES) {
        s = ldi(ei, e, i64);
        d = ldi(ei, (long)N_EDGES + e, i64);
        s = min(max(s, 0), N_NODES - 1);
        d = min(max(d, 0), N_NODES - 1);
    } else {
        s = d = e - N_EDGES;
    }
}

// ---------------- CSR build (once; graph is layer-invariant) ----------------
__global__ void deg_kernel(const void* __restrict__ ei, int* __restrict__ deg,
                           const int* __restrict__ flags) {
    int e = blockIdx.x * 256 + threadIdx.x;
    if (e >= ET) return;
    int s, d; edge_sd(ei, e, flags[1], s, d);
    atomicAdd(&deg[d], 1);
}

__global__ void chunk_sum_kernel(const int* __restrict__ deg, int* __restrict__ csum) {
    __shared__ int sd[256];
    int t = threadIdx.x;
    int i = blockIdx.x * 256 + t;
    sd[t] = (i < N_NODES) ? deg[i] : 0;
    __syncthreads();
    for (int off = 128; off; off >>= 1) {
        if (t < off) sd[t] += sd[t + off];
        __syncthreads();
    }
    if (t == 0) csum[blockIdx.x] = sd[0];
}

__global__ void scan_csum_kernel(int* __restrict__ csum) {  // in-place exclusive
    if (threadIdx.x != 0 || blockIdx.x != 0) return;
    int acc = 0;
    for (int i = 0; i < NCHUNK; i++) { int v = csum[i]; csum[i] = acc; acc += v; }
}

__global__ void chunk_scan_kernel(const int* __restrict__ deg, const int* __restrict__ csum,
                                  int* __restrict__ rowptr, int* __restrict__ cursor) {
    __shared__ int sd[256];
    int t = threadIdx.x;
    int i = blockIdx.x * 256 + t;
    int v = (i < N_NODES) ? deg[i] : 0;
    sd[t] = v;
    for (int off = 1; off < 256; off <<= 1) {
        __syncthreads();
        int add = (t >= off) ? sd[t - off] : 0;
        __syncthreads();
        sd[t] += add;
    }
    __syncthreads();
    int excl = sd[t] - v + csum[blockIdx.x];
    if (i < N_NODES) { rowptr[i] = excl; cursor[i] = excl; }
    if (i == 0) rowptr[N_NODES] = ET;
}

__global__ void fill_kernel(const void* __restrict__ ei, int* __restrict__ cursor,
                            int* __restrict__ srcs, const int* __restrict__ flags) {
    int e = blockIdx.x * 256 + threadIdx.x;
    if (e >= ET) return;
    int s, d; edge_sd(ei, e, flags[1], s, d);
    int pos = atomicAdd(&cursor[d], 1);
    srcs[pos] = s;
}

// ---------------- GEMM: MFMA split-bf16 (hi+lo), f32-accurate ----------------
// Transpose W[K][128] -> Wt_hi/Wt_lo[n][k] bf16 (once per layer; L2-resident).
__global__ void wt_kernel(const void* __restrict__ W, ushort* __restrict__ wt_hi,
                          ushort* __restrict__ wt_lo, int K, const int* __restrict__ flags) {
    int i = blockIdx.x * 256 + threadIdx.x;
    if (i >= K * G) return;
    int k = i >> 7, n = i & (G - 1);
    float w = ldf(W, i, flags[0]);
    ushort h = f2bf(w);
    wt_hi[(size_t)n * K + k] = h;
    wt_lo[(size_t)n * K + k] = f2bf(w - bf2f(h));
}

// C[M x 128] = A[M x K] @ W. Round-8 lesson: M is exhausted (3125 wave-tiles)
// -> grid-limited occupancy (20%), latency unhidden. Fix: N-SPLIT. Each wave:
// 16 rows x 64 cols (4 n-tiles). Block 256thr = 4 waves = 32 rows x 2 halves.
// Grid 1563 blocks = 6252 waves (~24/CU). Fused ead combines col-half partials
// via LDS. Layouts (HW-verified): A: m=lane&15,k=quad*8+j; B: n=lane&15,
// k=quad*8+j; C/D: col=lane&15,row=quad*4+reg.
template <int K>
__global__ __launch_bounds__(256, 4) void gemm_mfma_kernel(
    const void* __restrict__ A, const ushort* __restrict__ wt_hi,
    const ushort* __restrict__ wt_lo, float* __restrict__ C,
    int a_internal, const int* __restrict__ flags,
    const void* __restrict__ aS, const void* __restrict__ aD,
    float* __restrict__ es, float* __restrict__ edv) {
    int wave = threadIdx.x >> 6, lane = threadIdx.x & 63;
    int quad = lane >> 4, n16 = lane & 15;
    int colh = wave & 1, rowp = wave >> 1;
    int rb = blockIdx.x * 32 + rowp * 16;
    int rowa = min(rb + n16, N_NODES - 1);       // A-frag row (clamped tail)
    int af32 = a_internal ? 1 : flags[0];
    __shared__ float pS[32][2], pD[32][2];
    f32x4 acc[4];
#pragma unroll
    for (int t = 0; t < 4; t++) acc[t] = (f32x4){0.f, 0.f, 0.f, 0.f};

#pragma unroll
    for (int k0 = 0; k0 < K; k0 += 32) {
        // A first (HBM latency), then the 8 B loads (L2)
        float av[8];
        if (af32) {
            const float* ap = (const float*)A + (size_t)rowa * K + k0 + quad * 8;
            f32x4 a0 = *(const f32x4*)ap;
            f32x4 a1 = *(const f32x4*)(ap + 4);
#pragma unroll
            for (int j = 0; j < 4; j++) { av[j] = a0[j]; av[j + 4] = a1[j]; }
        } else {
            const ushort* ap = (const ushort*)A + (size_t)rowa * K + k0 + quad * 8;
#pragma unroll
            for (int j = 0; j < 8; j++) av[j] = bf2f(ap[j]);
        }
        short8 bh[4], bl[4];
#pragma unroll
        for (int nt = 0; nt < 4; nt++) {
            size_t boff = (size_t)(colh * 64 + nt * 16 + n16) * K + k0 + quad * 8;
            bh[nt] = *(const short8*)(wt_hi + boff);
            bl[nt] = *(const short8*)(wt_lo + boff);
        }
        short8 ahi, alo;
#pragma unroll
        for (int j = 0; j < 8; j++) {
            ushort h = f2bf(av[j]);
            ahi[j] = (short)h;
            alo[j] = (short)f2bf(av[j] - bf2f(h));
        }
#pragma unroll
        for (int nt = 0; nt < 4; nt++) {
            acc[nt] = __builtin_amdgcn_mfma_f32_16x16x32_bf16(ahi, bh[nt], acc[nt], 0, 0, 0);
            acc[nt] = __builtin_amdgcn_mfma_f32_16x16x32_bf16(ahi, bl[nt], acc[nt], 0, 0, 0);
            acc[nt] = __builtin_amdgcn_mfma_f32_16x16x32_bf16(alo, bh[nt], acc[nt], 0, 0, 0);
        }
    }

    // epilogue: C store + fused ead partials (this wave's 64 cols)
    int f32 = flags[0];
    float asv[4], adv[4];
#pragma unroll
    for (int nt = 0; nt < 4; nt++) {
        asv[nt] = ldf(aS, colh * 64 + nt * 16 + n16, f32);
        adv[nt] = ldf(aD, colh * 64 + nt * 16 + n16, f32);
    }
#pragma unroll
    for (int r = 0; r < 4; r++) {
        int ro = rb + quad * 4 + r;
        float s = 0.f, dv = 0.f;
#pragma unroll
        for (int nt = 0; nt < 4; nt++) {
            float v = acc[nt][r];
            if (ro < N_NODES) C[(size_t)ro * G + colh * 64 + nt * 16 + n16] = v;
            s += v * asv[nt];
            dv += v * adv[nt];
        }
#pragma unroll
        for (int off = 8; off; off >>= 1) {   // reduce across the 16-lane n16 group
            s += __shfl_xor(s, off);
            dv += __shfl_xor(dv, off);
        }
        if (n16 == 0) {
            int ri = rowp * 16 + quad * 4 + r;
            pS[ri][colh] = s;
            pD[ri][colh] = dv;
        }
    }
    __syncthreads();
    if (threadIdx.x < 32) {
        int ro = blockIdx.x * 32 + threadIdx.x;
        if (ro < N_NODES) {
            es[ro]  = pS[threadIdx.x][0] + pS[threadIdx.x][1];
            edv[ro] = pD[threadIdx.x][0] + pD[threadIdx.x][1];
        }
    }
}

// Fused GAT aggregate: one wave per dst node. Online softmax over incoming
// edge list (CSR), weighted gather of h[src], normalize, +bias, SELU.
__global__ __launch_bounds__(64) void gat_agg_kernel(
    const float* __restrict__ h, const int* __restrict__ rowptr,
    const int* __restrict__ srcs, const float* __restrict__ es,
    const float* __restrict__ edv, const void* __restrict__ bias,
    float* __restrict__ outbuf, const int* __restrict__ flags) {
    int d = blockIdx.x;
    int l = threadIdx.x;  // 64
    __shared__ float sp[CHUNK];
    __shared__ int ssrc[CHUNK];
    int start = rowptr[d], end = rowptr[d + 1];
    float edd = edv[d];
    float m = -INFINITY, den = 0.f;
    float acc0 = 0.f, acc1 = 0.f;
    for (int c0 = start; c0 < end; c0 += CHUNK) {
        int cn = min(end - c0, CHUNK);
        float mc = -INFINITY;
        for (int i = l; i < cn; i += 64) {
            int s = srcs[c0 + i];
            ssrc[i] = s;
            float v = es[s] + edd;
            v = v >= 0.f ? v : 0.2f * v;  // LeakyReLU(0.2)
            sp[i] = v;
            mc = fmaxf(mc, v);
        }
        for (int off = 32; off; off >>= 1) mc = fmaxf(mc, __shfl_xor(mc, off));
        float mnew = fmaxf(m, mc);
        float scale = (den > 0.f) ? expf(m - mnew) : 0.f;
        __syncthreads();
        float lsum = 0.f;
        for (int i = l; i < cn; i += 64) {
            float p = expf(sp[i] - mnew);
            sp[i] = p;
            lsum += p;
        }
        for (int off = 32; off; off >>= 1) lsum += __shfl_xor(lsum, off);
        den = den * scale + lsum;
        acc0 *= scale; acc1 *= scale;
        __syncthreads();
        for (int i = 0; i < cn; i++) {
            float p = sp[i];
            const float* hp = h + (size_t)ssrc[i] * G;
            acc0 += p * hp[l];
            acc1 += p * hp[l + 64];
        }
        __syncthreads();
        m = mnew;
    }
    float inv = 1.f / (den + 1e-16f);
    int f32 = flags[0];
    float o0 = acc0 * inv + ldf(bias, l, f32);
    float o1 = acc1 * inv + ldf(bias, l + 64, f32);
    outbuf[(size_t)d * G + l]      = selu_f(o0);
    outbuf[(size_t)d * G + l + 64] = selu_f(o1);
}

// ---------------- pool + head ----------------
__global__ void pool_kernel(const float* __restrict__ h, const void* __restrict__ batch,
                            float* __restrict__ gsum, const int* __restrict__ flags) {
    int t = threadIdx.x;  // 128
    int i64 = flags[1];
    int i0 = blockIdx.x * POOL_NODES;
    int i1 = min(N_NODES, i0 + POOL_NODES);
    int cur = -1;
    float acc = 0.f;
    for (int i = i0; i < i1; i++) {
        int g = min(max(ldi(batch, i, i64), 0), NGRAPH - 1);
        if (g != cur) {
            if (cur >= 0) atomicAdd(&gsum[cur * G + t], acc);
            cur = g; acc = 0.f;
        }
        acc += h[(size_t)i * G + t];
    }
    if (cur >= 0) atomicAdd(&gsum[cur * G + t], acc);
}

__global__ void count_kernel(const void* __restrict__ batch, float* __restrict__ gcnt,
                             const int* __restrict__ flags) {
    __shared__ int hist[NGRAPH];
    int t = threadIdx.x;
    if (t < NGRAPH) hist[t] = 0;
    __syncthreads();
    int i = blockIdx.x * 256 + t;
    if (i < N_NODES) {
        int g = min(max(ldi(batch, i, flags[1]), 0), NGRAPH - 1);
        atomicAdd(&hist[g], 1);
    }
    __syncthreads();
    if (t < NGRAPH && hist[t] != 0) atomicAdd(&gcnt[t], (float)hist[t]);
}

// pooled -> selu -> lin1+selu -> lin2 -> log_softmax; OUTPUT FLOAT32
__global__ void head_kernel(const float* __restrict__ gsum, const float* __restrict__ gcnt,
                            const void* __restrict__ lw1, const void* __restrict__ lb1,
                            const void* __restrict__ lw2, const void* __restrict__ lb2,
                            float* __restrict__ out, const int* __restrict__ flags) {
    int g = blockIdx.x, t = threadIdx.x;  // 64
    int f32 = flags[0];
    __shared__ float z[G];
    __shared__ float z1[NHID];
    __shared__ float z2[2];
    float cnt = fmaxf(gcnt[g], 1.0f);
    z[t]      = selu_f(gsum[g * G + t] / cnt);
    z[t + 64] = selu_f(gsum[g * G + 64 + t] / cnt);
    __syncthreads();
    float a = ldf(lb1, t, f32);
    for (int k = 0; k < G; k++) a += z[k] * ldf(lw1, k * NHID + t, f32);
    z1[t] = selu_f(a);
    __syncthreads();
    if (t < 2) {
        float s = ldf(lb2, t, f32);
        for (int j = 0; j < NHID; j++) s += z1[j] * ldf(lw2, j * 2 + t, f32);
        z2[t] = s;
    }
    __syncthreads();
    if (t == 0) {
        float mx = fmaxf(z2[0], z2[1]);
        float l = mx + logf(expf(z2[0] - mx) + expf(z2[1] - mx));
        out[g * 2 + 0] = z2[0] - l;
        out[g * 2 + 1] = z2[1] - l;
    }
}

extern "C" void kernel_launch(void* const* d_in, const int* in_sizes, int n_in,
                              void* d_out, int out_size, void* d_ws, size_t ws_size,
                              hipStream_t stream) {
    const void* x    = d_in[0];
    const void* ei   = d_in[1];
    const void* batch= d_in[2];
    const void* W1   = d_in[3];
    const void* as1  = d_in[4];
    const void* ad1  = d_in[5];
    const void* b1   = d_in[6];
    const void* W2   = d_in[7];
    const void* as2  = d_in[8];
    const void* ad2  = d_in[9];
    const void* b2   = d_in[10];
    const void* lw1  = d_in[11];
    const void* lb1  = d_in[12];
    const void* lw2  = d_in[13];
    const void* lb2  = d_in[14];
    float* out = (float*)d_out;

    char* w = (char*)d_ws;
    size_t off = 0;
    auto alloc = [&](size_t bytes) -> char* {
        char* p = w + off;
        off = (off + bytes + 255) & ~(size_t)255;
        return p;
    };
    int*    flags  = (int*)alloc(256);
    float*  hbuf   = (float*)alloc((size_t)N_NODES * G * 4);
    float*  abuf   = (float*)alloc((size_t)N_NODES * G * 4);
    float*  es     = (float*)alloc((size_t)N_NODES * 4);
    float*  edv    = (float*)alloc((size_t)N_NODES * 4);
    int*    deg    = (int*)alloc((size_t)N_NODES * 4);
    int*    rowptr = (int*)alloc((size_t)(N_NODES + 1) * 4);
    int*    cursor = (int*)alloc((size_t)N_NODES * 4);
    int*    csum   = (int*)alloc((size_t)NCHUNK * 4);
    int*    srcs   = (int*)alloc((size_t)ET * 4);
    float*  gsum   = (float*)alloc((size_t)NGRAPH * G * 4);
    float*  gcnt   = (float*)alloc((size_t)NGRAPH * 4);
    ushort* wt1_hi = (ushort*)alloc((size_t)IN_F * G * 2);
    ushort* wt1_lo = (ushort*)alloc((size_t)IN_F * G * 2);
    ushort* wt2_hi = (ushort*)alloc((size_t)G * G * 2);
    ushort* wt2_lo = (ushort*)alloc((size_t)G * G * 2);

    unsigned eb = (ET + 255) / 256;
    unsigned gemm_grid = (N_NODES + 31) / 32;   // N-split: 32 rows/block

    detect_kernel<<<1, 64, 0, stream>>>(x, ei, flags);

    // ---------------- CSR build (once) ----------------
    zero_int_kernel<<<(N_NODES + 255) / 256, 256, 0, stream>>>(deg, N_NODES);
    deg_kernel<<<eb, 256, 0, stream>>>(ei, deg, flags);
    chunk_sum_kernel<<<NCHUNK, 256, 0, stream>>>(deg, csum);
    scan_csum_kernel<<<1, 64, 0, stream>>>(csum);
    chunk_scan_kernel<<<NCHUNK, 256, 0, stream>>>(deg, csum, rowptr, cursor);
    fill_kernel<<<eb, 256, 0, stream>>>(ei, cursor, srcs, flags);

    // ---------------- W split/transpose (once per layer) ----------------
    wt_kernel<<<(IN_F * G + 255) / 256, 256, 0, stream>>>(W1, wt1_hi, wt1_lo, IN_F, flags);
    wt_kernel<<<(G * G + 255) / 256, 256, 0, stream>>>(W2, wt2_hi, wt2_lo, G, flags);

    // ---------------- Layer 1 (gemm + fused ead) ----------------
    gemm_mfma_kernel<IN_F><<<gemm_grid, 256, 0, stream>>>(x, wt1_hi, wt1_lo, hbuf,
                                                          0, flags, as1, ad1, es, edv);
    gat_agg_kernel<<<N_NODES, 64, 0, stream>>>(hbuf, rowptr, srcs, es, edv, b1, abuf, flags);

    // ---------------- Layer 2 (gemm + fused ead) ----------------
    gemm_mfma_kernel<G><<<gemm_grid, 256, 0, stream>>>(abuf, wt2_hi, wt2_lo, hbuf,
                                                       1, flags, as2, ad2, es, edv);
    gat_agg_kernel<<<N_NODES, 64, 0, stream>>>(hbuf, rowptr, srcs, es, edv, b2, abuf, flags);

    // ---------------- Pool + head ----------------
    zero_float_kernel<<<(NGRAPH * G + 255) / 256, 256, 0, stream>>>(gsum, NGRAPH * G);
    zero_float_kernel<<<1, 256, 0, stream>>>(gcnt, NGRAPH);
    pool_kernel<<<(N_NODES + POOL_NODES - 1) / POOL_NODES, 128, 0, stream>>>(abuf, batch, gsum, flags);
    count_kernel<<<(N_NODES + 255) / 256, 256, 0, stream>>>(batch, gcnt, flags);
    head_kernel<<<NGRAPH, 64, 0, stream>>>(gsum, gcnt, lw1, lb1, lw2, lb2, out, flags);
}

// Round 10
// 432.792 us; speedup vs baseline: 4.5087x; 1.1598x over previous
//
#include <hip/hip_runtime.h>
#include <hip/hip_bf16.h>
#include <math.h>

#define N_NODES 50000
#define N_EDGES 800000
#define ET (N_EDGES + N_NODES)   // edges + self loops
#define IN_F 256
#define G 128                    // 2*HID
#define NHID 64
#define NGRAPH 32
#define NCHUNK ((N_NODES + 255) / 256)   // 196
#define CHUNK 1024                        // edges per LDS softmax chunk
#define POOL_NODES 64

typedef __hip_bfloat16 bf16;
typedef unsigned short ushort;
typedef __attribute__((ext_vector_type(8))) short short8;
typedef __attribute__((ext_vector_type(4))) float f32x4;

// ---------- dtype-agnostic loads (flags resolved at runtime, wave-uniform) ----------
__device__ __forceinline__ float bf2f(ushort u) {
    union { unsigned u; float f; } c; c.u = ((unsigned)u) << 16; return c.f;
}
// round-to-nearest-even f32 -> bf16 (finite inputs)
__device__ __forceinline__ ushort f2bf(float f) {
    unsigned u = __float_as_uint(f);
    u += 0x7FFFu + ((u >> 16) & 1u);
    return (ushort)(u >> 16);
}
__device__ __forceinline__ float ldf(const void* p, long i, int f32) {
    return f32 ? ((const float*)p)[i] : bf2f(((const ushort*)p)[i]);
}
__device__ __forceinline__ int ldi(const void* p, long i, int i64) {
    return i64 ? (int)((const long long*)p)[i] : ((const int*)p)[i];
}

__device__ __forceinline__ float selu_f(float x) {
    const float sc = 1.0507009873554805f, al = 1.6732632423543772f;
    return x > 0.f ? sc * x : sc * al * expm1f(x);
}

// async global->LDS, 16 B/lane; lds base must be wave-uniform (data lands at
// base + lane*16). gfx950: emits global_load_lds_dwordx4.
typedef const __attribute__((address_space(1))) void gas_void;
typedef __attribute__((address_space(3))) void las_void;
__device__ __forceinline__ void stage16(const void* g, void* l) {
    __builtin_amdgcn_global_load_lds((gas_void*)g, (las_void*)l, 16, 0, 0);
}

// flags[0]=1 -> float inputs are f32 (else bf16); flags[1]=1 -> ints are int64.
__global__ void detect_kernel(const void* x, const void* ei, int* flags) {
    int l = threadIdx.x;  // 64
    const unsigned* xu = (const unsigned*)x;
    const long NW = (long)N_NODES * IN_F / 2;
    long stride = NW / 1024;
    int sane = 0;
    for (int k = l; k < 1024; k += 64) {
        unsigned u = xu[(long)k * stride];
        unsigned e = (u >> 23) & 0xFF;
        if (u == 0u || (e >= 100 && e <= 140)) sane++;
    }
    const unsigned* wu = (const unsigned*)ei;
    int nz = 0;
    for (int k = l; k < 1024; k += 64) {
        long j = ((long)k * 1562) | 1;
        nz += (wu[j] != 0u);
    }
    for (int off = 32; off; off >>= 1) {
        sane += __shfl_xor(sane, off);
        nz   += __shfl_xor(nz, off);
    }
    if (l == 0) {
        flags[0] = (sane >= 512) ? 1 : 0;
        flags[1] = (nz < 16) ? 1 : 0;
    }
}

__global__ void zero_float_kernel(float* __restrict__ p, long n) {
    long i = (long)blockIdx.x * 256 + threadIdx.x;
    if (i < n) p[i] = 0.f;
}
__global__ void zero_int_kernel(int* __restrict__ p, long n) {
    long i = (long)blockIdx.x * 256 + threadIdx.x;
    if (i < n) p[i] = 0;
}

__device__ __forceinline__ void edge_sd(const void* __restrict__ ei, int e, int i64,
                                        int& s, int& d) {
    if (e < N_EDGES) {
        s = ldi(ei, e, i64);
        d = ldi(ei, (long)N_EDGES + e, i64);
        s = min(max(s, 0), N_NODES - 1);
        d = min(max(d, 0), N_NODES - 1);
    } else {
        s = d = e - N_EDGES;
    }
}

// ---------------- CSR build (once; graph is layer-invariant) ----------------
__global__ void deg_kernel(const void* __restrict__ ei, int* __restrict__ deg,
                           const int* __restrict__ flags) {
    int e = blockIdx.x * 256 + threadIdx.x;
    if (e >= ET) return;
    int s, d; edge_sd(ei, e, flags[1], s, d);
    atomicAdd(&deg[d], 1);
}

__global__ void chunk_sum_kernel(const int* __restrict__ deg, int* __restrict__ csum) {
    __shared__ int sd[256];
    int t = threadIdx.x;
    int i = blockIdx.x * 256 + t;
    sd[t] = (i < N_NODES) ? deg[i] : 0;
    __syncthreads();
    for (int off = 128; off; off >>= 1) {
        if (t < off) sd[t] += sd[t + off];
        __syncthreads();
    }
    if (t == 0) csum[blockIdx.x] = sd[0];
}

__global__ void scan_csum_kernel(int* __restrict__ csum) {  // in-place exclusive
    if (threadIdx.x != 0 || blockIdx.x != 0) return;
    int acc = 0;
    for (int i = 0; i < NCHUNK; i++) { int v = csum[i]; csum[i] = acc; acc += v; }
}

__global__ void chunk_scan_kernel(const int* __restrict__ deg, const int* __restrict__ csum,
                                  int* __restrict__ rowptr, int* __restrict__ cursor) {
    __shared__ int sd[256];
    int t = threadIdx.x;
    int i = blockIdx.x * 256 + t;
    int v = (i < N_NODES) ? deg[i] : 0;
    sd[t] = v;
    for (int off = 1; off < 256; off <<= 1) {
        __syncthreads();
        int add = (t >= off) ? sd[t - off] : 0;
        __syncthreads();
        sd[t] += add;
    }
    __syncthreads();
    int excl = sd[t] - v + csum[blockIdx.x];
    if (i < N_NODES) { rowptr[i] = excl; cursor[i] = excl; }
    if (i == 0) rowptr[N_NODES] = ET;
}

__global__ void fill_kernel(const void* __restrict__ ei, int* __restrict__ cursor,
                            int* __restrict__ srcs, const int* __restrict__ flags) {
    int e = blockIdx.x * 256 + threadIdx.x;
    if (e >= ET) return;
    int s, d; edge_sd(ei, e, flags[1], s, d);
    int pos = atomicAdd(&cursor[d], 1);
    srcs[pos] = s;
}

// ---------------- GEMM: MFMA split-bf16 (hi+lo) with frag-ordered W ----------------
// Round-9 lesson: B-frag loads strided 512B/lane = 16-line scatter per load ->
// TA-request + latency bound regardless of occupancy. Fix: pre-swizzle W into
// MFMA fragment order so staging is contiguous, stage via global_load_lds,
// ds_read_b128 conflict-free (m97 structure).
// wt layout: frag gf = c*16 + nt*2 + hilo (c = k-chunk of 32); element
// (lane=quad*16+n16, j) = W[k=c*32+quad*8+j][n=nt*16+n16]; 512 shorts/frag.
__global__ void wt_kernel(const void* __restrict__ W, ushort* __restrict__ wt,
                          int K, const int* __restrict__ flags) {
    int i = blockIdx.x * 256 + threadIdx.x;
    if (i >= K * G) return;
    int k = i >> 7, n = i & (G - 1);
    float w = ldf(W, i, flags[0]);
    ushort h = f2bf(w);
    ushort lo = f2bf(w - bf2f(h));
    int c = k >> 5, q = (k >> 3) & 3, j = k & 7;
    int nt = n >> 4, n16 = n & 15;
    int lane = q * 16 + n16;
    size_t base = ((size_t)c * 16 + nt * 2) * 512 + lane * 8 + j;
    wt[base] = h;           // hilo = 0
    wt[base + 512] = lo;    // hilo = 1
}

// Block 256 thr = 4 waves; wave = 16 rows x 128 cols; grid = 782.
// Per 32-k chunk: each wave stages 4 of 16 frags (1KB each, contiguous) into
// LDS; barrier; 16 ds_read_b128 + A global load + in-reg hi/lo split; 24 MFMA.
// Epilogue fuses ead (verified round-8). Layouts (HW-verified): A: m=lane&15,
// k=quad*8+j; B: n=lane&15,k=quad*8+j; C/D: col=lane&15,row=quad*4+reg.
template <int K, bool AF32>
__device__ __forceinline__ void gemm_body(
    const void* __restrict__ A, const ushort* __restrict__ wt, float* __restrict__ C,
    const int* __restrict__ flags, const void* __restrict__ aS,
    const void* __restrict__ aD, float* __restrict__ es, float* __restrict__ edv,
    short8* sB8) {
    constexpr int NC = K / 32;
    int wave = threadIdx.x >> 6, lane = threadIdx.x & 63;
    int quad = lane >> 4, n16 = lane & 15;
    int rb = blockIdx.x * 64 + wave * 16;
    int rowa = min(rb + n16, N_NODES - 1);
    f32x4 acc[8];
#pragma unroll
    for (int t = 0; t < 8; t++) acc[t] = (f32x4){0.f, 0.f, 0.f, 0.f};

    for (int c = 0; c < NC; c++) {
        // stage this wave's 4 frags (contiguous 16B/lane)
#pragma unroll
        for (int i = 0; i < 4; i++) {
            int fw = wave * 4 + i;
            stage16(wt + ((size_t)c * 16 + fw) * 512 + lane * 8, &sB8[fw * 64]);
        }
        // A-frag from global (independent of staging)
        float av[8];
        if (AF32) {
            const float* ap = (const float*)A + (size_t)rowa * K + c * 32 + quad * 8;
            f32x4 a0 = *(const f32x4*)ap;
            f32x4 a1 = *(const f32x4*)(ap + 4);
#pragma unroll
            for (int j = 0; j < 4; j++) { av[j] = a0[j]; av[j + 4] = a1[j]; }
        } else {
            const ushort* ap = (const ushort*)A + (size_t)rowa * K + c * 32 + quad * 8;
#pragma unroll
            for (int j = 0; j < 8; j++) av[j] = bf2f(ap[j]);
        }
        short8 ahi, alo;
#pragma unroll
        for (int j = 0; j < 8; j++) {
            ushort h = f2bf(av[j]);
            ahi[j] = (short)h;
            alo[j] = (short)f2bf(av[j] - bf2f(h));
        }
        __syncthreads();   // staging complete (vmcnt drained at barrier)
#pragma unroll
        for (int nt = 0; nt < 8; nt++) {
            short8 bh = sB8[(nt * 2 + 0) * 64 + lane];
            short8 bl = sB8[(nt * 2 + 1) * 64 + lane];
            acc[nt] = __builtin_amdgcn_mfma_f32_16x16x32_bf16(ahi, bh, acc[nt], 0, 0, 0);
            acc[nt] = __builtin_amdgcn_mfma_f32_16x16x32_bf16(ahi, bl, acc[nt], 0, 0, 0);
            acc[nt] = __builtin_amdgcn_mfma_f32_16x16x32_bf16(alo, bh, acc[nt], 0, 0, 0);
        }
        __syncthreads();   // all waves done reading before next overwrite
    }

    // epilogue: C store + fused ead (es = h.as, ed = h.ad per row)
    int f32 = flags[0];
    float asv[8], adv[8];
#pragma unroll
    for (int nt = 0; nt < 8; nt++) {
        asv[nt] = ldf(aS, nt * 16 + n16, f32);
        adv[nt] = ldf(aD, nt * 16 + n16, f32);
    }
#pragma unroll
    for (int r = 0; r < 4; r++) {
        int ro = rb + quad * 4 + r;
        float s = 0.f, dv = 0.f;
#pragma unroll
        for (int nt = 0; nt < 8; nt++) {
            float v = acc[nt][r];
            if (ro < N_NODES) C[(size_t)ro * G + nt * 16 + n16] = v;
            s += v * asv[nt];
            dv += v * adv[nt];
        }
#pragma unroll
        for (int off = 8; off; off >>= 1) {   // reduce across the 16-lane n16 group
            s += __shfl_xor(s, off);
            dv += __shfl_xor(dv, off);
        }
        if (n16 == 0 && ro < N_NODES) { es[ro] = s; edv[ro] = dv; }
    }
}

template <int K>
__global__ __launch_bounds__(256, 3) void gemm_mfma_kernel(
    const void* __restrict__ A, const ushort* __restrict__ wt, float* __restrict__ C,
    int a_internal, const int* __restrict__ flags,
    const void* __restrict__ aS, const void* __restrict__ aD,
    float* __restrict__ es, float* __restrict__ edv) {
    __shared__ short8 sB8[16 * 64];   // 16 frags x 1 KB = 16 KB
    int af32 = a_internal ? 1 : flags[0];   // block-uniform
    if (af32) gemm_body<K, true>(A, wt, C, flags, aS, aD, es, edv, sB8);
    else      gemm_body<K, false>(A, wt, C, flags, aS, aD, es, edv, sB8);
}

// Fused GAT aggregate: one wave per dst node. Online softmax over incoming
// edge list (CSR), weighted gather of h[src], normalize, +bias, SELU.
__global__ __launch_bounds__(64) void gat_agg_kernel(
    const float* __restrict__ h, const int* __restrict__ rowptr,
    const int* __restrict__ srcs, const float* __restrict__ es,
    const float* __restrict__ edv, const void* __restrict__ bias,
    float* __restrict__ outbuf, const int* __restrict__ flags) {
    int d = blockIdx.x;
    int l = threadIdx.x;  // 64
    __shared__ float sp[CHUNK];
    __shared__ int ssrc[CHUNK];
    int start = rowptr[d], end = rowptr[d + 1];
    float edd = edv[d];
    float m = -INFINITY, den = 0.f;
    float acc0 = 0.f, acc1 = 0.f;
    for (int c0 = start; c0 < end; c0 += CHUNK) {
        int cn = min(end - c0, CHUNK);
        float mc = -INFINITY;
        for (int i = l; i < cn; i += 64) {
            int s = srcs[c0 + i];
            ssrc[i] = s;
            float v = es[s] + edd;
            v = v >= 0.f ? v : 0.2f * v;  // LeakyReLU(0.2)
            sp[i] = v;
            mc = fmaxf(mc, v);
        }
        for (int off = 32; off; off >>= 1) mc = fmaxf(mc, __shfl_xor(mc, off));
        float mnew = fmaxf(m, mc);
        float scale = (den > 0.f) ? expf(m - mnew) : 0.f;
        __syncthreads();
        float lsum = 0.f;
        for (int i = l; i < cn; i += 64) {
            float p = expf(sp[i] - mnew);
            sp[i] = p;
            lsum += p;
        }
        for (int off = 32; off; off >>= 1) lsum += __shfl_xor(lsum, off);
        den = den * scale + lsum;
        acc0 *= scale; acc1 *= scale;
        __syncthreads();
        for (int i = 0; i < cn; i++) {
            float p = sp[i];
            const float* hp = h + (size_t)ssrc[i] * G;
            acc0 += p * hp[l];
            acc1 += p * hp[l + 64];
        }
        __syncthreads();
        m = mnew;
    }
    float inv = 1.f / (den + 1e-16f);
    int f32 = flags[0];
    float o0 = acc0 * inv + ldf(bias, l, f32);
    float o1 = acc1 * inv + ldf(bias, l + 64, f32);
    outbuf[(size_t)d * G + l]      = selu_f(o0);
    outbuf[(size_t)d * G + l + 64] = selu_f(o1);
}

// ---------------- pool + head ----------------
__global__ void pool_kernel(const float* __restrict__ h, const void* __restrict__ batch,
                            float* __restrict__ gsum, const int* __restrict__ flags) {
    int t = threadIdx.x;  // 128
    int i64 = flags[1];
    int i0 = blockIdx.x * POOL_NODES;
    int i1 = min(N_NODES, i0 + POOL_NODES);
    int cur = -1;
    float acc = 0.f;
    for (int i = i0; i < i1; i++) {
        int g = min(max(ldi(batch, i, i64), 0), NGRAPH - 1);
        if (g != cur) {
            if (cur >= 0) atomicAdd(&gsum[cur * G + t], acc);
            cur = g; acc = 0.f;
        }
        acc += h[(size_t)i * G + t];
    }
    if (cur >= 0) atomicAdd(&gsum[cur * G + t], acc);
}

__global__ void count_kernel(const void* __restrict__ batch, float* __restrict__ gcnt,
                             const int* __restrict__ flags) {
    __shared__ int hist[NGRAPH];
    int t = threadIdx.x;
    if (t < NGRAPH) hist[t] = 0;
    __syncthreads();
    int i = blockIdx.x * 256 + t;
    if (i < N_NODES) {
        int g = min(max(ldi(batch, i, flags[1]), 0), NGRAPH - 1);
        atomicAdd(&hist[g], 1);
    }
    __syncthreads();
    if (t < NGRAPH && hist[t] != 0) atomicAdd(&gcnt[t], (float)hist[t]);
}

// pooled -> selu -> lin1+selu -> lin2 -> log_softmax; OUTPUT FLOAT32
__global__ void head_kernel(const float* __restrict__ gsum, const float* __restrict__ gcnt,
                            const void* __restrict__ lw1, const void* __restrict__ lb1,
                            const void* __restrict__ lw2, const void* __restrict__ lb2,
                            float* __restrict__ out, const int* __restrict__ flags) {
    int g = blockIdx.x, t = threadIdx.x;  // 64
    int f32 = flags[0];
    __shared__ float z[G];
    __shared__ float z1[NHID];
    __shared__ float z2[2];
    float cnt = fmaxf(gcnt[g], 1.0f);
    z[t]      = selu_f(gsum[g * G + t] / cnt);
    z[t + 64] = selu_f(gsum[g * G + 64 + t] / cnt);
    __syncthreads();
    float a = ldf(lb1, t, f32);
    for (int k = 0; k < G; k++) a += z[k] * ldf(lw1, k * NHID + t, f32);
    z1[t] = selu_f(a);
    __syncthreads();
    if (t < 2) {
        float s = ldf(lb2, t, f32);
        for (int j = 0; j < NHID; j++) s += z1[j] * ldf(lw2, j * 2 + t, f32);
        z2[t] = s;
    }
    __syncthreads();
    if (t == 0) {
        float mx = fmaxf(z2[0], z2[1]);
        float l = mx + logf(expf(z2[0] - mx) + expf(z2[1] - mx));
        out[g * 2 + 0] = z2[0] - l;
        out[g * 2 + 1] = z2[1] - l;
    }
}

extern "C" void kernel_launch(void* const* d_in, const int* in_sizes, int n_in,
                              void* d_out, int out_size, void* d_ws, size_t ws_size,
                              hipStream_t stream) {
    const void* x    = d_in[0];
    const void* ei   = d_in[1];
    const void* batch= d_in[2];
    const void* W1   = d_in[3];
    const void* as1  = d_in[4];
    const void* ad1  = d_in[5];
    const void* b1   = d_in[6];
    const void* W2   = d_in[7];
    const void* as2  = d_in[8];
    const void* ad2  = d_in[9];
    const void* b2   = d_in[10];
    const void* lw1  = d_in[11];
    const void* lb1  = d_in[12];
    const void* lw2  = d_in[13];
    const void* lb2  = d_in[14];
    float* out = (float*)d_out;

    char* w = (char*)d_ws;
    size_t off = 0;
    auto alloc = [&](size_t bytes) -> char* {
        char* p = w + off;
        off = (off + bytes + 255) & ~(size_t)255;
        return p;
    };
    int*    flags  = (int*)alloc(256);
    float*  hbuf   = (float*)alloc((size_t)N_NODES * G * 4);
    float*  abuf   = (float*)alloc((size_t)N_NODES * G * 4);
    float*  es     = (float*)alloc((size_t)N_NODES * 4);
    float*  edv    = (float*)alloc((size_t)N_NODES * 4);
    int*    deg    = (int*)alloc((size_t)N_NODES * 4);
    int*    rowptr = (int*)alloc((size_t)(N_NODES + 1) * 4);
    int*    cursor = (int*)alloc((size_t)N_NODES * 4);
    int*    csum   = (int*)alloc((size_t)NCHUNK * 4);
    int*    srcs   = (int*)alloc((size_t)ET * 4);
    float*  gsum   = (float*)alloc((size_t)NGRAPH * G * 4);
    float*  gcnt   = (float*)alloc((size_t)NGRAPH * 4);
    ushort* wt1    = (ushort*)alloc((size_t)IN_F * G * 2 * 2);   // hi+lo frag-ordered
    ushort* wt2    = (ushort*)alloc((size_t)G * G * 2 * 2);

    unsigned eb = (ET + 255) / 256;
    unsigned gemm_grid = (N_NODES + 63) / 64;   // 64 rows/block

    detect_kernel<<<1, 64, 0, stream>>>(x, ei, flags);

    // ---------------- CSR build (once) ----------------
    zero_int_kernel<<<(N_NODES + 255) / 256, 256, 0, stream>>>(deg, N_NODES);
    deg_kernel<<<eb, 256, 0, stream>>>(ei, deg, flags);
    chunk_sum_kernel<<<NCHUNK, 256, 0, stream>>>(deg, csum);
    scan_csum_kernel<<<1, 64, 0, stream>>>(csum);
    chunk_scan_kernel<<<NCHUNK, 256, 0, stream>>>(deg, csum, rowptr, cursor);
    fill_kernel<<<eb, 256, 0, stream>>>(ei, cursor, srcs, flags);

    // ---------------- W split/transpose into fragment order (once per layer) ----
    wt_kernel<<<(IN_F * G + 255) / 256, 256, 0, stream>>>(W1, wt1, IN_F, flags);
    wt_kernel<<<(G * G + 255) / 256, 256, 0, stream>>>(W2, wt2, G, flags);

    // ---------------- Layer 1 (gemm + fused ead) ----------------
    gemm_mfma_kernel<IN_F><<<gemm_grid, 256, 0, stream>>>(x, wt1, hbuf,
                                                          0, flags, as1, ad1, es, edv);
    gat_agg_kernel<<<N_NODES, 64, 0, stream>>>(hbuf, rowptr, srcs, es, edv, b1, abuf, flags);

    // ---------------- Layer 2 (gemm + fused ead) ----------------
    gemm_mfma_kernel<G><<<gemm_grid, 256, 0, stream>>>(abuf, wt2, hbuf,
                                                       1, flags, as2, ad2, es, edv);
    gat_agg_kernel<<<N_NODES, 64, 0, stream>>>(hbuf, rowptr, srcs, es, edv, b2, abuf, flags);

    // ---------------- Pool + head ----------------
    zero_float_kernel<<<(NGRAPH * G + 255) / 256, 256, 0, stream>>>(gsum, NGRAPH * G);
    zero_float_kernel<<<1, 256, 0, stream>>>(gcnt, NGRAPH);
    pool_kernel<<<(N_NODES + POOL_NODES - 1) / POOL_NODES, 128, 0, stream>>>(abuf, batch, gsum, flags);
    count_kernel<<<(N_NODES + 255) / 256, 256, 0, stream>>>(batch, gcnt, flags);
    head_kernel<<<NGRAPH, 64, 0, stream>>>(gsum, gcnt, lw1, lb1, lw2, lb2, out, flags);
}

// Round 11
// 430.139 us; speedup vs baseline: 4.5365x; 1.0062x over previous
//
#include <hip/hip_runtime.h>
#include <hip/hip_bf16.h>
#include <math.h>

#define N_NODES 50000
#define N_EDGES 800000
#define ET (N_EDGES + N_NODES)   // edges + self loops
#define IN_F 256
#define G 128                    // 2*HID
#define NHID 64
#define NGRAPH 32
#define NCHUNK ((N_NODES + 255) / 256)   // 196
#define POOL_NODES 64

typedef __hip_bfloat16 bf16;
typedef unsigned short ushort;
typedef __attribute__((ext_vector_type(8))) short short8;
typedef __attribute__((ext_vector_type(4))) float f32x4;

// ---------- dtype-agnostic loads (flags resolved at runtime, wave-uniform) ----------
__device__ __forceinline__ float bf2f(ushort u) {
    union { unsigned u; float f; } c; c.u = ((unsigned)u) << 16; return c.f;
}
// round-to-nearest-even f32 -> bf16 (finite inputs)
__device__ __forceinline__ ushort f2bf(float f) {
    unsigned u = __float_as_uint(f);
    u += 0x7FFFu + ((u >> 16) & 1u);
    return (ushort)(u >> 16);
}
__device__ __forceinline__ float ldf(const void* p, long i, int f32) {
    return f32 ? ((const float*)p)[i] : bf2f(((const ushort*)p)[i]);
}
__device__ __forceinline__ int ldi(const void* p, long i, int i64) {
    return i64 ? (int)((const long long*)p)[i] : ((const int*)p)[i];
}

__device__ __forceinline__ float selu_f(float x) {
    const float sc = 1.0507009873554805f, al = 1.6732632423543772f;
    return x > 0.f ? sc * x : sc * al * expm1f(x);
}

// async global->LDS, 16 B/lane; lds base must be wave-uniform (data lands at
// base + lane*16). gfx950: emits global_load_lds_dwordx4.
typedef const __attribute__((address_space(1))) void gas_void;
typedef __attribute__((address_space(3))) void las_void;
__device__ __forceinline__ void stage16(const void* g, void* l) {
    __builtin_amdgcn_global_load_lds((gas_void*)g, (las_void*)l, 16, 0, 0);
}

// flags[0]=1 -> float inputs are f32 (else bf16); flags[1]=1 -> ints are int64.
__global__ void detect_kernel(const void* x, const void* ei, int* flags) {
    int l = threadIdx.x;  // 64
    const unsigned* xu = (const unsigned*)x;
    const long NW = (long)N_NODES * IN_F / 2;
    long stride = NW / 1024;
    int sane = 0;
    for (int k = l; k < 1024; k += 64) {
        unsigned u = xu[(long)k * stride];
        unsigned e = (u >> 23) & 0xFF;
        if (u == 0u || (e >= 100 && e <= 140)) sane++;
    }
    const unsigned* wu = (const unsigned*)ei;
    int nz = 0;
    for (int k = l; k < 1024; k += 64) {
        long j = ((long)k * 1562) | 1;
        nz += (wu[j] != 0u);
    }
    for (int off = 32; off; off >>= 1) {
        sane += __shfl_xor(sane, off);
        nz   += __shfl_xor(nz, off);
    }
    if (l == 0) {
        flags[0] = (sane >= 512) ? 1 : 0;
        flags[1] = (nz < 16) ? 1 : 0;
    }
}

__global__ void zero_float_kernel(float* __restrict__ p, long n) {
    long i = (long)blockIdx.x * 256 + threadIdx.x;
    if (i < n) p[i] = 0.f;
}
__global__ void zero_int_kernel(int* __restrict__ p, long n) {
    long i = (long)blockIdx.x * 256 + threadIdx.x;
    if (i < n) p[i] = 0;
}

__device__ __forceinline__ void edge_sd(const void* __restrict__ ei, int e, int i64,
                                        int& s, int& d) {
    if (e < N_EDGES) {
        s = ldi(ei, e, i64);
        d = ldi(ei, (long)N_EDGES + e, i64);
        s = min(max(s, 0), N_NODES - 1);
        d = min(max(d, 0), N_NODES - 1);
    } else {
        s = d = e - N_EDGES;
    }
}

// ---------------- CSR build (once; graph is layer-invariant) ----------------
__global__ void deg_kernel(const void* __restrict__ ei, int* __restrict__ deg,
                           const int* __restrict__ flags) {
    int e = blockIdx.x * 256 + threadIdx.x;
    if (e >= ET) return;
    int s, d; edge_sd(ei, e, flags[1], s, d);
    atomicAdd(&deg[d], 1);
}

__global__ void chunk_sum_kernel(const int* __restrict__ deg, int* __restrict__ csum) {
    __shared__ int sd[256];
    int t = threadIdx.x;
    int i = blockIdx.x * 256 + t;
    sd[t] = (i < N_NODES) ? deg[i] : 0;
    __syncthreads();
    for (int off = 128; off; off >>= 1) {
        if (t < off) sd[t] += sd[t + off];
        __syncthreads();
    }
    if (t == 0) csum[blockIdx.x] = sd[0];
}

__global__ void scan_csum_kernel(int* __restrict__ csum) {  // in-place exclusive
    if (threadIdx.x != 0 || blockIdx.x != 0) return;
    int acc = 0;
    for (int i = 0; i < NCHUNK; i++) { int v = csum[i]; csum[i] = acc; acc += v; }
}

__global__ void chunk_scan_kernel(const int* __restrict__ deg, const int* __restrict__ csum,
                                  int* __restrict__ rowptr, int* __restrict__ cursor) {
    __shared__ int sd[256];
    int t = threadIdx.x;
    int i = blockIdx.x * 256 + t;
    int v = (i < N_NODES) ? deg[i] : 0;
    sd[t] = v;
    for (int off = 1; off < 256; off <<= 1) {
        __syncthreads();
        int add = (t >= off) ? sd[t - off] : 0;
        __syncthreads();
        sd[t] += add;
    }
    __syncthreads();
    int excl = sd[t] - v + csum[blockIdx.x];
    if (i < N_NODES) { rowptr[i] = excl; cursor[i] = excl; }
    if (i == 0) rowptr[N_NODES] = ET;
}

__global__ void fill_kernel(const void* __restrict__ ei, int* __restrict__ cursor,
                            int* __restrict__ srcs, const int* __restrict__ flags) {
    int e = blockIdx.x * 256 + threadIdx.x;
    if (e >= ET) return;
    int s, d; edge_sd(ei, e, flags[1], s, d);
    int pos = atomicAdd(&cursor[d], 1);
    srcs[pos] = s;
}

// ---------------- GEMM: MFMA split-bf16 (hi+lo) with frag-ordered W ----------------
// wt layout: frag gf = c*16 + nt*2 + hilo (c = k-chunk of 32); element
// (lane=quad*16+n16, j) = W[k=c*32+quad*8+j][n=nt*16+n16]; 512 shorts/frag.
__global__ void wt_kernel(const void* __restrict__ W, ushort* __restrict__ wt,
                          int K, const int* __restrict__ flags) {
    int i = blockIdx.x * 256 + threadIdx.x;
    if (i >= K * G) return;
    int k = i >> 7, n = i & (G - 1);
    float w = ldf(W, i, flags[0]);
    ushort h = f2bf(w);
    ushort lo = f2bf(w - bf2f(h));
    int c = k >> 5, q = (k >> 3) & 3, j = k & 7;
    int nt = n >> 4, n16 = n & 15;
    int lane = q * 16 + n16;
    size_t base = ((size_t)c * 16 + nt * 2) * 512 + lane * 8 + j;
    wt[base] = h;           // hilo = 0
    wt[base + 512] = lo;    // hilo = 1
}

// Block 256 thr = 4 waves; wave = 16 rows x 128 cols; grid = 782.
// Output H2: packed bf16x2, word l of a row = {f_l, f_{l+64}} -> the gather
// reads ONE 256B wave-load per edge (round-10: 193MB FETCH on f32 gather).
// es/ed computed from f32 accs (fused ead). Layouts HW-verified (rounds 7-10).
template <int K, bool AF32>
__device__ __forceinline__ void gemm_body(
    const void* __restrict__ A, const ushort* __restrict__ wt,
    unsigned* __restrict__ H2, const int* __restrict__ flags,
    const void* __restrict__ aS, const void* __restrict__ aD,
    float* __restrict__ es, float* __restrict__ edv, short8* sB8) {
    constexpr int NC = K / 32;
    int wave = threadIdx.x >> 6, lane = threadIdx.x & 63;
    int quad = lane >> 4, n16 = lane & 15;
    int rb = blockIdx.x * 64 + wave * 16;
    int rowa = min(rb + n16, N_NODES - 1);
    f32x4 acc[8];
#pragma unroll
    for (int t = 0; t < 8; t++) acc[t] = (f32x4){0.f, 0.f, 0.f, 0.f};

    for (int c = 0; c < NC; c++) {
#pragma unroll
        for (int i = 0; i < 4; i++) {
            int fw = wave * 4 + i;
            stage16(wt + ((size_t)c * 16 + fw) * 512 + lane * 8, &sB8[fw * 64]);
        }
        float av[8];
        if (AF32) {
            const float* ap = (const float*)A + (size_t)rowa * K + c * 32 + quad * 8;
            f32x4 a0 = *(const f32x4*)ap;
            f32x4 a1 = *(const f32x4*)(ap + 4);
#pragma unroll
            for (int j = 0; j < 4; j++) { av[j] = a0[j]; av[j + 4] = a1[j]; }
        } else {
            const ushort* ap = (const ushort*)A + (size_t)rowa * K + c * 32 + quad * 8;
#pragma unroll
            for (int j = 0; j < 8; j++) av[j] = bf2f(ap[j]);
        }
        short8 ahi, alo;
#pragma unroll
        for (int j = 0; j < 8; j++) {
            ushort h = f2bf(av[j]);
            ahi[j] = (short)h;
            alo[j] = (short)f2bf(av[j] - bf2f(h));
        }
        __syncthreads();   // staging complete
#pragma unroll
        for (int nt = 0; nt < 8; nt++) {
            short8 bh = sB8[(nt * 2 + 0) * 64 + lane];
            short8 bl = sB8[(nt * 2 + 1) * 64 + lane];
            acc[nt] = __builtin_amdgcn_mfma_f32_16x16x32_bf16(ahi, bh, acc[nt], 0, 0, 0);
            acc[nt] = __builtin_amdgcn_mfma_f32_16x16x32_bf16(ahi, bl, acc[nt], 0, 0, 0);
            acc[nt] = __builtin_amdgcn_mfma_f32_16x16x32_bf16(alo, bh, acc[nt], 0, 0, 0);
        }
        __syncthreads();
    }

    // epilogue: packed-bf16 H2 store + fused ead from f32 accs
    int f32 = flags[0];
    float asv[8], adv[8];
#pragma unroll
    for (int nt = 0; nt < 8; nt++) {
        asv[nt] = ldf(aS, nt * 16 + n16, f32);
        adv[nt] = ldf(aD, nt * 16 + n16, f32);
    }
#pragma unroll
    for (int r = 0; r < 4; r++) {
        int ro = rb + quad * 4 + r;
        float s = 0.f, dv = 0.f;
#pragma unroll
        for (int nt = 0; nt < 8; nt++) {
            s += acc[nt][r] * asv[nt];
            dv += acc[nt][r] * adv[nt];
        }
        if (ro < N_NODES) {
#pragma unroll
            for (int nt = 0; nt < 4; nt++) {   // word c = {f_c, f_{c+64}}
                unsigned pack = (unsigned)f2bf(acc[nt][r]) |
                                ((unsigned)f2bf(acc[nt + 4][r]) << 16);
                H2[(size_t)ro * 64 + nt * 16 + n16] = pack;
            }
        }
#pragma unroll
        for (int off = 8; off; off >>= 1) {
            s += __shfl_xor(s, off);
            dv += __shfl_xor(dv, off);
        }
        if (n16 == 0 && ro < N_NODES) { es[ro] = s; edv[ro] = dv; }
    }
}

template <int K>
__global__ __launch_bounds__(256, 3) void gemm_mfma_kernel(
    const void* __restrict__ A, const ushort* __restrict__ wt,
    unsigned* __restrict__ H2, int a_internal, const int* __restrict__ flags,
    const void* __restrict__ aS, const void* __restrict__ aD,
    float* __restrict__ es, float* __restrict__ edv) {
    __shared__ short8 sB8[16 * 64];   // 16 frags x 1 KB = 16 KB
    int af32 = a_internal ? 1 : flags[0];   // block-uniform
    if (af32) gemm_body<K, true>(A, wt, H2, flags, aS, aD, es, edv, sB8);
    else      gemm_body<K, false>(A, wt, H2, flags, aS, aD, es, edv, sB8);
}

// Fused GAT aggregate v2: 4 independent waves per 256-thr block (no LDS, no
// barriers -> occupancy ceiling 32 waves/CU vs round-10's 16 1-wave blocks).
// 64-edge register chunks; per-edge broadcast via shuffles; gather is ONE
// 256B packed-bf16 wave-load per edge.
__global__ __launch_bounds__(256) void gat_agg_kernel(
    const unsigned* __restrict__ h2, const int* __restrict__ rowptr,
    const int* __restrict__ srcs, const float* __restrict__ es,
    const float* __restrict__ edv, const void* __restrict__ bias,
    float* __restrict__ outbuf, const int* __restrict__ flags) {
    int node = blockIdx.x * 4 + (threadIdx.x >> 6);
    if (node >= N_NODES) return;            // wave-uniform exit, no barriers used
    int l = threadIdx.x & 63;
    int start = rowptr[node], end = rowptr[node + 1];
    float edd = edv[node];
    float m = -INFINITY, den = 0.f;
    float acc0 = 0.f, acc1 = 0.f;
    for (int c0 = start; c0 < end; c0 += 64) {
        int cn = min(end - c0, 64);
        int s = 0; float v = -INFINITY;
        if (l < cn) {
            s = srcs[c0 + l];
            v = es[s] + edd;
            v = v >= 0.f ? v : 0.2f * v;    // LeakyReLU(0.2)
        }
        float mc = v;
#pragma unroll
        for (int off = 32; off; off >>= 1) mc = fmaxf(mc, __shfl_xor(mc, off));
        float mnew = fmaxf(m, mc);
        float scale = expf(m - mnew);        // m=-INF first chunk -> 0
        float p = (l < cn) ? expf(v - mnew) : 0.f;
        float lsum = p;
#pragma unroll
        for (int off = 32; off; off >>= 1) lsum += __shfl_xor(lsum, off);
        den = den * scale + lsum;
        acc0 *= scale; acc1 *= scale;
        for (int i = 0; i < cn; i++) {
            float pi = __shfl(p, i);
            int si = __shfl(s, i);
            unsigned hv = h2[(size_t)si * 64 + l];
            acc0 += pi * bf2f((ushort)(hv & 0xFFFFu));
            acc1 += pi * bf2f((ushort)(hv >> 16));
        }
        m = mnew;
    }
    float inv = 1.f / (den + 1e-16f);
    int f32 = flags[0];
    float o0 = acc0 * inv + ldf(bias, l, f32);
    float o1 = acc1 * inv + ldf(bias, l + 64, f32);
    outbuf[(size_t)node * G + l]      = selu_f(o0);
    outbuf[(size_t)node * G + l + 64] = selu_f(o1);
}

// ---------------- pool + head ----------------
__global__ void pool_kernel(const float* __restrict__ h, const void* __restrict__ batch,
                            float* __restrict__ gsum, const int* __restrict__ flags) {
    int t = threadIdx.x;  // 128
    int i64 = flags[1];
    int i0 = blockIdx.x * POOL_NODES;
    int i1 = min(N_NODES, i0 + POOL_NODES);
    int cur = -1;
    float acc = 0.f;
    for (int i = i0; i < i1; i++) {
        int g = min(max(ldi(batch, i, i64), 0), NGRAPH - 1);
        if (g != cur) {
            if (cur >= 0) atomicAdd(&gsum[cur * G + t], acc);
            cur = g; acc = 0.f;
        }
        acc += h[(size_t)i * G + t];
    }
    if (cur >= 0) atomicAdd(&gsum[cur * G + t], acc);
}

__global__ void count_kernel(const void* __restrict__ batch, float* __restrict__ gcnt,
                             const int* __restrict__ flags) {
    __shared__ int hist[NGRAPH];
    int t = threadIdx.x;
    if (t < NGRAPH) hist[t] = 0;
    __syncthreads();
    int i = blockIdx.x * 256 + t;
    if (i < N_NODES) {
        int g = min(max(ldi(batch, i, flags[1]), 0), NGRAPH - 1);
        atomicAdd(&hist[g], 1);
    }
    __syncthreads();
    if (t < NGRAPH && hist[t] != 0) atomicAdd(&gcnt[t], (float)hist[t]);
}

// pooled -> selu -> lin1+selu -> lin2 -> log_softmax; OUTPUT FLOAT32
__global__ void head_kernel(const float* __restrict__ gsum, const float* __restrict__ gcnt,
                            const void* __restrict__ lw1, const void* __restrict__ lb1,
                            const void* __restrict__ lw2, const void* __restrict__ lb2,
                            float* __restrict__ out, const int* __restrict__ flags) {
    int g = blockIdx.x, t = threadIdx.x;  // 64
    int f32 = flags[0];
    __shared__ float z[G];
    __shared__ float z1[NHID];
    __shared__ float z2[2];
    float cnt = fmaxf(gcnt[g], 1.0f);
    z[t]      = selu_f(gsum[g * G + t] / cnt);
    z[t + 64] = selu_f(gsum[g * G + 64 + t] / cnt);
    __syncthreads();
    float a = ldf(lb1, t, f32);
    for (int k = 0; k < G; k++) a += z[k] * ldf(lw1, k * NHID + t, f32);
    z1[t] = selu_f(a);
    __syncthreads();
    if (t < 2) {
        float s = ldf(lb2, t, f32);
        for (int j = 0; j < NHID; j++) s += z1[j] * ldf(lw2, j * 2 + t, f32);
        z2[t] = s;
    }
    __syncthreads();
    if (t == 0) {
        float mx = fmaxf(z2[0], z2[1]);
        float l = mx + logf(expf(z2[0] - mx) + expf(z2[1] - mx));
        out[g * 2 + 0] = z2[0] - l;
        out[g * 2 + 1] = z2[1] - l;
    }
}

extern "C" void kernel_launch(void* const* d_in, const int* in_sizes, int n_in,
                              void* d_out, int out_size, void* d_ws, size_t ws_size,
                              hipStream_t stream) {
    const void* x    = d_in[0];
    const void* ei   = d_in[1];
    const void* batch= d_in[2];
    const void* W1   = d_in[3];
    const void* as1  = d_in[4];
    const void* ad1  = d_in[5];
    const void* b1   = d_in[6];
    const void* W2   = d_in[7];
    const void* as2  = d_in[8];
    const void* ad2  = d_in[9];
    const void* b2   = d_in[10];
    const void* lw1  = d_in[11];
    const void* lb1  = d_in[12];
    const void* lw2  = d_in[13];
    const void* lb2  = d_in[14];
    float* out = (float*)d_out;

    char* w = (char*)d_ws;
    size_t off = 0;
    auto alloc = [&](size_t bytes) -> char* {
        char* p = w + off;
        off = (off + bytes + 255) & ~(size_t)255;
        return p;
    };
    int*      flags  = (int*)alloc(256);
    unsigned* h2     = (unsigned*)alloc((size_t)N_NODES * 64 * 4);  // packed bf16x2
    float*    abuf   = (float*)alloc((size_t)N_NODES * G * 4);
    float*    es     = (float*)alloc((size_t)N_NODES * 4);
    float*    edv    = (float*)alloc((size_t)N_NODES * 4);
    int*      deg    = (int*)alloc((size_t)N_NODES * 4);
    int*      rowptr = (int*)alloc((size_t)(N_NODES + 1) * 4);
    int*      cursor = (int*)alloc((size_t)N_NODES * 4);
    int*      csum   = (int*)alloc((size_t)NCHUNK * 4);
    int*      srcs   = (int*)alloc((size_t)ET * 4);
    float*    gsum   = (float*)alloc((size_t)NGRAPH * G * 4);
    float*    gcnt   = (float*)alloc((size_t)NGRAPH * 4);
    ushort*   wt1    = (ushort*)alloc((size_t)IN_F * G * 2 * 2);   // hi+lo frag-ordered
    ushort*   wt2    = (ushort*)alloc((size_t)G * G * 2 * 2);

    unsigned eb = (ET + 255) / 256;
    unsigned gemm_grid = (N_NODES + 63) / 64;
    unsigned agg_grid = (N_NODES + 3) / 4;

    detect_kernel<<<1, 64, 0, stream>>>(x, ei, flags);

    // ---------------- CSR build (once) ----------------
    zero_int_kernel<<<(N_NODES + 255) / 256, 256, 0, stream>>>(deg, N_NODES);
    deg_kernel<<<eb, 256, 0, stream>>>(ei, deg, flags);
    chunk_sum_kernel<<<NCHUNK, 256, 0, stream>>>(deg, csum);
    scan_csum_kernel<<<1, 64, 0, stream>>>(csum);
    chunk_scan_kernel<<<NCHUNK, 256, 0, stream>>>(deg, csum, rowptr, cursor);
    fill_kernel<<<eb, 256, 0, stream>>>(ei, cursor, srcs, flags);

    // ---------------- W split/transpose into fragment order (once per layer) ----
    wt_kernel<<<(IN_F * G + 255) / 256, 256, 0, stream>>>(W1, wt1, IN_F, flags);
    wt_kernel<<<(G * G + 255) / 256, 256, 0, stream>>>(W2, wt2, G, flags);

    // ---------------- Layer 1 (gemm + fused ead -> packed h2) ----------------
    gemm_mfma_kernel<IN_F><<<gemm_grid, 256, 0, stream>>>(x, wt1, h2,
                                                          0, flags, as1, ad1, es, edv);
    gat_agg_kernel<<<agg_grid, 256, 0, stream>>>(h2, rowptr, srcs, es, edv, b1, abuf, flags);

    // ---------------- Layer 2 (gemm + fused ead -> packed h2) ----------------
    gemm_mfma_kernel<G><<<gemm_grid, 256, 0, stream>>>(abuf, wt2, h2,
                                                       1, flags, as2, ad2, es, edv);
    gat_agg_kernel<<<agg_grid, 256, 0, stream>>>(h2, rowptr, srcs, es, edv, b2, abuf, flags);

    // ---------------- Pool + head ----------------
    zero_float_kernel<<<(NGRAPH * G + 255) / 256, 256, 0, stream>>>(gsum, NGRAPH * G);
    zero_float_kernel<<<1, 256, 0, stream>>>(gcnt, NGRAPH);
    pool_kernel<<<(N_NODES + POOL_NODES - 1) / POOL_NODES, 128, 0, stream>>>(abuf, batch, gsum, flags);
    count_kernel<<<(N_NODES + 255) / 256, 256, 0, stream>>>(batch, gcnt, flags);
    head_kernel<<<NGRAPH, 64, 0, stream>>>(gsum, gcnt, lw1, lb1, lw2, lb2, out, flags);
}

// Round 12
// 418.154 us; speedup vs baseline: 4.6666x; 1.0287x over previous
//
#include <hip/hip_runtime.h>
#include <hip/hip_bf16.h>
#include <math.h>

#define N_NODES 50000
#define N_EDGES 800000
#define ET (N_EDGES + N_NODES)   // edges + self loops
#define IN_F 256
#define G 128                    // 2*HID
#define NHID 64
#define NGRAPH 32
#define NCHUNK ((N_NODES + 255) / 256)   // 196
#define POOL_NODES 64

typedef __hip_bfloat16 bf16;
typedef unsigned short ushort;
typedef __attribute__((ext_vector_type(8))) short short8;
typedef __attribute__((ext_vector_type(4))) float f32x4;

// ---------- dtype-agnostic loads (flags resolved at runtime, wave-uniform) ----------
__device__ __forceinline__ float bf2f(ushort u) {
    union { unsigned u; float f; } c; c.u = ((unsigned)u) << 16; return c.f;
}
// round-to-nearest-even f32 -> bf16 (finite inputs)
__device__ __forceinline__ ushort f2bf(float f) {
    unsigned u = __float_as_uint(f);
    u += 0x7FFFu + ((u >> 16) & 1u);
    return (ushort)(u >> 16);
}
__device__ __forceinline__ float ldf(const void* p, long i, int f32) {
    return f32 ? ((const float*)p)[i] : bf2f(((const ushort*)p)[i]);
}
__device__ __forceinline__ int ldi(const void* p, long i, int i64) {
    return i64 ? (int)((const long long*)p)[i] : ((const int*)p)[i];
}

__device__ __forceinline__ float selu_f(float x) {
    const float sc = 1.0507009873554805f, al = 1.6732632423543772f;
    return x > 0.f ? sc * x : sc * al * expm1f(x);
}

// async global->LDS, 16 B/lane; lds base must be wave-uniform.
typedef const __attribute__((address_space(1))) void gas_void;
typedef __attribute__((address_space(3))) void las_void;
__device__ __forceinline__ void stage16(const void* g, void* l) {
    __builtin_amdgcn_global_load_lds((gas_void*)g, (las_void*)l, 16, 0, 0);
}

// flags[0]=1 -> float inputs are f32 (else bf16); flags[1]=1 -> ints are int64.
__global__ void detect_kernel(const void* x, const void* ei, int* flags) {
    int l = threadIdx.x;  // 64
    const unsigned* xu = (const unsigned*)x;
    const long NW = (long)N_NODES * IN_F / 2;
    long stride = NW / 1024;
    int sane = 0;
    for (int k = l; k < 1024; k += 64) {
        unsigned u = xu[(long)k * stride];
        unsigned e = (u >> 23) & 0xFF;
        if (u == 0u || (e >= 100 && e <= 140)) sane++;
    }
    const unsigned* wu = (const unsigned*)ei;
    int nz = 0;
    for (int k = l; k < 1024; k += 64) {
        long j = ((long)k * 1562) | 1;
        nz += (wu[j] != 0u);
    }
    for (int off = 32; off; off >>= 1) {
        sane += __shfl_xor(sane, off);
        nz   += __shfl_xor(nz, off);
    }
    if (l == 0) {
        flags[0] = (sane >= 512) ? 1 : 0;
        flags[1] = (nz < 16) ? 1 : 0;
    }
}

__device__ __forceinline__ void edge_sd(const void* __restrict__ ei, int e, int i64,
                                        int& s, int& d) {
    if (e < N_EDGES) {
        s = ldi(ei, e, i64);
        d = ldi(ei, (long)N_EDGES + e, i64);
        s = min(max(s, 0), N_NODES - 1);
        d = min(max(d, 0), N_NODES - 1);
    } else {
        s = d = e - N_EDGES;
    }
}

// ---------------- CSR build (once; graph is layer-invariant) ----------------
__global__ void deg_kernel(const void* __restrict__ ei, int* __restrict__ deg,
                           const int* __restrict__ flags) {
    int e = blockIdx.x * 256 + threadIdx.x;
    if (e >= ET) return;
    int s, d; edge_sd(ei, e, flags[1], s, d);
    atomicAdd(&deg[d], 1);
}

__global__ void chunk_sum_kernel(const int* __restrict__ deg, int* __restrict__ csum) {
    __shared__ int sd[256];
    int t = threadIdx.x;
    int i = blockIdx.x * 256 + t;
    sd[t] = (i < N_NODES) ? deg[i] : 0;
    __syncthreads();
    for (int off = 128; off; off >>= 1) {
        if (t < off) sd[t] += sd[t + off];
        __syncthreads();
    }
    if (t == 0) csum[blockIdx.x] = sd[0];
}

__global__ void scan_csum_kernel(int* __restrict__ csum) {  // in-place exclusive
    if (threadIdx.x != 0 || blockIdx.x != 0) return;
    int acc = 0;
    for (int i = 0; i < NCHUNK; i++) { int v = csum[i]; csum[i] = acc; acc += v; }
}

__global__ void chunk_scan_kernel(const int* __restrict__ deg, const int* __restrict__ csum,
                                  int* __restrict__ rowptr, int* __restrict__ cursor) {
    __shared__ int sd[256];
    int t = threadIdx.x;
    int i = blockIdx.x * 256 + t;
    int v = (i < N_NODES) ? deg[i] : 0;
    sd[t] = v;
    for (int off = 1; off < 256; off <<= 1) {
        __syncthreads();
        int add = (t >= off) ? sd[t - off] : 0;
        __syncthreads();
        sd[t] += add;
    }
    __syncthreads();
    int excl = sd[t] - v + csum[blockIdx.x];
    if (i < N_NODES) { rowptr[i] = excl; cursor[i] = excl; }
    if (i == 0) rowptr[N_NODES] = ET;
}

__global__ void fill_kernel(const void* __restrict__ ei, int* __restrict__ cursor,
                            int* __restrict__ srcs, const int* __restrict__ flags) {
    int e = blockIdx.x * 256 + threadIdx.x;
    if (e >= ET) return;
    int s, d; edge_sd(ei, e, flags[1], s, d);
    int pos = atomicAdd(&cursor[d], 1);
    srcs[pos] = s;
}

// ---------------- GEMM: MFMA split-bf16 (hi+lo) with frag-ordered W ----------------
__global__ void wt_kernel(const void* __restrict__ W, ushort* __restrict__ wt,
                          int K, const int* __restrict__ flags) {
    int i = blockIdx.x * 256 + threadIdx.x;
    if (i >= K * G) return;
    int k = i >> 7, n = i & (G - 1);
    float w = ldf(W, i, flags[0]);
    ushort h = f2bf(w);
    ushort lo = f2bf(w - bf2f(h));
    int c = k >> 5, q = (k >> 3) & 3, j = k & 7;
    int nt = n >> 4, n16 = n & 15;
    int lane = q * 16 + n16;
    size_t base = ((size_t)c * 16 + nt * 2) * 512 + lane * 8 + j;
    wt[base] = h;           // hilo = 0
    wt[base + 512] = lo;    // hilo = 1
}

// Block 256 thr = 4 waves; wave = 16 rows x 128 cols; grid = 782.
// H2: packed bf16x2, word l = {f_l, f_{l+64}}; es2[n] = {es, ed} (float2).
template <int K, bool AF32>
__device__ __forceinline__ void gemm_body(
    const void* __restrict__ A, const ushort* __restrict__ wt,
    unsigned* __restrict__ H2, const int* __restrict__ flags,
    const void* __restrict__ aS, const void* __restrict__ aD,
    float2* __restrict__ es2, short8* sB8) {
    constexpr int NC = K / 32;
    int wave = threadIdx.x >> 6, lane = threadIdx.x & 63;
    int quad = lane >> 4, n16 = lane & 15;
    int rb = blockIdx.x * 64 + wave * 16;
    int rowa = min(rb + n16, N_NODES - 1);
    f32x4 acc[8];
#pragma unroll
    for (int t = 0; t < 8; t++) acc[t] = (f32x4){0.f, 0.f, 0.f, 0.f};

    for (int c = 0; c < NC; c++) {
#pragma unroll
        for (int i = 0; i < 4; i++) {
            int fw = wave * 4 + i;
            stage16(wt + ((size_t)c * 16 + fw) * 512 + lane * 8, &sB8[fw * 64]);
        }
        float av[8];
        if (AF32) {
            const float* ap = (const float*)A + (size_t)rowa * K + c * 32 + quad * 8;
            f32x4 a0 = *(const f32x4*)ap;
            f32x4 a1 = *(const f32x4*)(ap + 4);
#pragma unroll
            for (int j = 0; j < 4; j++) { av[j] = a0[j]; av[j + 4] = a1[j]; }
        } else {
            const ushort* ap = (const ushort*)A + (size_t)rowa * K + c * 32 + quad * 8;
#pragma unroll
            for (int j = 0; j < 8; j++) av[j] = bf2f(ap[j]);
        }
        short8 ahi, alo;
#pragma unroll
        for (int j = 0; j < 8; j++) {
            ushort h = f2bf(av[j]);
            ahi[j] = (short)h;
            alo[j] = (short)f2bf(av[j] - bf2f(h));
        }
        __syncthreads();   // staging complete
#pragma unroll
        for (int nt = 0; nt < 8; nt++) {
            short8 bh = sB8[(nt * 2 + 0) * 64 + lane];
            short8 bl = sB8[(nt * 2 + 1) * 64 + lane];
            acc[nt] = __builtin_amdgcn_mfma_f32_16x16x32_bf16(ahi, bh, acc[nt], 0, 0, 0);
            acc[nt] = __builtin_amdgcn_mfma_f32_16x16x32_bf16(ahi, bl, acc[nt], 0, 0, 0);
            acc[nt] = __builtin_amdgcn_mfma_f32_16x16x32_bf16(alo, bh, acc[nt], 0, 0, 0);
        }
        __syncthreads();
    }

    // epilogue: packed-bf16 H2 store + fused ead (es2 = {h.as, h.ad})
    int f32 = flags[0];
    float asv[8], adv[8];
#pragma unroll
    for (int nt = 0; nt < 8; nt++) {
        asv[nt] = ldf(aS, nt * 16 + n16, f32);
        adv[nt] = ldf(aD, nt * 16 + n16, f32);
    }
#pragma unroll
    for (int r = 0; r < 4; r++) {
        int ro = rb + quad * 4 + r;
        float s = 0.f, dv = 0.f;
#pragma unroll
        for (int nt = 0; nt < 8; nt++) {
            s += acc[nt][r] * asv[nt];
            dv += acc[nt][r] * adv[nt];
        }
        if (ro < N_NODES) {
#pragma unroll
            for (int nt = 0; nt < 4; nt++) {   // word c = {f_c, f_{c+64}}
                unsigned pack = (unsigned)f2bf(acc[nt][r]) |
                                ((unsigned)f2bf(acc[nt + 4][r]) << 16);
                H2[(size_t)ro * 64 + nt * 16 + n16] = pack;
            }
        }
#pragma unroll
        for (int off = 8; off; off >>= 1) {
            s += __shfl_xor(s, off);
            dv += __shfl_xor(dv, off);
        }
        if (n16 == 0 && ro < N_NODES) es2[ro] = make_float2(s, dv);
    }
}

template <int K>
__global__ __launch_bounds__(256, 3) void gemm_mfma_kernel(
    const void* __restrict__ A, const ushort* __restrict__ wt,
    unsigned* __restrict__ H2, int a_internal, const int* __restrict__ flags,
    const void* __restrict__ aS, const void* __restrict__ aD,
    float2* __restrict__ es2) {
    __shared__ short8 sB8[16 * 64];   // 16 frags x 1 KB = 16 KB
    int af32 = a_internal ? 1 : flags[0];   // block-uniform
    if (af32) gemm_body<K, true>(A, wt, H2, flags, aS, aD, es2, sB8);
    else      gemm_body<K, false>(A, wt, H2, flags, aS, aD, es2, sB8);
}

// Fused GAT aggregate v3: 4 independent waves / 256-thr block, no LDS/barriers.
// Per-edge broadcast via v_readlane (loop index is wave-uniform -> scalar pipe,
// no lgkm stall; gather address becomes saddr + lane*4). Round-11 lesson:
// bpermute chains were the stall, not BW (FETCH halved, dur flat).
__global__ __launch_bounds__(256) void gat_agg_kernel(
    const unsigned* __restrict__ h2, const int* __restrict__ rowptr,
    const int* __restrict__ srcs, const float2* __restrict__ es2,
    const void* __restrict__ bias, float* __restrict__ outbuf,
    const int* __restrict__ flags) {
    int node = blockIdx.x * 4 + (threadIdx.x >> 6);
    if (node >= N_NODES) return;            // wave-uniform: all 64 lanes stay active
    int l = threadIdx.x & 63;
    int start = rowptr[node], end = rowptr[node + 1];
    float edd = es2[node].y;
    float m = -INFINITY, den = 0.f;
    float acc0 = 0.f, acc1 = 0.f;
    for (int c0 = start; c0 < end; c0 += 64) {
        int cn = min(end - c0, 64);
        int s = 0; float v = -INFINITY;
        if (l < cn) {
            s = srcs[c0 + l];
            v = es2[s].x + edd;
            v = v >= 0.f ? v : 0.2f * v;    // LeakyReLU(0.2)
        }
        float mc = v;
#pragma unroll
        for (int off = 32; off; off >>= 1) mc = fmaxf(mc, __shfl_xor(mc, off));
        float mnew = fmaxf(m, mc);
        float scale = expf(m - mnew);        // m=-INF first chunk -> 0
        float p = (l < cn) ? expf(v - mnew) : 0.f;
        float lsum = p;
#pragma unroll
        for (int off = 32; off; off >>= 1) lsum += __shfl_xor(lsum, off);
        den = den * scale + lsum;
        acc0 *= scale; acc1 *= scale;
#pragma unroll 4
        for (int i = 0; i < cn; i++) {
            int si = __builtin_amdgcn_readlane(s, i);                      // SGPR
            float pi = __uint_as_float(
                __builtin_amdgcn_readlane(__float_as_uint(p), i));         // SGPR
            unsigned hv = h2[(size_t)si * 64 + l];   // saddr-form wave load, 256B/row
            acc0 += pi * bf2f((ushort)(hv & 0xFFFFu));
            acc1 += pi * bf2f((ushort)(hv >> 16));
        }
        m = mnew;
    }
    float inv = 1.f / (den + 1e-16f);
    int f32 = flags[0];
    float o0 = acc0 * inv + ldf(bias, l, f32);
    float o1 = acc1 * inv + ldf(bias, l + 64, f32);
    outbuf[(size_t)node * G + l]      = selu_f(o0);
    outbuf[(size_t)node * G + l + 64] = selu_f(o1);
}

// ---------------- pool (+fused count) + head ----------------
__global__ void pool_kernel(const float* __restrict__ h, const void* __restrict__ batch,
                            float* __restrict__ gsum, float* __restrict__ gcnt,
                            const int* __restrict__ flags) {
    int t = threadIdx.x;  // 128
    int i64 = flags[1];
    int i0 = blockIdx.x * POOL_NODES;
    int i1 = min(N_NODES, i0 + POOL_NODES);
    int cur = -1, runLen = 0;
    float acc = 0.f;
    for (int i = i0; i < i1; i++) {
        int g = min(max(ldi(batch, i, i64), 0), NGRAPH - 1);
        if (g != cur) {
            if (cur >= 0) {
                atomicAdd(&gsum[cur * G + t], acc);
                if (t == 0) atomicAdd(&gcnt[cur], (float)runLen);
            }
            cur = g; acc = 0.f; runLen = 0;
        }
        acc += h[(size_t)i * G + t];
        runLen++;
    }
    if (cur >= 0) {
        atomicAdd(&gsum[cur * G + t], acc);
        if (t == 0) atomicAdd(&gcnt[cur], (float)runLen);
    }
}

// pooled -> selu -> lin1+selu -> lin2 -> log_softmax; OUTPUT FLOAT32
__global__ void head_kernel(const float* __restrict__ gsum, const float* __restrict__ gcnt,
                            const void* __restrict__ lw1, const void* __restrict__ lb1,
                            const void* __restrict__ lw2, const void* __restrict__ lb2,
                            float* __restrict__ out, const int* __restrict__ flags) {
    int g = blockIdx.x, t = threadIdx.x;  // 64
    int f32 = flags[0];
    __shared__ float z[G];
    __shared__ float z1[NHID];
    __shared__ float z2[2];
    float cnt = fmaxf(gcnt[g], 1.0f);
    z[t]      = selu_f(gsum[g * G + t] / cnt);
    z[t + 64] = selu_f(gsum[g * G + 64 + t] / cnt);
    __syncthreads();
    float a = ldf(lb1, t, f32);
    for (int k = 0; k < G; k++) a += z[k] * ldf(lw1, k * NHID + t, f32);
    z1[t] = selu_f(a);
    __syncthreads();
    if (t < 2) {
        float s = ldf(lb2, t, f32);
        for (int j = 0; j < NHID; j++) s += z1[j] * ldf(lw2, j * 2 + t, f32);
        z2[t] = s;
    }
    __syncthreads();
    if (t == 0) {
        float mx = fmaxf(z2[0], z2[1]);
        float l = mx + logf(expf(z2[0] - mx) + expf(z2[1] - mx));
        out[g * 2 + 0] = z2[0] - l;
        out[g * 2 + 1] = z2[1] - l;
    }
}

extern "C" void kernel_launch(void* const* d_in, const int* in_sizes, int n_in,
                              void* d_out, int out_size, void* d_ws, size_t ws_size,
                              hipStream_t stream) {
    const void* x    = d_in[0];
    const void* ei   = d_in[1];
    const void* batch= d_in[2];
    const void* W1   = d_in[3];
    const void* as1  = d_in[4];
    const void* ad1  = d_in[5];
    const void* b1   = d_in[6];
    const void* W2   = d_in[7];
    const void* as2  = d_in[8];
    const void* ad2  = d_in[9];
    const void* b2   = d_in[10];
    const void* lw1  = d_in[11];
    const void* lb1  = d_in[12];
    const void* lw2  = d_in[13];
    const void* lb2  = d_in[14];
    float* out = (float*)d_out;

    char* w = (char*)d_ws;
    size_t off = 0;
    auto alloc = [&](size_t bytes) -> char* {
        char* p = w + off;
        off = (off + bytes + 255) & ~(size_t)255;
        return p;
    };
    int*      flags  = (int*)alloc(256);
    unsigned* h2     = (unsigned*)alloc((size_t)N_NODES * 64 * 4);  // packed bf16x2
    float*    abuf   = (float*)alloc((size_t)N_NODES * G * 4);
    float2*   es2    = (float2*)alloc((size_t)N_NODES * 8);
    int*      deg    = (int*)alloc((size_t)N_NODES * 4);
    int*      rowptr = (int*)alloc((size_t)(N_NODES + 1) * 4);
    int*      cursor = (int*)alloc((size_t)N_NODES * 4);
    int*      csum   = (int*)alloc((size_t)NCHUNK * 4);
    int*      srcs   = (int*)alloc((size_t)ET * 4);
    float*    gsum   = (float*)alloc((size_t)NGRAPH * G * 4);
    float*    gcnt   = (float*)alloc((size_t)NGRAPH * 4);
    ushort*   wt1    = (ushort*)alloc((size_t)IN_F * G * 2 * 2);   // hi+lo frag-ordered
    ushort*   wt2    = (ushort*)alloc((size_t)G * G * 2 * 2);

    unsigned eb = (ET + 255) / 256;
    unsigned gemm_grid = (N_NODES + 63) / 64;
    unsigned agg_grid = (N_NODES + 3) / 4;

    detect_kernel<<<1, 64, 0, stream>>>(x, ei, flags);

    // ---------------- CSR build (once) ----------------
    hipMemsetAsync(deg, 0, (size_t)N_NODES * 4, stream);
    deg_kernel<<<eb, 256, 0, stream>>>(ei, deg, flags);
    chunk_sum_kernel<<<NCHUNK, 256, 0, stream>>>(deg, csum);
    scan_csum_kernel<<<1, 64, 0, stream>>>(csum);
    chunk_scan_kernel<<<NCHUNK, 256, 0, stream>>>(deg, csum, rowptr, cursor);
    fill_kernel<<<eb, 256, 0, stream>>>(ei, cursor, srcs, flags);

    // ---------------- W split/transpose into fragment order (once per layer) ----
    wt_kernel<<<(IN_F * G + 255) / 256, 256, 0, stream>>>(W1, wt1, IN_F, flags);
    wt_kernel<<<(G * G + 255) / 256, 256, 0, stream>>>(W2, wt2, G, flags);

    // ---------------- Layer 1 (gemm + fused ead -> packed h2) ----------------
    gemm_mfma_kernel<IN_F><<<gemm_grid, 256, 0, stream>>>(x, wt1, h2,
                                                          0, flags, as1, ad1, es2);
    gat_agg_kernel<<<agg_grid, 256, 0, stream>>>(h2, rowptr, srcs, es2, b1, abuf, flags);

    // ---------------- Layer 2 (gemm + fused ead -> packed h2) ----------------
    gemm_mfma_kernel<G><<<gemm_grid, 256, 0, stream>>>(abuf, wt2, h2,
                                                       1, flags, as2, ad2, es2);
    gat_agg_kernel<<<agg_grid, 256, 0, stream>>>(h2, rowptr, srcs, es2, b2, abuf, flags);

    // ---------------- Pool (+count) + head ----------------
    hipMemsetAsync(gsum, 0, (size_t)NGRAPH * G * 4, stream);
    hipMemsetAsync(gcnt, 0, (size_t)NGRAPH * 4, stream);
    pool_kernel<<<(N_NODES + POOL_NODES - 1) / POOL_NODES, 128, 0, stream>>>(
        abuf, batch, gsum, gcnt, flags);
    head_kernel<<<NGRAPH, 64, 0, stream>>>(gsum, gcnt, lw1, lb1, lw2, lb2, out, flags);
}

// Round 13
// 371.867 us; speedup vs baseline: 5.2474x; 1.1245x over previous
//
#include <hip/hip_runtime.h>
#include <hip/hip_bf16.h>
#include <math.h>

#define N_NODES 50000
#define N_EDGES 800000
#define ET (N_EDGES + N_NODES)   // edges + self loops
#define IN_F 256
#define G 128                    // 2*HID
#define NHID 64
#define NGRAPH 32
#define NCHUNK ((N_NODES + 255) / 256)   // 196
#define POOL_NODES 64

typedef __hip_bfloat16 bf16;
typedef unsigned short ushort;
typedef __attribute__((ext_vector_type(8))) short short8;
typedef __attribute__((ext_vector_type(4))) float f32x4;

// ---------- dtype-agnostic loads (flags resolved at runtime, wave-uniform) ----------
__device__ __forceinline__ float bf2f(ushort u) {
    union { unsigned u; float f; } c; c.u = ((unsigned)u) << 16; return c.f;
}
// round-to-nearest-even f32 -> bf16 (finite inputs)
__device__ __forceinline__ ushort f2bf(float f) {
    unsigned u = __float_as_uint(f);
    u += 0x7FFFu + ((u >> 16) & 1u);
    return (ushort)(u >> 16);
}
__device__ __forceinline__ float ldf(const void* p, long i, int f32) {
    return f32 ? ((const float*)p)[i] : bf2f(((const ushort*)p)[i]);
}
__device__ __forceinline__ int ldi(const void* p, long i, int i64) {
    return i64 ? (int)((const long long*)p)[i] : ((const int*)p)[i];
}

__device__ __forceinline__ float selu_f(float x) {
    const float sc = 1.0507009873554805f, al = 1.6732632423543772f;
    return x > 0.f ? sc * x : sc * al * expm1f(x);
}

// async global->LDS, 16 B/lane; lds base must be wave-uniform.
typedef const __attribute__((address_space(1))) void gas_void;
typedef __attribute__((address_space(3))) void las_void;
__device__ __forceinline__ void stage16(const void* g, void* l) {
    __builtin_amdgcn_global_load_lds((gas_void*)g, (las_void*)l, 16, 0, 0);
}

// flags[0]=1 -> float inputs are f32 (else bf16); flags[1]=1 -> ints are int64.
__global__ void detect_kernel(const void* x, const void* ei, int* flags) {
    int l = threadIdx.x;  // 64
    const unsigned* xu = (const unsigned*)x;
    const long NW = (long)N_NODES * IN_F / 2;
    long stride = NW / 1024;
    int sane = 0;
    for (int k = l; k < 1024; k += 64) {
        unsigned u = xu[(long)k * stride];
        unsigned e = (u >> 23) & 0xFF;
        if (u == 0u || (e >= 100 && e <= 140)) sane++;
    }
    const unsigned* wu = (const unsigned*)ei;
    int nz = 0;
    for (int k = l; k < 1024; k += 64) {
        long j = ((long)k * 1562) | 1;
        nz += (wu[j] != 0u);
    }
    for (int off = 32; off; off >>= 1) {
        sane += __shfl_xor(sane, off);
        nz   += __shfl_xor(nz, off);
    }
    if (l == 0) {
        flags[0] = (sane >= 512) ? 1 : 0;
        flags[1] = (nz < 16) ? 1 : 0;
    }
}

__device__ __forceinline__ void edge_sd(const void* __restrict__ ei, int e, int i64,
                                        int& s, int& d) {
    if (e < N_EDGES) {
        s = ldi(ei, e, i64);
        d = ldi(ei, (long)N_EDGES + e, i64);
        s = min(max(s, 0), N_NODES - 1);
        d = min(max(d, 0), N_NODES - 1);
    } else {
        s = d = e - N_EDGES;
    }
}

// ---------------- CSR build (once; graph is layer-invariant) ----------------
__global__ void deg_kernel(const void* __restrict__ ei, int* __restrict__ deg,
                           const int* __restrict__ flags) {
    int e = blockIdx.x * 256 + threadIdx.x;
    if (e >= ET) return;
    int s, d; edge_sd(ei, e, flags[1], s, d);
    atomicAdd(&deg[d], 1);
}

__global__ void chunk_sum_kernel(const int* __restrict__ deg, int* __restrict__ csum) {
    __shared__ int sd[256];
    int t = threadIdx.x;
    int i = blockIdx.x * 256 + t;
    sd[t] = (i < N_NODES) ? deg[i] : 0;
    __syncthreads();
    for (int off = 128; off; off >>= 1) {
        if (t < off) sd[t] += sd[t + off];
        __syncthreads();
    }
    if (t == 0) csum[blockIdx.x] = sd[0];
}

__global__ void scan_csum_kernel(int* __restrict__ csum) {  // in-place exclusive
    if (threadIdx.x != 0 || blockIdx.x != 0) return;
    int acc = 0;
    for (int i = 0; i < NCHUNK; i++) { int v = csum[i]; csum[i] = acc; acc += v; }
}

__global__ void chunk_scan_kernel(const int* __restrict__ deg, const int* __restrict__ csum,
                                  int* __restrict__ rowptr, int* __restrict__ cursor) {
    __shared__ int sd[256];
    int t = threadIdx.x;
    int i = blockIdx.x * 256 + t;
    int v = (i < N_NODES) ? deg[i] : 0;
    sd[t] = v;
    for (int off = 1; off < 256; off <<= 1) {
        __syncthreads();
        int add = (t >= off) ? sd[t - off] : 0;
        __syncthreads();
        sd[t] += add;
    }
    __syncthreads();
    int excl = sd[t] - v + csum[blockIdx.x];
    if (i < N_NODES) { rowptr[i] = excl; cursor[i] = excl; }
    if (i == 0) rowptr[N_NODES] = ET;
}

__global__ void fill_kernel(const void* __restrict__ ei, int* __restrict__ cursor,
                            int* __restrict__ srcs, const int* __restrict__ flags) {
    int e = blockIdx.x * 256 + threadIdx.x;
    if (e >= ET) return;
    int s, d; edge_sd(ei, e, flags[1], s, d);
    int pos = atomicAdd(&cursor[d], 1);
    srcs[pos] = s;
}

// ---------------- GEMM: MFMA split-bf16 (hi+lo) with frag-ordered W ----------------
__global__ void wt_kernel(const void* __restrict__ W, ushort* __restrict__ wt,
                          int K, const int* __restrict__ flags) {
    int i = blockIdx.x * 256 + threadIdx.x;
    if (i >= K * G) return;
    int k = i >> 7, n = i & (G - 1);
    float w = ldf(W, i, flags[0]);
    ushort h = f2bf(w);
    ushort lo = f2bf(w - bf2f(h));
    int c = k >> 5, q = (k >> 3) & 3, j = k & 7;
    int nt = n >> 4, n16 = n & 15;
    int lane = q * 16 + n16;
    size_t base = ((size_t)c * 16 + nt * 2) * 512 + lane * 8 + j;
    wt[base] = h;           // hilo = 0
    wt[base + 512] = lo;    // hilo = 1
}

// Block 256 thr = 4 waves; wave = 16 rows x 128 cols; grid = 782.
// H2: packed bf16x2, word l = {f_l, f_{l+64}}; es2[n] = {es, ed} (float2).
// A path: AF32 (external f32) or bf16 row-major (external bf16 OR internal abuf).
template <int K, bool AF32>
__device__ __forceinline__ void gemm_body(
    const void* __restrict__ A, const ushort* __restrict__ wt,
    unsigned* __restrict__ H2, const int* __restrict__ flags,
    const void* __restrict__ aS, const void* __restrict__ aD,
    float2* __restrict__ es2, short8* sB8) {
    constexpr int NC = K / 32;
    int wave = threadIdx.x >> 6, lane = threadIdx.x & 63;
    int quad = lane >> 4, n16 = lane & 15;
    int rb = blockIdx.x * 64 + wave * 16;
    int rowa = min(rb + n16, N_NODES - 1);
    f32x4 acc[8];
#pragma unroll
    for (int t = 0; t < 8; t++) acc[t] = (f32x4){0.f, 0.f, 0.f, 0.f};

    for (int c = 0; c < NC; c++) {
#pragma unroll
        for (int i = 0; i < 4; i++) {
            int fw = wave * 4 + i;
            stage16(wt + ((size_t)c * 16 + fw) * 512 + lane * 8, &sB8[fw * 64]);
        }
        float av[8];
        if (AF32) {
            const float* ap = (const float*)A + (size_t)rowa * K + c * 32 + quad * 8;
            f32x4 a0 = *(const f32x4*)ap;
            f32x4 a1 = *(const f32x4*)(ap + 4);
#pragma unroll
            for (int j = 0; j < 4; j++) { av[j] = a0[j]; av[j + 4] = a1[j]; }
        } else {
            const ushort* ap = (const ushort*)A + (size_t)rowa * K + c * 32 + quad * 8;
#pragma unroll
            for (int j = 0; j < 8; j++) av[j] = bf2f(ap[j]);
        }
        short8 ahi, alo;
#pragma unroll
        for (int j = 0; j < 8; j++) {
            ushort h = f2bf(av[j]);
            ahi[j] = (short)h;
            alo[j] = (short)f2bf(av[j] - bf2f(h));
        }
        __syncthreads();   // staging complete
#pragma unroll
        for (int nt = 0; nt < 8; nt++) {
            short8 bh = sB8[(nt * 2 + 0) * 64 + lane];
            short8 bl = sB8[(nt * 2 + 1) * 64 + lane];
            acc[nt] = __builtin_amdgcn_mfma_f32_16x16x32_bf16(ahi, bh, acc[nt], 0, 0, 0);
            acc[nt] = __builtin_amdgcn_mfma_f32_16x16x32_bf16(ahi, bl, acc[nt], 0, 0, 0);
            acc[nt] = __builtin_amdgcn_mfma_f32_16x16x32_bf16(alo, bh, acc[nt], 0, 0, 0);
        }
        __syncthreads();
    }

    // epilogue: packed-bf16 H2 store + fused ead (es2 = {h.as, h.ad})
    int f32 = flags[0];
    float asv[8], adv[8];
#pragma unroll
    for (int nt = 0; nt < 8; nt++) {
        asv[nt] = ldf(aS, nt * 16 + n16, f32);
        adv[nt] = ldf(aD, nt * 16 + n16, f32);
    }
#pragma unroll
    for (int r = 0; r < 4; r++) {
        int ro = rb + quad * 4 + r;
        float s = 0.f, dv = 0.f;
#pragma unroll
        for (int nt = 0; nt < 8; nt++) {
            s += acc[nt][r] * asv[nt];
            dv += acc[nt][r] * adv[nt];
        }
        if (ro < N_NODES) {
#pragma unroll
            for (int nt = 0; nt < 4; nt++) {   // word c = {f_c, f_{c+64}}
                unsigned pack = (unsigned)f2bf(acc[nt][r]) |
                                ((unsigned)f2bf(acc[nt + 4][r]) << 16);
                H2[(size_t)ro * 64 + nt * 16 + n16] = pack;
            }
        }
#pragma unroll
        for (int off = 8; off; off >>= 1) {
            s += __shfl_xor(s, off);
            dv += __shfl_xor(dv, off);
        }
        if (n16 == 0 && ro < N_NODES) es2[ro] = make_float2(s, dv);
    }
}

// a_mode: 0 = external (flags-dependent), 2 = internal bf16 row-major
template <int K>
__global__ __launch_bounds__(256, 3) void gemm_mfma_kernel(
    const void* __restrict__ A, const ushort* __restrict__ wt,
    unsigned* __restrict__ H2, int a_mode, const int* __restrict__ flags,
    const void* __restrict__ aS, const void* __restrict__ aD,
    float2* __restrict__ es2) {
    __shared__ short8 sB8[16 * 64];   // 16 frags x 1 KB = 16 KB
    int af32 = (a_mode == 2) ? 0 : flags[0];   // block-uniform
    if (af32) gemm_body<K, true>(A, wt, H2, flags, aS, aD, es2, sB8);
    else      gemm_body<K, false>(A, wt, H2, flags, aS, aD, es2, sB8);
}

// Fused GAT aggregate v4: rounds 10-12 all ~66us across 3 broadcast styles ->
// MLP-bound (VGPR=16 allowed only ~4 outstanding gathers vs ~500cyc L3/HBM
// latency). Fix: 8-deep explicit load batching. Chunk rounded up to x8:
// inactive lanes carry s=0,p=0 -> harmless row-0 loads, zero contribution.
// Output: row-major bf16 (f32 accumulate, round at store) -> layer-2 GEMM
// reads it via its bf16-A path; pool reads bf16.
__global__ __launch_bounds__(256) void gat_agg_kernel(
    const unsigned* __restrict__ h2, const int* __restrict__ rowptr,
    const int* __restrict__ srcs, const float2* __restrict__ es2,
    const void* __restrict__ bias, ushort* __restrict__ outb,
    const int* __restrict__ flags) {
    int node = blockIdx.x * 4 + (threadIdx.x >> 6);
    if (node >= N_NODES) return;            // wave-uniform: all 64 lanes stay active
    int l = threadIdx.x & 63;
    int start = rowptr[node], end = rowptr[node + 1];
    float edd = es2[node].y;
    float m = -INFINITY, den = 0.f;
    float acc0 = 0.f, acc1 = 0.f;
    for (int c0 = start; c0 < end; c0 += 64) {
        int cn = min(end - c0, 64);
        int s = 0; float v = -INFINITY;
        if (l < cn) {
            s = srcs[c0 + l];
            v = es2[s].x + edd;
            v = v >= 0.f ? v : 0.2f * v;    // LeakyReLU(0.2)
        }
        float mc = v;
#pragma unroll
        for (int off = 32; off; off >>= 1) mc = fmaxf(mc, __shfl_xor(mc, off));
        float mnew = fmaxf(m, mc);
        float scale = expf(m - mnew);        // m=-INF first chunk -> 0
        float p = (l < cn) ? expf(v - mnew) : 0.f;
        float lsum = p;
#pragma unroll
        for (int off = 32; off; off >>= 1) lsum += __shfl_xor(lsum, off);
        den = den * scale + lsum;
        acc0 *= scale; acc1 *= scale;
        int cnr = (cn + 7) & ~7;             // round up: tail lanes have p=0
        for (int i = 0; i < cnr; i += 8) {
            int sis[8]; float pis[8]; unsigned hv[8];
#pragma unroll
            for (int j = 0; j < 8; j++) {
                sis[j] = __builtin_amdgcn_readlane(s, i + j);
                pis[j] = __uint_as_float(
                    __builtin_amdgcn_readlane(__float_as_uint(p), i + j));
            }
#pragma unroll
            for (int j = 0; j < 8; j++)      // 8 outstanding 256B wave-loads
                hv[j] = h2[(size_t)sis[j] * 64 + l];
#pragma unroll
            for (int j = 0; j < 8; j++) {
                acc0 += pis[j] * bf2f((ushort)(hv[j] & 0xFFFFu));
                acc1 += pis[j] * bf2f((ushort)(hv[j] >> 16));
            }
        }
        m = mnew;
    }
    float inv = 1.f / (den + 1e-16f);
    int f32 = flags[0];
    float o0 = acc0 * inv + ldf(bias, l, f32);
    float o1 = acc1 * inv + ldf(bias, l + 64, f32);
    outb[(size_t)node * G + l]      = f2bf(selu_f(o0));
    outb[(size_t)node * G + l + 64] = f2bf(selu_f(o1));
}

// ---------------- pool (+fused count) + head ----------------
__global__ void pool_kernel(const ushort* __restrict__ h, const void* __restrict__ batch,
                            float* __restrict__ gsum, float* __restrict__ gcnt,
                            const int* __restrict__ flags) {
    int t = threadIdx.x;  // 128
    int i64 = flags[1];
    int i0 = blockIdx.x * POOL_NODES;
    int i1 = min(N_NODES, i0 + POOL_NODES);
    int cur = -1, runLen = 0;
    float acc = 0.f;
    for (int i = i0; i < i1; i++) {
        int g = min(max(ldi(batch, i, i64), 0), NGRAPH - 1);
        if (g != cur) {
            if (cur >= 0) {
                atomicAdd(&gsum[cur * G + t], acc);
                if (t == 0) atomicAdd(&gcnt[cur], (float)runLen);
            }
            cur = g; acc = 0.f; runLen = 0;
        }
        acc += bf2f(h[(size_t)i * G + t]);
        runLen++;
    }
    if (cur >= 0) {
        atomicAdd(&gsum[cur * G + t], acc);
        if (t == 0) atomicAdd(&gcnt[cur], (float)runLen);
    }
}

// pooled -> selu -> lin1+selu -> lin2 -> log_softmax; OUTPUT FLOAT32
__global__ void head_kernel(const float* __restrict__ gsum, const float* __restrict__ gcnt,
                            const void* __restrict__ lw1, const void* __restrict__ lb1,
                            const void* __restrict__ lw2, const void* __restrict__ lb2,
                            float* __restrict__ out, const int* __restrict__ flags) {
    int g = blockIdx.x, t = threadIdx.x;  // 64
    int f32 = flags[0];
    __shared__ float z[G];
    __shared__ float z1[NHID];
    __shared__ float z2[2];
    float cnt = fmaxf(gcnt[g], 1.0f);
    z[t]      = selu_f(gsum[g * G + t] / cnt);
    z[t + 64] = selu_f(gsum[g * G + 64 + t] / cnt);
    __syncthreads();
    float a = ldf(lb1, t, f32);
    for (int k = 0; k < G; k++) a += z[k] * ldf(lw1, k * NHID + t, f32);
    z1[t] = selu_f(a);
    __syncthreads();
    if (t < 2) {
        float s = ldf(lb2, t, f32);
        for (int j = 0; j < NHID; j++) s += z1[j] * ldf(lw2, j * 2 + t, f32);
        z2[t] = s;
    }
    __syncthreads();
    if (t == 0) {
        float mx = fmaxf(z2[0], z2[1]);
        float l = mx + logf(expf(z2[0] - mx) + expf(z2[1] - mx));
        out[g * 2 + 0] = z2[0] - l;
        out[g * 2 + 1] = z2[1] - l;
    }
}

extern "C" void kernel_launch(void* const* d_in, const int* in_sizes, int n_in,
                              void* d_out, int out_size, void* d_ws, size_t ws_size,
                              hipStream_t stream) {
    const void* x    = d_in[0];
    const void* ei   = d_in[1];
    const void* batch= d_in[2];
    const void* W1   = d_in[3];
    const void* as1  = d_in[4];
    const void* ad1  = d_in[5];
    const void* b1   = d_in[6];
    const void* W2   = d_in[7];
    const void* as2  = d_in[8];
    const void* ad2  = d_in[9];
    const void* b2   = d_in[10];
    const void* lw1  = d_in[11];
    const void* lb1  = d_in[12];
    const void* lw2  = d_in[13];
    const void* lb2  = d_in[14];
    float* out = (float*)d_out;

    char* w = (char*)d_ws;
    size_t off = 0;
    auto alloc = [&](size_t bytes) -> char* {
        char* p = w + off;
        off = (off + bytes + 255) & ~(size_t)255;
        return p;
    };
    int*      flags  = (int*)alloc(256);
    unsigned* h2     = (unsigned*)alloc((size_t)N_NODES * 64 * 4);  // packed bf16x2
    ushort*   abuf   = (ushort*)alloc((size_t)N_NODES * G * 2);     // bf16 activations
    float2*   es2    = (float2*)alloc((size_t)N_NODES * 8);
    int*      deg    = (int*)alloc((size_t)N_NODES * 4);
    int*      rowptr = (int*)alloc((size_t)(N_NODES + 1) * 4);
    int*      cursor = (int*)alloc((size_t)N_NODES * 4);
    int*      csum   = (int*)alloc((size_t)NCHUNK * 4);
    int*      srcs   = (int*)alloc((size_t)ET * 4);
    float*    gsum   = (float*)alloc((size_t)NGRAPH * G * 4);
    float*    gcnt   = (float*)alloc((size_t)NGRAPH * 4);
    ushort*   wt1    = (ushort*)alloc((size_t)IN_F * G * 2 * 2);   // hi+lo frag-ordered
    ushort*   wt2    = (ushort*)alloc((size_t)G * G * 2 * 2);

    unsigned eb = (ET + 255) / 256;
    unsigned gemm_grid = (N_NODES + 63) / 64;
    unsigned agg_grid = (N_NODES + 3) / 4;

    detect_kernel<<<1, 64, 0, stream>>>(x, ei, flags);

    // ---------------- CSR build (once) ----------------
    hipMemsetAsync(deg, 0, (size_t)N_NODES * 4, stream);
    deg_kernel<<<eb, 256, 0, stream>>>(ei, deg, flags);
    chunk_sum_kernel<<<NCHUNK, 256, 0, stream>>>(deg, csum);
    scan_csum_kernel<<<1, 64, 0, stream>>>(csum);
    chunk_scan_kernel<<<NCHUNK, 256, 0, stream>>>(deg, csum, rowptr, cursor);
    fill_kernel<<<eb, 256, 0, stream>>>(ei, cursor, srcs, flags);

    // ---------------- W split/transpose into fragment order (once per layer) ----
    wt_kernel<<<(IN_F * G + 255) / 256, 256, 0, stream>>>(W1, wt1, IN_F, flags);
    wt_kernel<<<(G * G + 255) / 256, 256, 0, stream>>>(W2, wt2, G, flags);

    // ---------------- Layer 1 (gemm + fused ead -> packed h2) ----------------
    gemm_mfma_kernel<IN_F><<<gemm_grid, 256, 0, stream>>>(x, wt1, h2,
                                                          0, flags, as1, ad1, es2);
    gat_agg_kernel<<<agg_grid, 256, 0, stream>>>(h2, rowptr, srcs, es2, b1, abuf, flags);

    // ---------------- Layer 2 (gemm + fused ead -> packed h2) ----------------
    gemm_mfma_kernel<G><<<gemm_grid, 256, 0, stream>>>(abuf, wt2, h2,
                                                       2, flags, as2, ad2, es2);
    gat_agg_kernel<<<agg_grid, 256, 0, stream>>>(h2, rowptr, srcs, es2, b2, abuf, flags);

    // ---------------- Pool (+count) + head ----------------
    hipMemsetAsync(gsum, 0, (size_t)NGRAPH * G * 4, stream);
    hipMemsetAsync(gcnt, 0, (size_t)NGRAPH * 4, stream);
    pool_kernel<<<(N_NODES + POOL_NODES - 1) / POOL_NODES, 128, 0, stream>>>(
        abuf, batch, gsum, gcnt, flags);
    head_kernel<<<NGRAPH, 64, 0, stream>>>(gsum, gcnt, lw1, lb1, lw2, lb2, out, flags);
}

// Round 14
// 314.023 us; speedup vs baseline: 6.2140x; 1.1842x over previous
//
#include <hip/hip_runtime.h>
#include <hip/hip_bf16.h>
#include <math.h>

#define N_NODES 50000
#define N_EDGES 800000
#define ET (N_EDGES + N_NODES)   // edges + self loops
#define IN_F 256
#define G 128                    // 2*HID
#define NHID 64
#define NGRAPH 32
#define NCHUNK ((N_NODES + 255) / 256)   // 196 buckets (dst>>8)
#define POOL_NODES 64
#define EPB 4096                          // edges per binA block
#define NBA ((ET + EPB - 1) / EPB)        // 208

typedef __hip_bfloat16 bf16;
typedef unsigned short ushort;
typedef __attribute__((ext_vector_type(8))) short short8;
typedef __attribute__((ext_vector_type(4))) float f32x4;

// ---------- dtype-agnostic loads (flags resolved at runtime, wave-uniform) ----------
__device__ __forceinline__ float bf2f(ushort u) {
    union { unsigned u; float f; } c; c.u = ((unsigned)u) << 16; return c.f;
}
// round-to-nearest-even f32 -> bf16 (finite inputs)
__device__ __forceinline__ ushort f2bf(float f) {
    unsigned u = __float_as_uint(f);
    u += 0x7FFFu + ((u >> 16) & 1u);
    return (ushort)(u >> 16);
}
__device__ __forceinline__ float ldf(const void* p, long i, int f32) {
    return f32 ? ((const float*)p)[i] : bf2f(((const ushort*)p)[i]);
}
__device__ __forceinline__ int ldi(const void* p, long i, int i64) {
    return i64 ? (int)((const long long*)p)[i] : ((const int*)p)[i];
}

__device__ __forceinline__ float selu_f(float x) {
    const float sc = 1.0507009873554805f, al = 1.6732632423543772f;
    return x > 0.f ? sc * x : sc * al * expm1f(x);
}

// async global->LDS, 16 B/lane; lds base must be wave-uniform.
typedef const __attribute__((address_space(1))) void gas_void;
typedef __attribute__((address_space(3))) void las_void;
__device__ __forceinline__ void stage16(const void* g, void* l) {
    __builtin_amdgcn_global_load_lds((gas_void*)g, (las_void*)l, 16, 0, 0);
}

// flags[0]=1 -> float inputs are f32 (else bf16); flags[1]=1 -> ints are int64.
__global__ void detect_kernel(const void* x, const void* ei, int* flags) {
    int l = threadIdx.x;  // 64
    const unsigned* xu = (const unsigned*)x;
    const long NW = (long)N_NODES * IN_F / 2;
    long stride = NW / 1024;
    int sane = 0;
    for (int k = l; k < 1024; k += 64) {
        unsigned u = xu[(long)k * stride];
        unsigned e = (u >> 23) & 0xFF;
        if (u == 0u || (e >= 100 && e <= 140)) sane++;
    }
    const unsigned* wu = (const unsigned*)ei;
    int nz = 0;
    for (int k = l; k < 1024; k += 64) {
        long j = ((long)k * 1562) | 1;
        nz += (wu[j] != 0u);
    }
    for (int off = 32; off; off >>= 1) {
        sane += __shfl_xor(sane, off);
        nz   += __shfl_xor(nz, off);
    }
    if (l == 0) {
        flags[0] = (sane >= 512) ? 1 : 0;
        flags[1] = (nz < 16) ? 1 : 0;
    }
}

__device__ __forceinline__ void edge_sd(const void* __restrict__ ei, int e, int i64,
                                        int& s, int& d) {
    if (e < N_EDGES) {
        s = ldi(ei, e, i64);
        d = ldi(ei, (long)N_EDGES + e, i64);
        s = min(max(s, 0), N_NODES - 1);
        d = min(max(d, 0), N_NODES - 1);
    } else {
        s = d = e - N_EDGES;
    }
}

// ---------------- CSR build v2: 2-level bucket sort (round-13 lesson: random
// 4B scatter = 64B/edge HBM write-amp, 54.6MB; bucketing makes all writes
// block-local/contiguous) ----------------

// per-block LDS histogram over 196 dst-buckets -> few global atomics
__global__ void histA_kernel(const void* __restrict__ ei, int* __restrict__ bcnt,
                             const int* __restrict__ flags) {
    __shared__ int h[256];
    int t = threadIdx.x;
    h[t] = 0;
    __syncthreads();
    int e0 = blockIdx.x * EPB;
    int i64 = flags[1];
    for (int j = 0; j < EPB / 256; j++) {
        int e = e0 + j * 256 + t;
        if (e < ET) {
            int s, d; edge_sd(ei, e, i64, s, d);
            atomicAdd(&h[d >> 8], 1);
        }
    }
    __syncthreads();
    if (t < NCHUNK && h[t]) atomicAdd(&bcnt[t], h[t]);
}

__global__ void scan196_kernel(const int* __restrict__ bcnt, int* __restrict__ csum,
                               int* __restrict__ bcur) {
    if (threadIdx.x != 0 || blockIdx.x != 0) return;
    int acc = 0;
    for (int i = 0; i < NCHUNK; i++) { csum[i] = acc; bcur[i] = acc; acc += bcnt[i]; }
}

// bin 4096 edges into bucket-grouped LDS staging, copy out contiguously.
__global__ __launch_bounds__(256) void binA_kernel(
    const void* __restrict__ ei, int* __restrict__ bcur, int2* __restrict__ pairs,
    const int* __restrict__ flags) {
    __shared__ int cnt[256], lofs[256], pcur[256], gbase[256];
    __shared__ int2 stage[EPB];
    int t = threadIdx.x;
    int e0 = blockIdx.x * EPB;
    int nE = min(EPB, ET - e0);
    int i64 = flags[1];
    int sj[EPB / 256], dj[EPB / 256];
    cnt[t] = 0;
    __syncthreads();
#pragma unroll
    for (int j = 0; j < EPB / 256; j++) {
        int idx = j * 256 + t;
        if (idx < nE) {
            edge_sd(ei, e0 + idx, i64, sj[j], dj[j]);
            atomicAdd(&cnt[dj[j] >> 8], 1);
        } else dj[j] = -1;
    }
    __syncthreads();
    lofs[t] = cnt[t];
    for (int off = 1; off < 256; off <<= 1) {
        __syncthreads();
        int v = (t >= off) ? lofs[t - off] : 0;
        __syncthreads();
        lofs[t] += v;
    }
    __syncthreads();
    int excl = lofs[t] - cnt[t];
    __syncthreads();
    lofs[t] = excl;
    pcur[t] = excl;
    __syncthreads();
    if (t < NCHUNK && cnt[t]) gbase[t] = atomicAdd(&bcur[t], cnt[t]);
    __syncthreads();
#pragma unroll
    for (int j = 0; j < EPB / 256; j++) {
        if (dj[j] >= 0) {
            int lp = atomicAdd(&pcur[dj[j] >> 8], 1);
            stage[lp] = make_int2(sj[j], dj[j]);
        }
    }
    __syncthreads();
    for (int i = t; i < nE; i += 256) {   // contiguous per-bucket runs (~21 edges)
        int2 p = stage[i];
        int b = p.y >> 8;
        pairs[gbase[b] + i - lofs[b]] = p;
    }
}

// one block per bucket: per-node counts+scan in LDS -> rowptr (coalesced),
// then scatter srcs within the bucket's ~17KB window (single block -> L2-local)
__global__ __launch_bounds__(256) void binB_kernel(
    const int2* __restrict__ pairs, const int* __restrict__ csum,
    int* __restrict__ rowptr, int* __restrict__ srcs) {
    __shared__ int cnt[256], cur[256];
    int b = blockIdx.x, t = threadIdx.x;
    int start = csum[b];
    int end = (b + 1 < NCHUNK) ? csum[b + 1] : ET;
    cnt[t] = 0;
    __syncthreads();
    for (int i = start + t; i < end; i += 256)
        atomicAdd(&cnt[pairs[i].y & 255], 1);
    __syncthreads();
    cur[t] = cnt[t];
    for (int off = 1; off < 256; off <<= 1) {
        __syncthreads();
        int v = (t >= off) ? cur[t - off] : 0;
        __syncthreads();
        cur[t] += v;
    }
    __syncthreads();
    int excl = cur[t] - cnt[t];
    __syncthreads();
    cur[t] = start + excl;
    int node = b * 256 + t;
    if (node < N_NODES) rowptr[node] = start + excl;
    if (b == NCHUNK - 1 && t == 0) rowptr[N_NODES] = ET;
    __syncthreads();
    for (int i = start + t; i < end; i += 256) {
        int2 p = pairs[i];
        int pos = atomicAdd(&cur[p.y & 255], 1);
        srcs[pos] = p.x;
    }
}

// ---------------- GEMM: MFMA split-bf16 (hi+lo) with frag-ordered W ----------------
__global__ void wt_kernel(const void* __restrict__ W, ushort* __restrict__ wt,
                          int K, const int* __restrict__ flags) {
    int i = blockIdx.x * 256 + threadIdx.x;
    if (i >= K * G) return;
    int k = i >> 7, n = i & (G - 1);
    float w = ldf(W, i, flags[0]);
    ushort h = f2bf(w);
    ushort lo = f2bf(w - bf2f(h));
    int c = k >> 5, q = (k >> 3) & 3, j = k & 7;
    int nt = n >> 4, n16 = n & 15;
    int lane = q * 16 + n16;
    size_t base = ((size_t)c * 16 + nt * 2) * 512 + lane * 8 + j;
    wt[base] = h;           // hilo = 0
    wt[base + 512] = lo;    // hilo = 1
}

// Block 256 thr = 4 waves; wave = 16 rows x 128 cols; grid = 782.
// H2: packed bf16x2, word l = {f_l, f_{l+64}}; es2[n] = {es, ed} (float2).
template <int K, bool AF32>
__device__ __forceinline__ void gemm_body(
    const void* __restrict__ A, const ushort* __restrict__ wt,
    unsigned* __restrict__ H2, const int* __restrict__ flags,
    const void* __restrict__ aS, const void* __restrict__ aD,
    float2* __restrict__ es2, short8* sB8) {
    constexpr int NC = K / 32;
    int wave = threadIdx.x >> 6, lane = threadIdx.x & 63;
    int quad = lane >> 4, n16 = lane & 15;
    int rb = blockIdx.x * 64 + wave * 16;
    int rowa = min(rb + n16, N_NODES - 1);
    f32x4 acc[8];
#pragma unroll
    for (int t = 0; t < 8; t++) acc[t] = (f32x4){0.f, 0.f, 0.f, 0.f};

    for (int c = 0; c < NC; c++) {
#pragma unroll
        for (int i = 0; i < 4; i++) {
            int fw = wave * 4 + i;
            stage16(wt + ((size_t)c * 16 + fw) * 512 + lane * 8, &sB8[fw * 64]);
        }
        float av[8];
        if (AF32) {
            const float* ap = (const float*)A + (size_t)rowa * K + c * 32 + quad * 8;
            f32x4 a0 = *(const f32x4*)ap;
            f32x4 a1 = *(const f32x4*)(ap + 4);
#pragma unroll
            for (int j = 0; j < 4; j++) { av[j] = a0[j]; av[j + 4] = a1[j]; }
        } else {
            const ushort* ap = (const ushort*)A + (size_t)rowa * K + c * 32 + quad * 8;
#pragma unroll
            for (int j = 0; j < 8; j++) av[j] = bf2f(ap[j]);
        }
        short8 ahi, alo;
#pragma unroll
        for (int j = 0; j < 8; j++) {
            ushort h = f2bf(av[j]);
            ahi[j] = (short)h;
            alo[j] = (short)f2bf(av[j] - bf2f(h));
        }
        __syncthreads();   // staging complete
#pragma unroll
        for (int nt = 0; nt < 8; nt++) {
            short8 bh = sB8[(nt * 2 + 0) * 64 + lane];
            short8 bl = sB8[(nt * 2 + 1) * 64 + lane];
            acc[nt] = __builtin_amdgcn_mfma_f32_16x16x32_bf16(ahi, bh, acc[nt], 0, 0, 0);
            acc[nt] = __builtin_amdgcn_mfma_f32_16x16x32_bf16(ahi, bl, acc[nt], 0, 0, 0);
            acc[nt] = __builtin_amdgcn_mfma_f32_16x16x32_bf16(alo, bh, acc[nt], 0, 0, 0);
        }
        __syncthreads();
    }

    // epilogue: packed-bf16 H2 store + fused ead (es2 = {h.as, h.ad})
    int f32 = flags[0];
    float asv[8], adv[8];
#pragma unroll
    for (int nt = 0; nt < 8; nt++) {
        asv[nt] = ldf(aS, nt * 16 + n16, f32);
        adv[nt] = ldf(aD, nt * 16 + n16, f32);
    }
#pragma unroll
    for (int r = 0; r < 4; r++) {
        int ro = rb + quad * 4 + r;
        float s = 0.f, dv = 0.f;
#pragma unroll
        for (int nt = 0; nt < 8; nt++) {
            s += acc[nt][r] * asv[nt];
            dv += acc[nt][r] * adv[nt];
        }
        if (ro < N_NODES) {
#pragma unroll
            for (int nt = 0; nt < 4; nt++) {   // word c = {f_c, f_{c+64}}
                unsigned pack = (unsigned)f2bf(acc[nt][r]) |
                                ((unsigned)f2bf(acc[nt + 4][r]) << 16);
                H2[(size_t)ro * 64 + nt * 16 + n16] = pack;
            }
        }
#pragma unroll
        for (int off = 8; off; off >>= 1) {
            s += __shfl_xor(s, off);
            dv += __shfl_xor(dv, off);
        }
        if (n16 == 0 && ro < N_NODES) es2[ro] = make_float2(s, dv);
    }
}

// a_mode: 0 = external (flags-dependent), 2 = internal bf16 row-major
template <int K>
__global__ __launch_bounds__(256, 3) void gemm_mfma_kernel(
    const void* __restrict__ A, const ushort* __restrict__ wt,
    unsigned* __restrict__ H2, int a_mode, const int* __restrict__ flags,
    const void* __restrict__ aS, const void* __restrict__ aD,
    float2* __restrict__ es2) {
    __shared__ short8 sB8[16 * 64];   // 16 frags x 1 KB = 16 KB
    int af32 = (a_mode == 2) ? 0 : flags[0];   // block-uniform
    if (af32) gemm_body<K, true>(A, wt, H2, flags, aS, aD, es2, sB8);
    else      gemm_body<K, false>(A, wt, H2, flags, aS, aD, es2, sB8);
}

// Fused GAT aggregate v4 (round-13 verified): 4 waves/block, no LDS/barriers,
// 8-deep explicit gather batching, bf16 output.
__global__ __launch_bounds__(256) void gat_agg_kernel(
    const unsigned* __restrict__ h2, const int* __restrict__ rowptr,
    const int* __restrict__ srcs, const float2* __restrict__ es2,
    const void* __restrict__ bias, ushort* __restrict__ outb,
    const int* __restrict__ flags) {
    int node = blockIdx.x * 4 + (threadIdx.x >> 6);
    if (node >= N_NODES) return;            // wave-uniform: all 64 lanes stay active
    int l = threadIdx.x & 63;
    int start = rowptr[node], end = rowptr[node + 1];
    float edd = es2[node].y;
    float m = -INFINITY, den = 0.f;
    float acc0 = 0.f, acc1 = 0.f;
    for (int c0 = start; c0 < end; c0 += 64) {
        int cn = min(end - c0, 64);
        int s = 0; float v = -INFINITY;
        if (l < cn) {
            s = srcs[c0 + l];
            v = es2[s].x + edd;
            v = v >= 0.f ? v : 0.2f * v;    // LeakyReLU(0.2)
        }
        float mc = v;
#pragma unroll
        for (int off = 32; off; off >>= 1) mc = fmaxf(mc, __shfl_xor(mc, off));
        float mnew = fmaxf(m, mc);
        float scale = expf(m - mnew);        // m=-INF first chunk -> 0
        float p = (l < cn) ? expf(v - mnew) : 0.f;
        float lsum = p;
#pragma unroll
        for (int off = 32; off; off >>= 1) lsum += __shfl_xor(lsum, off);
        den = den * scale + lsum;
        acc0 *= scale; acc1 *= scale;
        int cnr = (cn + 7) & ~7;             // round up: tail lanes have p=0
        for (int i = 0; i < cnr; i += 8) {
            int sis[8]; float pis[8]; unsigned hv[8];
#pragma unroll
            for (int j = 0; j < 8; j++) {
                sis[j] = __builtin_amdgcn_readlane(s, i + j);
                pis[j] = __uint_as_float(
                    __builtin_amdgcn_readlane(__float_as_uint(p), i + j));
            }
#pragma unroll
            for (int j = 0; j < 8; j++)      // 8 outstanding 256B wave-loads
                hv[j] = h2[(size_t)sis[j] * 64 + l];
#pragma unroll
            for (int j = 0; j < 8; j++) {
                acc0 += pis[j] * bf2f((ushort)(hv[j] & 0xFFFFu));
                acc1 += pis[j] * bf2f((ushort)(hv[j] >> 16));
            }
        }
        m = mnew;
    }
    float inv = 1.f / (den + 1e-16f);
    int f32 = flags[0];
    float o0 = acc0 * inv + ldf(bias, l, f32);
    float o1 = acc1 * inv + ldf(bias, l + 64, f32);
    outb[(size_t)node * G + l]      = f2bf(selu_f(o0));
    outb[(size_t)node * G + l + 64] = f2bf(selu_f(o1));
}

// ---------------- pool (+fused count) + head ----------------
__global__ void pool_kernel(const ushort* __restrict__ h, const void* __restrict__ batch,
                            float* __restrict__ gsum, float* __restrict__ gcnt,
                            const int* __restrict__ flags) {
    int t = threadIdx.x;  // 128
    int i64 = flags[1];
    int i0 = blockIdx.x * POOL_NODES;
    int i1 = min(N_NODES, i0 + POOL_NODES);
    int cur = -1, runLen = 0;
    float acc = 0.f;
    for (int i = i0; i < i1; i++) {
        int g = min(max(ldi(batch, i, i64), 0), NGRAPH - 1);
        if (g != cur) {
            if (cur >= 0) {
                atomicAdd(&gsum[cur * G + t], acc);
                if (t == 0) atomicAdd(&gcnt[cur], (float)runLen);
            }
            cur = g; acc = 0.f; runLen = 0;
        }
        acc += bf2f(h[(size_t)i * G + t]);
        runLen++;
    }
    if (cur >= 0) {
        atomicAdd(&gsum[cur * G + t], acc);
        if (t == 0) atomicAdd(&gcnt[cur], (float)runLen);
    }
}

// pooled -> selu -> lin1+selu -> lin2 -> log_softmax; OUTPUT FLOAT32
__global__ void head_kernel(const float* __restrict__ gsum, const float* __restrict__ gcnt,
                            const void* __restrict__ lw1, const void* __restrict__ lb1,
                            const void* __restrict__ lw2, const void* __restrict__ lb2,
                            float* __restrict__ out, const int* __restrict__ flags) {
    int g = blockIdx.x, t = threadIdx.x;  // 64
    int f32 = flags[0];
    __shared__ float z[G];
    __shared__ float z1[NHID];
    __shared__ float z2[2];
    float cnt = fmaxf(gcnt[g], 1.0f);
    z[t]      = selu_f(gsum[g * G + t] / cnt);
    z[t + 64] = selu_f(gsum[g * G + 64 + t] / cnt);
    __syncthreads();
    float a = ldf(lb1, t, f32);
    for (int k = 0; k < G; k++) a += z[k] * ldf(lw1, k * NHID + t, f32);
    z1[t] = selu_f(a);
    __syncthreads();
    if (t < 2) {
        float s = ldf(lb2, t, f32);
        for (int j = 0; j < NHID; j++) s += z1[j] * ldf(lw2, j * 2 + t, f32);
        z2[t] = s;
    }
    __syncthreads();
    if (t == 0) {
        float mx = fmaxf(z2[0], z2[1]);
        float l = mx + logf(expf(z2[0] - mx) + expf(z2[1] - mx));
        out[g * 2 + 0] = z2[0] - l;
        out[g * 2 + 1] = z2[1] - l;
    }
}

extern "C" void kernel_launch(void* const* d_in, const int* in_sizes, int n_in,
                              void* d_out, int out_size, void* d_ws, size_t ws_size,
                              hipStream_t stream) {
    const void* x    = d_in[0];
    const void* ei   = d_in[1];
    const void* batch= d_in[2];
    const void* W1   = d_in[3];
    const void* as1  = d_in[4];
    const void* ad1  = d_in[5];
    const void* b1   = d_in[6];
    const void* W2   = d_in[7];
    const void* as2  = d_in[8];
    const void* ad2  = d_in[9];
    const void* b2   = d_in[10];
    const void* lw1  = d_in[11];
    const void* lb1  = d_in[12];
    const void* lw2  = d_in[13];
    const void* lb2  = d_in[14];
    float* out = (float*)d_out;

    char* w = (char*)d_ws;
    size_t off = 0;
    auto alloc = [&](size_t bytes) -> char* {
        char* p = w + off;
        off = (off + bytes + 255) & ~(size_t)255;
        return p;
    };
    int*      flags  = (int*)alloc(256);
    unsigned* h2     = (unsigned*)alloc((size_t)N_NODES * 64 * 4);  // packed bf16x2
    ushort*   abuf   = (ushort*)alloc((size_t)N_NODES * G * 2);     // bf16 activations
    float2*   es2    = (float2*)alloc((size_t)N_NODES * 8);
    int*      rowptr = (int*)alloc((size_t)(N_NODES + 1) * 4);
    int*      bcnt   = (int*)alloc((size_t)NCHUNK * 4);
    int*      csum   = (int*)alloc((size_t)NCHUNK * 4);
    int*      bcur   = (int*)alloc((size_t)NCHUNK * 4);
    int2*     pairs  = (int2*)alloc((size_t)ET * 8);
    int*      srcs   = (int*)alloc((size_t)ET * 4);
    float*    gsum   = (float*)alloc((size_t)NGRAPH * G * 4);
    float*    gcnt   = (float*)alloc((size_t)NGRAPH * 4);
    ushort*   wt1    = (ushort*)alloc((size_t)IN_F * G * 2 * 2);   // hi+lo frag-ordered
    ushort*   wt2    = (ushort*)alloc((size_t)G * G * 2 * 2);

    unsigned gemm_grid = (N_NODES + 63) / 64;
    unsigned agg_grid = (N_NODES + 3) / 4;

    detect_kernel<<<1, 64, 0, stream>>>(x, ei, flags);

    // ---------------- CSR build v2: bucket sort ----------------
    hipMemsetAsync(bcnt, 0, (size_t)NCHUNK * 4, stream);
    histA_kernel<<<NBA, 256, 0, stream>>>(ei, bcnt, flags);
    scan196_kernel<<<1, 64, 0, stream>>>(bcnt, csum, bcur);
    binA_kernel<<<NBA, 256, 0, stream>>>(ei, bcur, pairs, flags);
    binB_kernel<<<NCHUNK, 256, 0, stream>>>(pairs, csum, rowptr, srcs);

    // ---------------- W split/transpose into fragment order (once per layer) ----
    wt_kernel<<<(IN_F * G + 255) / 256, 256, 0, stream>>>(W1, wt1, IN_F, flags);
    wt_kernel<<<(G * G + 255) / 256, 256, 0, stream>>>(W2, wt2, G, flags);

    // ---------------- Layer 1 (gemm + fused ead -> packed h2) ----------------
    gemm_mfma_kernel<IN_F><<<gemm_grid, 256, 0, stream>>>(x, wt1, h2,
                                                          0, flags, as1, ad1, es2);
    gat_agg_kernel<<<agg_grid, 256, 0, stream>>>(h2, rowptr, srcs, es2, b1, abuf, flags);

    // ---------------- Layer 2 (gemm + fused ead -> packed h2) ----------------
    gemm_mfma_kernel<G><<<gemm_grid, 256, 0, stream>>>(abuf, wt2, h2,
                                                       2, flags, as2, ad2, es2);
    gat_agg_kernel<<<agg_grid, 256, 0, stream>>>(h2, rowptr, srcs, es2, b2, abuf, flags);

    // ---------------- Pool (+count) + head ----------------
    hipMemsetAsync(gsum, 0, (size_t)NGRAPH * G * 4, stream);
    hipMemsetAsync(gcnt, 0, (size_t)NGRAPH * 4, stream);
    pool_kernel<<<(N_NODES + POOL_NODES - 1) / POOL_NODES, 128, 0, stream>>>(
        abuf, batch, gsum, gcnt, flags);
    head_kernel<<<NGRAPH, 64, 0, stream>>>(gsum, gcnt, lw1, lb1, lw2, lb2, out, flags);
}